// Round 1
// baseline (12067.432 us; speedup 1.0000x reference)
//
#include <hip/hip_runtime.h>
#include <hip/hip_bf16.h>

// Problem constants (KANBlock): B=2,S=1024,H=1024,NH=16,HD=64,DFF=1024,E=4,TOPK=2
// b_splines: G=5, K_ORD=3, NB=8, grid[m] = 0.4*(m-3) - 1, m=0..11
#define T_TOK 2048
#define H_DIM 1024
#define S_SEQ 1024
#define NHEAD 16
#define HDIM  64
#define E_EXP 4
#define DFF_  1024

__device__ __forceinline__ float sigmoidf_(float x) { return 1.0f / (1.0f + __expf(-x)); }

// Cubic B-spline bases on uniform grid, matches reference b_splines() exactly
// (order-0 indicator + 3 Cox-de Boor recursions, in-place ascending update).
__device__ __forceinline__ void bspline8(float x, float* o) {
    float b[11];
#pragma unroll
    for (int m = 0; m < 11; ++m) {
        float g0 = 0.4f * (float)(m - 3) - 1.0f;
        float g1 = 0.4f * (float)(m - 2) - 1.0f;
        b[m] = (x >= g0 && x < g1) ? 1.0f : 0.0f;
    }
#pragma unroll
    for (int j = 1; j <= 3; ++j) {
        float inv = 1.0f / (0.4f * (float)j);
#pragma unroll
        for (int m = 0; m + j < 11; ++m) {
            float gm   = 0.4f * (float)(m - 3) - 1.0f;       // grid[m]
            float gmj1 = 0.4f * (float)(m + j - 2) - 1.0f;   // grid[m+j+1]
            b[m] = ((x - gm) * b[m] + (gmj1 - x) * b[m + 1]) * inv;
        }
    }
#pragma unroll
    for (int c = 0; c < 8; ++c) o[c] = b[c];
}

// ---------------- RMSNorm: one block per token, 1024 = 256 threads x float4
__global__ __launch_bounds__(256) void rmsnorm_kernel(const float* __restrict__ x,
                                                      const float* __restrict__ w,
                                                      float* __restrict__ out) {
    long t = blockIdx.x;
    const float4* xr = (const float4*)(x + t * H_DIM);
    float4 v = xr[threadIdx.x];
    float ss = v.x * v.x + v.y * v.y + v.z * v.z + v.w * v.w;
#pragma unroll
    for (int m = 1; m < 64; m <<= 1) ss += __shfl_xor(ss, m, 64);
    __shared__ float wsum[4];
    if ((threadIdx.x & 63) == 0) wsum[threadIdx.x >> 6] = ss;
    __syncthreads();
    ss = wsum[0] + wsum[1] + wsum[2] + wsum[3];
    float sc = rsqrtf(ss * (1.0f / (float)H_DIM) + 1e-6f);
    float4 wv = ((const float4*)w)[threadIdx.x];
    float4 r;
    r.x = v.x * sc * wv.x; r.y = v.y * sc * wv.y;
    r.z = v.z * sc * wv.z; r.w = v.w * sc * wv.w;
    ((float4*)(out + t * H_DIM))[threadIdx.x] = r;
}

// ---------------- Fused KAN GEMM: C(M,N) = [silu(A)|bspl(A)] @ [baseW | splW*scal]^T
// A: (M,1024) fp32. K_eff = 1024*9, tiled as KI=8 input elems -> BK=72.
// mode 0: C = acc (row-major, stride N)
// mode 1: C += rowScale[m*rsStride] * acc   (MoE accumulate into d_out)
#define KI 8
#define BKK 72
__global__ __launch_bounds__(256) void kan_gemm(const float* __restrict__ Act,
                                                const float* __restrict__ baseW,
                                                const float* __restrict__ splW,
                                                const float* __restrict__ scal,
                                                float* __restrict__ C,
                                                const float* __restrict__ rowScale,
                                                int rsStride, int N, int mode) {
    __shared__ float As[BKK][64];
    __shared__ float Bs[BKK][64];
    const int bm = blockIdx.y * 64;
    const int bn = blockIdx.x * 64;
    const int tid = threadIdx.x;
    const int tx = tid & 15, ty = tid >> 4;
    float acc[4][4] = {};
    for (int i0 = 0; i0 < H_DIM; i0 += KI) {
        // Stage A-tile: evaluate silu + 8 spline bases per activation element
        for (int e = tid; e < 64 * KI; e += 256) {
            int m = e >> 3, ii = e & 7;
            float xv = Act[(long)(bm + m) * H_DIM + i0 + ii];
            float sp[8];
            bspline8(xv, sp);
            As[ii * 9][m] = xv * sigmoidf_(xv);
#pragma unroll
            for (int c = 0; c < 8; ++c) As[ii * 9 + 1 + c][m] = sp[c];
        }
        // Stage B-tile: pack [base, spline*scaler] on the fly
        for (int e = tid; e < 64 * KI; e += 256) {
            int n = e >> 3, ii = e & 7;
            long w = (long)(bn + n) * H_DIM + i0 + ii;
            float sc = scal[w];
            Bs[ii * 9][n] = baseW[w];
            const float4* sp4 = (const float4*)(splW + w * 8);
            float4 s0 = sp4[0], s1 = sp4[1];
            Bs[ii * 9 + 1][n] = s0.x * sc; Bs[ii * 9 + 2][n] = s0.y * sc;
            Bs[ii * 9 + 3][n] = s0.z * sc; Bs[ii * 9 + 4][n] = s0.w * sc;
            Bs[ii * 9 + 5][n] = s1.x * sc; Bs[ii * 9 + 6][n] = s1.y * sc;
            Bs[ii * 9 + 7][n] = s1.z * sc; Bs[ii * 9 + 8][n] = s1.w * sc;
        }
        __syncthreads();
#pragma unroll 8
        for (int k = 0; k < BKK; ++k) {
            float4 a = *(const float4*)&As[k][ty * 4];
            float4 b = *(const float4*)&Bs[k][tx * 4];
            float av[4] = {a.x, a.y, a.z, a.w};
            float bv[4] = {b.x, b.y, b.z, b.w};
#pragma unroll
            for (int i = 0; i < 4; ++i)
#pragma unroll
                for (int j = 0; j < 4; ++j) acc[i][j] = fmaf(av[i], bv[j], acc[i][j]);
        }
        __syncthreads();
    }
#pragma unroll
    for (int i = 0; i < 4; ++i) {
        long m = bm + ty * 4 + i;
        float rs = (mode == 1) ? rowScale[m * rsStride] : 0.0f;
#pragma unroll
        for (int j = 0; j < 4; ++j) {
            long idx = m * (long)N + bn + tx * 4 + j;
            if (mode == 0) C[idx] = acc[i][j];
            else           C[idx] += rs * acc[i][j];
        }
    }
}

// ---------------- Plain GEMM for out-proj: C = res + bias + A @ Bw^T (all 1024-dim)
__global__ __launch_bounds__(256) void gemm_bias_res(const float* __restrict__ A,
                                                     const float* __restrict__ Bw,
                                                     const float* __restrict__ bias,
                                                     const float* __restrict__ res,
                                                     float* __restrict__ C) {
    __shared__ float As[16][64];
    __shared__ float Bs[16][64];
    const int bm = blockIdx.y * 64, bn = blockIdx.x * 64;
    const int tid = threadIdx.x;
    const int tx = tid & 15, ty = tid >> 4;
    float acc[4][4] = {};
    for (int k0 = 0; k0 < 1024; k0 += 16) {
        for (int e = tid; e < 1024; e += 256) {
            int r = e >> 4, kk = e & 15;
            As[kk][r] = A[(long)(bm + r) * 1024 + k0 + kk];
            Bs[kk][r] = Bw[(long)(bn + r) * 1024 + k0 + kk];
        }
        __syncthreads();
#pragma unroll
        for (int k = 0; k < 16; ++k) {
            float4 a = *(const float4*)&As[k][ty * 4];
            float4 b = *(const float4*)&Bs[k][tx * 4];
            float av[4] = {a.x, a.y, a.z, a.w};
            float bv[4] = {b.x, b.y, b.z, b.w};
#pragma unroll
            for (int i = 0; i < 4; ++i)
#pragma unroll
                for (int j = 0; j < 4; ++j) acc[i][j] = fmaf(av[i], bv[j], acc[i][j]);
        }
        __syncthreads();
    }
#pragma unroll
    for (int i = 0; i < 4; ++i) {
        long m = bm + ty * 4 + i;
#pragma unroll
        for (int j = 0; j < 4; ++j) {
            long n = bn + tx * 4 + j;
            C[m * 1024 + n] = res[m * 1024 + n] + bias[n] + acc[i][j];
        }
    }
}

// ---------------- RoPE in-place on qkv buffer (q and k parts per head)
__global__ __launch_bounds__(256) void rope_kernel(float* __restrict__ qkv,
                                                   const float* __restrict__ cs,
                                                   const float* __restrict__ sn) {
    int idx = blockIdx.x * 256 + threadIdx.x;   // T*NH*32
    if (idx >= T_TOK * NHEAD * 32) return;
    int p = idx & 31;
    int n = (idx >> 5) & 15;
    int t = idx >> 9;
    int s = t & (S_SEQ - 1);
    float c = cs[s * 32 + p], si = sn[s * 32 + p];
    long base = (long)t * 3072 + n * 192;
    float re = qkv[base + 2 * p], im = qkv[base + 2 * p + 1];
    qkv[base + 2 * p]     = re * c - im * si;
    qkv[base + 2 * p + 1] = re * si + im * c;
    re = qkv[base + 64 + 2 * p]; im = qkv[base + 64 + 2 * p + 1];
    qkv[base + 64 + 2 * p]     = re * c - im * si;
    qkv[base + 64 + 2 * p + 1] = re * si + im * c;
}

// ---------------- Flash attention fp32: block = (32 q-rows, one (b,h)), 256 thr
// Thread (q = tid/8, g = tid%8): owns 8 output dims [g*8, g*8+8), scores for k in [g*8,g*8+8).
__global__ __launch_bounds__(256) void attn_kernel(const float* __restrict__ qkv,
                                                   float* __restrict__ ctx) {
    const int qb = blockIdx.x * 32;
    const int h = blockIdx.y, b = blockIdx.z;
    __shared__ float Qs[32][64];
    __shared__ float Ks[64][64];
    __shared__ float Vs[64][64];
    __shared__ float Ss[32][64];
    const int tid = threadIdx.x;
    const int q = tid >> 3, g = tid & 7;
    for (int e = tid; e < 32 * 64; e += 256) {
        int r = e >> 6, d = e & 63;
        Qs[r][d] = qkv[(long)(b * S_SEQ + qb + r) * 3072 + h * 192 + d];
    }
    float m_run = -1e30f, l_run = 0.0f;
    float acc[8] = {};
    for (int k0 = 0; k0 < S_SEQ; k0 += 64) {
        for (int e = tid; e < 64 * 64; e += 256) {
            int r = e >> 6, d = e & 63;
            long base = (long)(b * S_SEQ + k0 + r) * 3072 + h * 192;
            Ks[r][d] = qkv[base + 64 + d];
            Vs[r][d] = qkv[base + 128 + d];
        }
        __syncthreads();
        float s[8];
#pragma unroll
        for (int kk = 0; kk < 8; ++kk) {
            int k = g * 8 + kk;
            float dot = 0.0f;
#pragma unroll
            for (int d = 0; d < 64; ++d) dot = fmaf(Qs[q][d], Ks[k][d], dot);
            s[kk] = dot * 0.125f;   // 1/sqrt(64)
        }
        float mx = s[0];
#pragma unroll
        for (int kk = 1; kk < 8; ++kk) mx = fmaxf(mx, s[kk]);
#pragma unroll
        for (int w = 1; w < 8; w <<= 1) mx = fmaxf(mx, __shfl_xor(mx, w, 64));
        float m_new = fmaxf(m_run, mx);
        float p[8], ls = 0.0f;
#pragma unroll
        for (int kk = 0; kk < 8; ++kk) { p[kk] = __expf(s[kk] - m_new); ls += p[kk]; }
#pragma unroll
        for (int w = 1; w < 8; w <<= 1) ls += __shfl_xor(ls, w, 64);
        float alpha = __expf(m_run - m_new);
        l_run = l_run * alpha + ls;
        m_run = m_new;
#pragma unroll
        for (int kk = 0; kk < 8; ++kk) Ss[q][g * 8 + kk] = p[kk];
        __syncthreads();
#pragma unroll
        for (int j = 0; j < 8; ++j) acc[j] *= alpha;
        for (int k = 0; k < 64; ++k) {
            float pv = Ss[q][k];
#pragma unroll
            for (int j = 0; j < 8; ++j) acc[j] = fmaf(pv, Vs[k][g * 8 + j], acc[j]);
        }
        __syncthreads();
    }
    float inv = 1.0f / l_run;
#pragma unroll
    for (int j = 0; j < 8; ++j)
        ctx[(long)(b * S_SEQ + qb + q) * H_DIM + h * 64 + g * 8 + j] = acc[j] * inv;
}

// ---------------- Gate: logits (T,4) -> top-2 softmax weights, zeros elsewhere
__global__ __launch_bounds__(256) void gate_kernel(const float* __restrict__ h2,
                                                   const float* __restrict__ gate_w,
                                                   float* __restrict__ gw) {
    long t = blockIdx.x;
    float sum[4] = {0, 0, 0, 0};
    for (int i = threadIdx.x; i < H_DIM; i += 256) {
        float v = h2[t * H_DIM + i];
#pragma unroll
        for (int e = 0; e < 4; ++e) sum[e] = fmaf(v, gate_w[e * H_DIM + i], sum[e]);
    }
#pragma unroll
    for (int w = 1; w < 64; w <<= 1)
#pragma unroll
        for (int e = 0; e < 4; ++e) sum[e] += __shfl_xor(sum[e], w, 64);
    __shared__ float part[4][4];
    if ((threadIdx.x & 63) == 0)
#pragma unroll
        for (int e = 0; e < 4; ++e) part[e][threadIdx.x >> 6] = sum[e];
    __syncthreads();
    if (threadIdx.x == 0) {
        float lg[4];
#pragma unroll
        for (int e = 0; e < 4; ++e) lg[e] = part[e][0] + part[e][1] + part[e][2] + part[e][3];
        int i0 = 0;
        for (int e = 1; e < 4; ++e) if (lg[e] > lg[i0]) i0 = e;   // ties -> lower idx (jax top_k)
        int i1 = -1;
        for (int e = 0; e < 4; ++e) if (e != i0 && (i1 < 0 || lg[e] > lg[i1])) i1 = e;
        float mx = fmaxf(lg[i0], lg[i1]);
        float e0 = __expf(lg[i0] - mx), e1 = __expf(lg[i1] - mx);
        float inv = 1.0f / (e0 + e1);
        float o[4] = {0, 0, 0, 0};
        o[i0] = e0 * inv; o[i1] = e1 * inv;
#pragma unroll
        for (int e = 0; e < 4; ++e) gw[t * 4 + e] = o[e];
    }
}

__global__ __launch_bounds__(256) void mul_kernel(const float* __restrict__ a,
                                                  const float* __restrict__ b,
                                                  float* __restrict__ c, int n) {
    int i = blockIdx.x * 256 + threadIdx.x;
    if (i < n) c[i] = a[i] * b[i];
}

extern "C" void kernel_launch(void* const* d_in, const int* in_sizes, int n_in,
                              void* d_out, int out_size, void* d_ws, size_t ws_size,
                              hipStream_t stream) {
    const float* x          = (const float*)d_in[0];
    const float* rot_cos    = (const float*)d_in[1];
    const float* rot_sin    = (const float*)d_in[2];
    const float* norm1_w    = (const float*)d_in[3];
    const float* norm2_w    = (const float*)d_in[4];
    const float* qkv_base   = (const float*)d_in[5];
    const float* qkv_spline = (const float*)d_in[6];
    const float* qkv_scaler = (const float*)d_in[7];
    const float* out_w      = (const float*)d_in[8];
    const float* out_b      = (const float*)d_in[9];
    const float* gate_w     = (const float*)d_in[10];
    const float* w1_base    = (const float*)d_in[11];
    const float* w1_spline  = (const float*)d_in[12];
    const float* w1_scaler  = (const float*)d_in[13];
    const float* w2_base    = (const float*)d_in[14];
    const float* w2_spline  = (const float*)d_in[15];
    const float* w2_scaler  = (const float*)d_in[16];
    const float* w3_base    = (const float*)d_in[17];
    const float* w3_spline  = (const float*)d_in[18];
    const float* w3_scaler  = (const float*)d_in[19];
    float* out = (float*)d_out;

    char* ws = (char*)d_ws;
    float* hn  = (float*)ws; ws += (size_t)T_TOK * H_DIM * 4;
    float* qkv = (float*)ws; ws += (size_t)T_TOK * 3072 * 4;
    float* ctx = (float*)ws; ws += (size_t)T_TOK * H_DIM * 4;
    float* h2  = (float*)ws; ws += (size_t)T_TOK * H_DIM * 4;
    float* gw  = (float*)ws; ws += (size_t)T_TOK * E_EXP * 4;
    float* g1  = (float*)ws; ws += (size_t)T_TOK * DFF_ * 4;
    float* g2  = (float*)ws; ws += (size_t)T_TOK * DFF_ * 4;
    float* gm  = (float*)ws; ws += (size_t)T_TOK * DFF_ * 4;

    // 1. hn = rmsnorm(x, norm1_w)
    rmsnorm_kernel<<<T_TOK, 256, 0, stream>>>(x, norm1_w, hn);
    // 2. qkv = kan_linear(hn, qkv_*)   (T,3072)
    dim3 gq(3072 / 64, T_TOK / 64);
    kan_gemm<<<gq, 256, 0, stream>>>(hn, qkv_base, qkv_spline, qkv_scaler, qkv,
                                     nullptr, 0, 3072, 0);
    // 3. RoPE on q,k in-place
    rope_kernel<<<(T_TOK * NHEAD * 32) / 256, 256, 0, stream>>>(qkv, rot_cos, rot_sin);
    // 4. flash attention -> ctx (T, H) head-major
    dim3 ga(S_SEQ / 32, NHEAD, 2);
    attn_kernel<<<ga, 256, 0, stream>>>(qkv, ctx);
    // 5. d_out = x + ctx @ out_w^T + out_b
    dim3 go(1024 / 64, T_TOK / 64);
    gemm_bias_res<<<go, 256, 0, stream>>>(ctx, out_w, out_b, x, out);
    // 6. h2 = rmsnorm(d_out, norm2_w)
    rmsnorm_kernel<<<T_TOK, 256, 0, stream>>>(out, norm2_w, h2);
    // 7. gate weights (T,4), zeros for unselected experts
    gate_kernel<<<T_TOK, 256, 0, stream>>>(h2, gate_w, gw);
    // 8. experts: d_out += gw[:,e] * kan3(kan1(h2)*kan2(h2))
    dim3 ge(1024 / 64, T_TOK / 64);
    for (int e = 0; e < E_EXP; ++e) {
        long wo = (long)e * DFF_ * H_DIM;
        kan_gemm<<<ge, 256, 0, stream>>>(h2, w1_base + wo, w1_spline + wo * 8,
                                         w1_scaler + wo, g1, nullptr, 0, DFF_, 0);
        kan_gemm<<<ge, 256, 0, stream>>>(h2, w2_base + wo, w2_spline + wo * 8,
                                         w2_scaler + wo, g2, nullptr, 0, DFF_, 0);
        mul_kernel<<<(T_TOK * DFF_) / 256, 256, 0, stream>>>(g1, g2, gm, T_TOK * DFF_);
        kan_gemm<<<ge, 256, 0, stream>>>(gm, w3_base + wo, w3_spline + wo * 8,
                                         w3_scaler + wo, out, gw + e, E_EXP, H_DIM, 1);
    }
}

// Round 2
// 2601.545 us; speedup vs baseline: 4.6386x; 4.6386x over previous
//
#include <hip/hip_runtime.h>
#include <hip/hip_bf16.h>

// KANBlock: B=2,S=1024,H=1024,NH=16,HD=64,DFF=1024,E=4,TOPK=2, NB=8 spline bases
#define T_TOK 2048
#define H_DIM 1024
#define S_SEQ 1024
#define NHEAD 16
#define E_EXP 4
#define DFF_  1024
#define KAUG  9216   // 9 * 1024 augmented K (k = c*1024 + i, c=0 silu, c=1..8 splines)

typedef __bf16 bf16x8 __attribute__((ext_vector_type(8)));
typedef float  f32x4  __attribute__((ext_vector_type(4)));

__device__ __forceinline__ float sigmoidf_(float x) { return 1.0f / (1.0f + __expf(-x)); }

__device__ __forceinline__ unsigned short f2bf(float f) {   // RNE f32 -> bf16 bits
    unsigned int u = __float_as_uint(f);
    u = (u + 0x7fffu + ((u >> 16) & 1u)) >> 16;
    return (unsigned short)u;
}
__device__ __forceinline__ float bf2f(unsigned short h) {
    return __uint_as_float(((unsigned int)h) << 16);
}

// Cubic B-spline bases, matches reference b_splines() (verified round 0)
__device__ __forceinline__ void bspline8(float x, float* o) {
    float b[11];
#pragma unroll
    for (int m = 0; m < 11; ++m) {
        float g0 = 0.4f * (float)(m - 3) - 1.0f;
        float g1 = 0.4f * (float)(m - 2) - 1.0f;
        b[m] = (x >= g0 && x < g1) ? 1.0f : 0.0f;
    }
#pragma unroll
    for (int j = 1; j <= 3; ++j) {
        float inv = 1.0f / (0.4f * (float)j);
#pragma unroll
        for (int m = 0; m + j < 11; ++m) {
            float gm   = 0.4f * (float)(m - 3) - 1.0f;
            float gmj1 = 0.4f * (float)(m + j - 2) - 1.0f;
            b[m] = ((x - gm) * b[m] + (gmj1 - x) * b[m + 1]) * inv;
        }
    }
#pragma unroll
    for (int c = 0; c < 8; ++c) o[c] = b[c];
}

// ---------------- RMSNorm
__global__ __launch_bounds__(256) void rmsnorm_kernel(const float* __restrict__ x,
                                                      const float* __restrict__ w,
                                                      float* __restrict__ out) {
    long t = blockIdx.x;
    float4 v = ((const float4*)(x + t * H_DIM))[threadIdx.x];
    float ss = v.x * v.x + v.y * v.y + v.z * v.z + v.w * v.w;
#pragma unroll
    for (int m = 1; m < 64; m <<= 1) ss += __shfl_xor(ss, m, 64);
    __shared__ float wsum[4];
    if ((threadIdx.x & 63) == 0) wsum[threadIdx.x >> 6] = ss;
    __syncthreads();
    ss = wsum[0] + wsum[1] + wsum[2] + wsum[3];
    float sc = rsqrtf(ss * (1.0f / (float)H_DIM) + 1e-6f);
    float4 wv = ((const float4*)w)[threadIdx.x];
    float4 r;
    r.x = v.x * sc * wv.x; r.y = v.y * sc * wv.y;
    r.z = v.z * sc * wv.z; r.w = v.w * sc * wv.w;
    ((float4*)(out + t * H_DIM))[threadIdx.x] = r;
}

// ---------------- pack activations -> augmented bf16 (hi, optional lo for split)
__global__ __launch_bounds__(256) void pack_act(const float* __restrict__ act,
                                                unsigned short* __restrict__ hi,
                                                unsigned short* __restrict__ lo) {
    long idx = (long)blockIdx.x * 256 + threadIdx.x;   // T_TOK*1024 exact
    long m = idx >> 10; int i = (int)(idx & 1023);
    float v = act[idx];
    float ch[9];
    ch[0] = v * sigmoidf_(v);
    bspline8(v, ch + 1);
    unsigned short* oh = hi + m * (long)KAUG + i;
#pragma unroll
    for (int c = 0; c < 9; ++c) oh[(long)c * 1024] = f2bf(ch[c]);
    if (lo) {
        unsigned short* ol = lo + m * (long)KAUG + i;
#pragma unroll
        for (int c = 0; c < 9; ++c) {
            unsigned short h = f2bf(ch[c]);
            ol[(long)c * 1024] = f2bf(ch[c] - bf2f(h));
        }
    }
}

// ---------------- pack weights -> augmented bf16: [base | spline*scaler]
__global__ __launch_bounds__(256) void pack_w(const float* __restrict__ base,
                                              const float* __restrict__ spl,
                                              const float* __restrict__ scal,
                                              unsigned short* __restrict__ hi,
                                              unsigned short* __restrict__ lo,
                                              long total) {
    long idx = (long)blockIdx.x * 256 + threadIdx.x;
    if (idx >= total) return;
    long n = idx >> 10; int i = (int)(idx & 1023);
    float sc = scal[idx];
    const float4* s4 = (const float4*)(spl + idx * 8);
    float4 s0 = s4[0], s1 = s4[1];
    float ch[9] = {base[idx], s0.x * sc, s0.y * sc, s0.z * sc, s0.w * sc,
                   s1.x * sc, s1.y * sc, s1.z * sc, s1.w * sc};
    unsigned short* oh = hi + n * (long)KAUG + i;
#pragma unroll
    for (int c = 0; c < 9; ++c) oh[(long)c * 1024] = f2bf(ch[c]);
    if (lo) {
        unsigned short* ol = lo + n * (long)KAUG + i;
#pragma unroll
        for (int c = 0; c < 9; ++c) {
            unsigned short h = f2bf(ch[c]);
            ol[(long)c * 1024] = f2bf(ch[c] - bf2f(h));
        }
    }
}

// ---------------- g = g1*g2 then bspline-pack -> augmented bf16 (hi only)
__global__ __launch_bounds__(256) void mul_pack(const float* __restrict__ g12,
                                                unsigned short* __restrict__ hi) {
    long idx = (long)blockIdx.x * 256 + threadIdx.x;   // T_TOK*1024 exact
    long m = idx >> 10; int i = (int)(idx & 1023);
    float v = g12[m * 2048 + i] * g12[m * 2048 + 1024 + i];
    float ch[9];
    ch[0] = v * sigmoidf_(v);
    bspline8(v, ch + 1);
    unsigned short* oh = hi + m * (long)KAUG + i;
#pragma unroll
    for (int c = 0; c < 9; ++c) oh[(long)c * 1024] = f2bf(ch[c]);
}

// ---------------- MFMA GEMM: C(M,N) = A(M,K) bf16 @ Bt(N,K)^T bf16, K=KAUG
// BM=64, BN=128, BK=32, 4 waves (2x2), wave tile 32x64, m97 2-barrier structure,
// global_load_lds width-16 staging. split!=0: 3-pass hi/lo (fp32-class accuracy).
// mode 0: C = acc ; mode 1: C += rowScale[row*4] * acc
#define GLD(gp, lp) __builtin_amdgcn_global_load_lds( \
    (const __attribute__((address_space(1))) void*)(gp), \
    (__attribute__((address_space(3))) void*)(lp), 16, 0, 0)

__global__ __launch_bounds__(256) void mfma_gemm(const unsigned short* __restrict__ Ah,
                                                 const unsigned short* __restrict__ Al,
                                                 const unsigned short* __restrict__ Bh,
                                                 const unsigned short* __restrict__ Bl,
                                                 float* __restrict__ C,
                                                 const float* __restrict__ rowScale,
                                                 int N, int split, int mode) {
    __shared__ __align__(16) unsigned short AsH[64 * 32];
    __shared__ __align__(16) unsigned short BsH[128 * 32];
    __shared__ __align__(16) unsigned short AsL[64 * 32];
    __shared__ __align__(16) unsigned short BsL[128 * 32];
    const int bm = blockIdx.y * 64, bn = blockIdx.x * 128;
    const int tid = threadIdx.x;
    const int w = tid >> 6, l = tid & 63;
    const int wr = w >> 1, wc = w & 1;
    const int half = l >> 4, lr = l & 15;
    const size_t rb = (size_t)KAUG * 2;   // row bytes

    // staging addresses (linear LDS dest; per-lane global src)
    const int oa = tid * 16;                       // A tile: 64*64B = 4KB, 1 issue/thr
    const int raA = oa >> 6, caA = oa & 63;
    const char* Agh = (const char*)Ah + (size_t)(bm + raA) * rb + caA;
    const char* Agl = split ? (const char*)Al + (size_t)(bm + raA) * rb + caA : nullptr;
    const int ob0 = w * 2048 + l * 16, ob1 = ob0 + 1024;   // B tile: 8KB, 2 issues/thr
    const int rb0 = ob0 >> 6, cb0 = ob0 & 63;
    const int rb1 = ob1 >> 6, cb1 = ob1 & 63;
    const char* Bgh0 = (const char*)Bh + (size_t)(bn + rb0) * rb + cb0;
    const char* Bgh1 = (const char*)Bh + (size_t)(bn + rb1) * rb + cb1;
    const char* Bgl0 = split ? (const char*)Bl + (size_t)(bn + rb0) * rb + cb0 : nullptr;
    const char* Bgl1 = split ? (const char*)Bl + (size_t)(bn + rb1) * rb + cb1 : nullptr;

    f32x4 acc[2][4] = {};
    for (int k0 = 0; k0 < KAUG; k0 += 32) {
        const size_t kb = (size_t)k0 * 2;
        GLD(Agh + kb, (char*)AsH + w * 1024);
        GLD(Bgh0 + kb, (char*)BsH + w * 2048);
        GLD(Bgh1 + kb, (char*)BsH + w * 2048 + 1024);
        if (split) {
            GLD(Agl + kb, (char*)AsL + w * 1024);
            GLD(Bgl0 + kb, (char*)BsL + w * 2048);
            GLD(Bgl1 + kb, (char*)BsL + w * 2048 + 1024);
        }
        __syncthreads();   // compiler drains vmcnt before s_barrier
        bf16x8 ah[2], bh[4];
#pragma unroll
        for (int mi = 0; mi < 2; ++mi)
            ah[mi] = *(const bf16x8*)&AsH[(wr * 32 + mi * 16 + lr) * 32 + half * 8];
#pragma unroll
        for (int ni = 0; ni < 4; ++ni)
            bh[ni] = *(const bf16x8*)&BsH[(wc * 64 + ni * 16 + lr) * 32 + half * 8];
#pragma unroll
        for (int mi = 0; mi < 2; ++mi)
#pragma unroll
            for (int ni = 0; ni < 4; ++ni)
                acc[mi][ni] = __builtin_amdgcn_mfma_f32_16x16x32_bf16(ah[mi], bh[ni],
                                                                      acc[mi][ni], 0, 0, 0);
        if (split) {
            bf16x8 al[2], bl[4];
#pragma unroll
            for (int mi = 0; mi < 2; ++mi)
                al[mi] = *(const bf16x8*)&AsL[(wr * 32 + mi * 16 + lr) * 32 + half * 8];
#pragma unroll
            for (int ni = 0; ni < 4; ++ni)
                bl[ni] = *(const bf16x8*)&BsL[(wc * 64 + ni * 16 + lr) * 32 + half * 8];
#pragma unroll
            for (int mi = 0; mi < 2; ++mi)
#pragma unroll
                for (int ni = 0; ni < 4; ++ni) {
                    acc[mi][ni] = __builtin_amdgcn_mfma_f32_16x16x32_bf16(ah[mi], bl[ni],
                                                                          acc[mi][ni], 0, 0, 0);
                    acc[mi][ni] = __builtin_amdgcn_mfma_f32_16x16x32_bf16(al[mi], bh[ni],
                                                                          acc[mi][ni], 0, 0, 0);
                }
        }
        __syncthreads();
    }
    // epilogue: C/D layout col=lane&15, row=(lane>>4)*4+reg (m89-verified)
#pragma unroll
    for (int mi = 0; mi < 2; ++mi)
#pragma unroll
        for (int r = 0; r < 4; ++r) {
            int row = bm + wr * 32 + mi * 16 + half * 4 + r;
            float rs = (mode == 1) ? rowScale[(size_t)row * 4] : 0.0f;
#pragma unroll
            for (int ni = 0; ni < 4; ++ni) {
                int col = bn + wc * 64 + ni * 16 + lr;
                size_t ix = (size_t)row * N + col;
                if (mode == 0) C[ix] = acc[mi][ni][r];
                else           C[ix] += rs * acc[mi][ni][r];
            }
        }
}

// ---------------- out-proj: C = res + bias + A @ Bw^T (fp32 SIMT)
__global__ __launch_bounds__(256) void gemm_bias_res(const float* __restrict__ A,
                                                     const float* __restrict__ Bw,
                                                     const float* __restrict__ bias,
                                                     const float* __restrict__ res,
                                                     float* __restrict__ C) {
    __shared__ float As[16][64];
    __shared__ float Bs[16][64];
    const int bm = blockIdx.y * 64, bn = blockIdx.x * 64;
    const int tid = threadIdx.x;
    const int tx = tid & 15, ty = tid >> 4;
    float acc[4][4] = {};
    for (int k0 = 0; k0 < 1024; k0 += 16) {
        for (int e = tid; e < 1024; e += 256) {
            int r = e >> 4, kk = e & 15;
            As[kk][r] = A[(long)(bm + r) * 1024 + k0 + kk];
            Bs[kk][r] = Bw[(long)(bn + r) * 1024 + k0 + kk];
        }
        __syncthreads();
#pragma unroll
        for (int k = 0; k < 16; ++k) {
            float4 a = *(const float4*)&As[k][ty * 4];
            float4 b = *(const float4*)&Bs[k][tx * 4];
            float av[4] = {a.x, a.y, a.z, a.w};
            float bv[4] = {b.x, b.y, b.z, b.w};
#pragma unroll
            for (int i = 0; i < 4; ++i)
#pragma unroll
                for (int j = 0; j < 4; ++j) acc[i][j] = fmaf(av[i], bv[j], acc[i][j]);
        }
        __syncthreads();
    }
#pragma unroll
    for (int i = 0; i < 4; ++i) {
        long m = bm + ty * 4 + i;
#pragma unroll
        for (int j = 0; j < 4; ++j) {
            long n = bn + tx * 4 + j;
            C[m * 1024 + n] = res[m * 1024 + n] + bias[n] + acc[i][j];
        }
    }
}

// ---------------- RoPE in-place
__global__ __launch_bounds__(256) void rope_kernel(float* __restrict__ qkv,
                                                   const float* __restrict__ cs,
                                                   const float* __restrict__ sn) {
    int idx = blockIdx.x * 256 + threadIdx.x;
    if (idx >= T_TOK * NHEAD * 32) return;
    int p = idx & 31;
    int n = (idx >> 5) & 15;
    int t = idx >> 9;
    int s = t & (S_SEQ - 1);
    float c = cs[s * 32 + p], si = sn[s * 32 + p];
    long base = (long)t * 3072 + n * 192;
    float re = qkv[base + 2 * p], im = qkv[base + 2 * p + 1];
    qkv[base + 2 * p]     = re * c - im * si;
    qkv[base + 2 * p + 1] = re * si + im * c;
    re = qkv[base + 64 + 2 * p]; im = qkv[base + 64 + 2 * p + 1];
    qkv[base + 64 + 2 * p]     = re * c - im * si;
    qkv[base + 64 + 2 * p + 1] = re * si + im * c;
}

// ---------------- flash attention fp32
__global__ __launch_bounds__(256) void attn_kernel(const float* __restrict__ qkv,
                                                   float* __restrict__ ctx) {
    const int qb = blockIdx.x * 32;
    const int h = blockIdx.y, b = blockIdx.z;
    __shared__ float Qs[32][64];
    __shared__ float Ks[64][64];
    __shared__ float Vs[64][64];
    __shared__ float Ss[32][64];
    const int tid = threadIdx.x;
    const int q = tid >> 3, g = tid & 7;
    for (int e = tid; e < 32 * 64; e += 256) {
        int r = e >> 6, d = e & 63;
        Qs[r][d] = qkv[(long)(b * S_SEQ + qb + r) * 3072 + h * 192 + d];
    }
    float m_run = -1e30f, l_run = 0.0f;
    float acc[8] = {};
    for (int k0 = 0; k0 < S_SEQ; k0 += 64) {
        for (int e = tid; e < 64 * 64; e += 256) {
            int r = e >> 6, d = e & 63;
            long base = (long)(b * S_SEQ + k0 + r) * 3072 + h * 192;
            Ks[r][d] = qkv[base + 64 + d];
            Vs[r][d] = qkv[base + 128 + d];
        }
        __syncthreads();
        float s[8];
#pragma unroll
        for (int kk = 0; kk < 8; ++kk) {
            int k = g * 8 + kk;
            float dot = 0.0f;
#pragma unroll
            for (int d = 0; d < 64; ++d) dot = fmaf(Qs[q][d], Ks[k][d], dot);
            s[kk] = dot * 0.125f;
        }
        float mx = s[0];
#pragma unroll
        for (int kk = 1; kk < 8; ++kk) mx = fmaxf(mx, s[kk]);
#pragma unroll
        for (int w = 1; w < 8; w <<= 1) mx = fmaxf(mx, __shfl_xor(mx, w, 64));
        float m_new = fmaxf(m_run, mx);
        float p[8], ls = 0.0f;
#pragma unroll
        for (int kk = 0; kk < 8; ++kk) { p[kk] = __expf(s[kk] - m_new); ls += p[kk]; }
#pragma unroll
        for (int w = 1; w < 8; w <<= 1) ls += __shfl_xor(ls, w, 64);
        float alpha = __expf(m_run - m_new);
        l_run = l_run * alpha + ls;
        m_run = m_new;
#pragma unroll
        for (int kk = 0; kk < 8; ++kk) Ss[q][g * 8 + kk] = p[kk];
        __syncthreads();
#pragma unroll
        for (int j = 0; j < 8; ++j) acc[j] *= alpha;
        for (int k = 0; k < 64; ++k) {
            float pv = Ss[q][k];
#pragma unroll
            for (int j = 0; j < 8; ++j) acc[j] = fmaf(pv, Vs[k][g * 8 + j], acc[j]);
        }
        __syncthreads();
    }
    float inv = 1.0f / l_run;
#pragma unroll
    for (int j = 0; j < 8; ++j)
        ctx[(long)(b * S_SEQ + qb + q) * H_DIM + h * 64 + g * 8 + j] = acc[j] * inv;
}

// ---------------- gate: top-2 softmax weights (zeros elsewhere)
__global__ __launch_bounds__(256) void gate_kernel(const float* __restrict__ h2,
                                                   const float* __restrict__ gate_w,
                                                   float* __restrict__ gw) {
    long t = blockIdx.x;
    float sum[4] = {0, 0, 0, 0};
    for (int i = threadIdx.x; i < H_DIM; i += 256) {
        float v = h2[t * H_DIM + i];
#pragma unroll
        for (int e = 0; e < 4; ++e) sum[e] = fmaf(v, gate_w[e * H_DIM + i], sum[e]);
    }
#pragma unroll
    for (int w = 1; w < 64; w <<= 1)
#pragma unroll
        for (int e = 0; e < 4; ++e) sum[e] += __shfl_xor(sum[e], w, 64);
    __shared__ float part[4][4];
    if ((threadIdx.x & 63) == 0)
#pragma unroll
        for (int e = 0; e < 4; ++e) part[e][threadIdx.x >> 6] = sum[e];
    __syncthreads();
    if (threadIdx.x == 0) {
        float lg[4];
#pragma unroll
        for (int e = 0; e < 4; ++e) lg[e] = part[e][0] + part[e][1] + part[e][2] + part[e][3];
        int i0 = 0;
        for (int e = 1; e < 4; ++e) if (lg[e] > lg[i0]) i0 = e;
        int i1 = -1;
        for (int e = 0; e < 4; ++e) if (e != i0 && (i1 < 0 || lg[e] > lg[i1])) i1 = e;
        float mx = fmaxf(lg[i0], lg[i1]);
        float e0 = __expf(lg[i0] - mx), e1 = __expf(lg[i1] - mx);
        float inv = 1.0f / (e0 + e1);
        float o[4] = {0, 0, 0, 0};
        o[i0] = e0 * inv; o[i1] = e1 * inv;
#pragma unroll
        for (int e = 0; e < 4; ++e) gw[t * 4 + e] = o[e];
    }
}

// ---------------- fallback-only kernels (round-0 fp32 path, used if ws too small)
#define KI 8
#define BKK 72
__global__ __launch_bounds__(256) void kan_gemm(const float* __restrict__ Act,
                                                const float* __restrict__ baseW,
                                                const float* __restrict__ splW,
                                                const float* __restrict__ scal,
                                                float* __restrict__ C,
                                                const float* __restrict__ rowScale,
                                                int rsStride, int N, int mode) {
    __shared__ float As[BKK][64];
    __shared__ float Bs[BKK][64];
    const int bm = blockIdx.y * 64;
    const int bn = blockIdx.x * 64;
    const int tid = threadIdx.x;
    const int tx = tid & 15, ty = tid >> 4;
    float acc[4][4] = {};
    for (int i0 = 0; i0 < H_DIM; i0 += KI) {
        for (int e = tid; e < 64 * KI; e += 256) {
            int m = e >> 3, ii = e & 7;
            float xv = Act[(long)(bm + m) * H_DIM + i0 + ii];
            float sp[8];
            bspline8(xv, sp);
            As[ii * 9][m] = xv * sigmoidf_(xv);
#pragma unroll
            for (int c = 0; c < 8; ++c) As[ii * 9 + 1 + c][m] = sp[c];
        }
        for (int e = tid; e < 64 * KI; e += 256) {
            int n = e >> 3, ii = e & 7;
            long w = (long)(bn + n) * H_DIM + i0 + ii;
            float sc = scal[w];
            Bs[ii * 9][n] = baseW[w];
            const float4* sp4 = (const float4*)(splW + w * 8);
            float4 s0 = sp4[0], s1 = sp4[1];
            Bs[ii * 9 + 1][n] = s0.x * sc; Bs[ii * 9 + 2][n] = s0.y * sc;
            Bs[ii * 9 + 3][n] = s0.z * sc; Bs[ii * 9 + 4][n] = s0.w * sc;
            Bs[ii * 9 + 5][n] = s1.x * sc; Bs[ii * 9 + 6][n] = s1.y * sc;
            Bs[ii * 9 + 7][n] = s1.z * sc; Bs[ii * 9 + 8][n] = s1.w * sc;
        }
        __syncthreads();
#pragma unroll 8
        for (int k = 0; k < BKK; ++k) {
            float4 a = *(const float4*)&As[k][ty * 4];
            float4 b = *(const float4*)&Bs[k][tx * 4];
            float av[4] = {a.x, a.y, a.z, a.w};
            float bv[4] = {b.x, b.y, b.z, b.w};
#pragma unroll
            for (int i = 0; i < 4; ++i)
#pragma unroll
                for (int j = 0; j < 4; ++j) acc[i][j] = fmaf(av[i], bv[j], acc[i][j]);
        }
        __syncthreads();
    }
#pragma unroll
    for (int i = 0; i < 4; ++i) {
        long m = bm + ty * 4 + i;
        float rs = (mode == 1) ? rowScale[m * rsStride] : 0.0f;
#pragma unroll
        for (int j = 0; j < 4; ++j) {
            long idx = m * (long)N + bn + tx * 4 + j;
            if (mode == 0) C[idx] = acc[i][j];
            else           C[idx] += rs * acc[i][j];
        }
    }
}

__global__ __launch_bounds__(256) void mul_kernel(const float* __restrict__ a,
                                                  const float* __restrict__ b,
                                                  float* __restrict__ c, int n) {
    int i = blockIdx.x * 256 + threadIdx.x;
    if (i < n) c[i] = a[i] * b[i];
}

extern "C" void kernel_launch(void* const* d_in, const int* in_sizes, int n_in,
                              void* d_out, int out_size, void* d_ws, size_t ws_size,
                              hipStream_t stream) {
    const float* x          = (const float*)d_in[0];
    const float* rot_cos    = (const float*)d_in[1];
    const float* rot_sin    = (const float*)d_in[2];
    const float* norm1_w    = (const float*)d_in[3];
    const float* norm2_w    = (const float*)d_in[4];
    const float* qkv_base   = (const float*)d_in[5];
    const float* qkv_spline = (const float*)d_in[6];
    const float* qkv_scaler = (const float*)d_in[7];
    const float* out_w      = (const float*)d_in[8];
    const float* out_b      = (const float*)d_in[9];
    const float* gate_w     = (const float*)d_in[10];
    const float* w1_base    = (const float*)d_in[11];
    const float* w1_spline  = (const float*)d_in[12];
    const float* w1_scaler  = (const float*)d_in[13];
    const float* w2_base    = (const float*)d_in[14];
    const float* w2_spline  = (const float*)d_in[15];
    const float* w2_scaler  = (const float*)d_in[16];
    const float* w3_base    = (const float*)d_in[17];
    const float* w3_spline  = (const float*)d_in[18];
    const float* w3_scaler  = (const float*)d_in[19];
    float* out = (float*)d_out;

    // ---- fast-path workspace layout (~236 MiB) ----
    const size_t SZ_AUG  = (size_t)T_TOK * KAUG * 2;   // 37,748,736
    const size_t SZ_WQ   = (size_t)3072 * KAUG * 2;    // 56,623,104
    const size_t SZ_QKV  = (size_t)T_TOK * 3072 * 4;
    const size_t SZ_G12  = (size_t)T_TOK * 2048 * 4;
    const size_t SZ_TOK  = (size_t)T_TOK * H_DIM * 4;
    const size_t NEED = 2 * SZ_AUG + 2 * SZ_WQ + SZ_QKV + SZ_G12 + 2 * SZ_TOK + 32768;

    if (ws_size >= NEED) {
        char* p = (char*)d_ws;
        unsigned short* A_hi = (unsigned short*)p; p += SZ_AUG;
        unsigned short* A_lo = (unsigned short*)p; p += SZ_AUG;   // reused as G_hi in MoE
        unsigned short* W1b  = (unsigned short*)p; p += SZ_WQ;
        unsigned short* W2b  = (unsigned short*)p; p += SZ_WQ;
        float* qkv = (float*)p; p += SZ_QKV;
        float* g12 = (float*)p; p += SZ_G12;
        float* ctx = (float*)p; p += SZ_TOK;
        float* tok = (float*)p; p += SZ_TOK;   // hn, later h2
        float* gw  = (float*)p; p += 32768;
        unsigned short* G_hi = A_lo;

        // attention branch: split-bf16 (hi/lo) to keep gate logits fp32-accurate
        rmsnorm_kernel<<<T_TOK, 256, 0, stream>>>(x, norm1_w, tok);
        pack_act<<<(T_TOK * 1024) / 256, 256, 0, stream>>>(tok, A_hi, A_lo);
        pack_w<<<(3072 * 1024) / 256, 256, 0, stream>>>(qkv_base, qkv_spline, qkv_scaler,
                                                        W1b, W2b, (long)3072 * 1024);
        mfma_gemm<<<dim3(3072 / 128, T_TOK / 64), 256, 0, stream>>>(
            A_hi, A_lo, W1b, W2b, qkv, nullptr, 3072, 1, 0);
        rope_kernel<<<(T_TOK * NHEAD * 32) / 256, 256, 0, stream>>>(qkv, rot_cos, rot_sin);
        attn_kernel<<<dim3(S_SEQ / 32, NHEAD, 2), 256, 0, stream>>>(qkv, ctx);
        gemm_bias_res<<<dim3(1024 / 64, T_TOK / 64), 256, 0, stream>>>(ctx, out_w, out_b, x, out);
        rmsnorm_kernel<<<T_TOK, 256, 0, stream>>>(out, norm2_w, tok);
        gate_kernel<<<T_TOK, 256, 0, stream>>>(tok, gate_w, gw);

        // MoE: plain bf16 (downstream of gate decision -> smooth error only)
        pack_act<<<(T_TOK * 1024) / 256, 256, 0, stream>>>(tok, A_hi, nullptr);
        for (int e = 0; e < E_EXP; ++e) {
            long wo = (long)e * DFF_ * H_DIM;
            pack_w<<<(1024 * 1024) / 256, 256, 0, stream>>>(
                w1_base + wo, w1_spline + wo * 8, w1_scaler + wo, W1b, nullptr,
                (long)1024 * 1024);
            pack_w<<<(1024 * 1024) / 256, 256, 0, stream>>>(
                w2_base + wo, w2_spline + wo * 8, w2_scaler + wo,
                W1b + (size_t)1024 * KAUG, nullptr, (long)1024 * 1024);
            mfma_gemm<<<dim3(2048 / 128, T_TOK / 64), 256, 0, stream>>>(
                A_hi, nullptr, W1b, nullptr, g12, nullptr, 2048, 0, 0);
            mul_pack<<<(T_TOK * 1024) / 256, 256, 0, stream>>>(g12, G_hi);
            pack_w<<<(1024 * 1024) / 256, 256, 0, stream>>>(
                w3_base + wo, w3_spline + wo * 8, w3_scaler + wo, W2b, nullptr,
                (long)1024 * 1024);
            mfma_gemm<<<dim3(1024 / 128, T_TOK / 64), 256, 0, stream>>>(
                G_hi, nullptr, W2b, nullptr, out, gw + e, 1024, 0, 1);
        }
        return;
    }

    // ---- fallback: round-0 fp32 path (fits ~65 MB) ----
    char* ws = (char*)d_ws;
    float* hn  = (float*)ws; ws += (size_t)T_TOK * H_DIM * 4;
    float* qkv = (float*)ws; ws += (size_t)T_TOK * 3072 * 4;
    float* ctx = (float*)ws; ws += (size_t)T_TOK * H_DIM * 4;
    float* h2  = (float*)ws; ws += (size_t)T_TOK * H_DIM * 4;
    float* gw  = (float*)ws; ws += (size_t)T_TOK * E_EXP * 4;
    float* g1  = (float*)ws; ws += (size_t)T_TOK * DFF_ * 4;
    float* g2  = (float*)ws; ws += (size_t)T_TOK * DFF_ * 4;
    float* gm  = (float*)ws; ws += (size_t)T_TOK * DFF_ * 4;

    rmsnorm_kernel<<<T_TOK, 256, 0, stream>>>(x, norm1_w, hn);
    dim3 gq(3072 / 64, T_TOK / 64);
    kan_gemm<<<gq, 256, 0, stream>>>(hn, qkv_base, qkv_spline, qkv_scaler, qkv,
                                     nullptr, 0, 3072, 0);
    rope_kernel<<<(T_TOK * NHEAD * 32) / 256, 256, 0, stream>>>(qkv, rot_cos, rot_sin);
    dim3 ga(S_SEQ / 32, NHEAD, 2);
    attn_kernel<<<ga, 256, 0, stream>>>(qkv, ctx);
    dim3 go(1024 / 64, T_TOK / 64);
    gemm_bias_res<<<go, 256, 0, stream>>>(ctx, out_w, out_b, x, out);
    rmsnorm_kernel<<<T_TOK, 256, 0, stream>>>(out, norm2_w, h2);
    gate_kernel<<<T_TOK, 256, 0, stream>>>(h2, gate_w, gw);
    dim3 ge(1024 / 64, T_TOK / 64);
    for (int e = 0; e < E_EXP; ++e) {
        long wo = (long)e * DFF_ * H_DIM;
        kan_gemm<<<ge, 256, 0, stream>>>(h2, w1_base + wo, w1_spline + wo * 8,
                                         w1_scaler + wo, g1, nullptr, 0, DFF_, 0);
        kan_gemm<<<ge, 256, 0, stream>>>(h2, w2_base + wo, w2_spline + wo * 8,
                                         w2_scaler + wo, g2, nullptr, 0, DFF_, 0);
        mul_kernel<<<(T_TOK * DFF_) / 256, 256, 0, stream>>>(g1, g2, gm, T_TOK * DFF_);
        kan_gemm<<<ge, 256, 0, stream>>>(gm, w3_base + wo, w3_spline + wo * 8,
                                         w3_scaler + wo, out, gw + e, E_EXP, H_DIM, 1);
    }
}

// Round 3
// 2194.501 us; speedup vs baseline: 5.4989x; 1.1855x over previous
//
#include <hip/hip_runtime.h>
#include <hip/hip_bf16.h>

// KANBlock: B=2,S=1024,H=1024,NH=16,HD=64,DFF=1024,E=4,TOPK=2, NB=8 spline bases
#define T_TOK 2048
#define H_DIM 1024
#define S_SEQ 1024
#define NHEAD 16
#define E_EXP 4
#define DFF_  1024
#define KAUG  9216   // 9*1024 augmented K (k = c*1024 + i; c=0 silu, c=1..8 splines)

typedef __bf16 bf16x8 __attribute__((ext_vector_type(8)));
typedef float  f32x4  __attribute__((ext_vector_type(4)));
typedef unsigned short ushort_t;

__device__ __forceinline__ float sigmoidf_(float x) { return 1.0f / (1.0f + __expf(-x)); }

__device__ __forceinline__ unsigned short f2bf(float f) {   // RNE f32 -> bf16 bits
    unsigned int u = __float_as_uint(f);
    u = (u + 0x7fffu + ((u >> 16) & 1u)) >> 16;
    return (unsigned short)u;
}
__device__ __forceinline__ float bf2f(unsigned short h) {
    return __uint_as_float(((unsigned int)h) << 16);
}

// Cubic B-spline bases, matches reference b_splines() (verified round 0)
__device__ __forceinline__ void bspline8(float x, float* o) {
    float b[11];
#pragma unroll
    for (int m = 0; m < 11; ++m) {
        float g0 = 0.4f * (float)(m - 3) - 1.0f;
        float g1 = 0.4f * (float)(m - 2) - 1.0f;
        b[m] = (x >= g0 && x < g1) ? 1.0f : 0.0f;
    }
#pragma unroll
    for (int j = 1; j <= 3; ++j) {
        float inv = 1.0f / (0.4f * (float)j);
#pragma unroll
        for (int m = 0; m + j < 11; ++m) {
            float gm   = 0.4f * (float)(m - 3) - 1.0f;
            float gmj1 = 0.4f * (float)(m + j - 2) - 1.0f;
            b[m] = ((x - gm) * b[m] + (gmj1 - x) * b[m + 1]) * inv;
        }
    }
#pragma unroll
    for (int c = 0; c < 8; ++c) o[c] = b[c];
}

// ---------------- RMSNorm
__global__ __launch_bounds__(256) void rmsnorm_kernel(const float* __restrict__ x,
                                                      const float* __restrict__ w,
                                                      float* __restrict__ out) {
    long t = blockIdx.x;
    float4 v = ((const float4*)(x + t * H_DIM))[threadIdx.x];
    float ss = v.x * v.x + v.y * v.y + v.z * v.z + v.w * v.w;
#pragma unroll
    for (int m = 1; m < 64; m <<= 1) ss += __shfl_xor(ss, m, 64);
    __shared__ float wsum[4];
    if ((threadIdx.x & 63) == 0) wsum[threadIdx.x >> 6] = ss;
    __syncthreads();
    ss = wsum[0] + wsum[1] + wsum[2] + wsum[3];
    float sc = rsqrtf(ss * (1.0f / (float)H_DIM) + 1e-6f);
    float4 wv = ((const float4*)w)[threadIdx.x];
    float4 r;
    r.x = v.x * sc * wv.x; r.y = v.y * sc * wv.y;
    r.z = v.z * sc * wv.z; r.w = v.w * sc * wv.w;
    ((float4*)(out + t * H_DIM))[threadIdx.x] = r;
}

// ---------------- pack activations -> augmented bf16 (hi, optional lo)
__global__ __launch_bounds__(256) void pack_act(const float* __restrict__ act,
                                                ushort_t* __restrict__ hi,
                                                ushort_t* __restrict__ lo) {
    long idx = (long)blockIdx.x * 256 + threadIdx.x;
    long m = idx >> 10; int i = (int)(idx & 1023);
    float v = act[idx];
    float ch[9];
    ch[0] = v * sigmoidf_(v);
    bspline8(v, ch + 1);
    ushort_t* oh = hi + m * (long)KAUG + i;
#pragma unroll
    for (int c = 0; c < 9; ++c) oh[(long)c * 1024] = f2bf(ch[c]);
    if (lo) {
        ushort_t* ol = lo + m * (long)KAUG + i;
#pragma unroll
        for (int c = 0; c < 9; ++c) {
            unsigned short h = f2bf(ch[c]);
            ol[(long)c * 1024] = f2bf(ch[c] - bf2f(h));
        }
    }
}

// ---------------- pack weights -> augmented bf16: [base | spline*scaler]
__global__ __launch_bounds__(256) void pack_w(const float* __restrict__ base,
                                              const float* __restrict__ spl,
                                              const float* __restrict__ scal,
                                              ushort_t* __restrict__ hi,
                                              ushort_t* __restrict__ lo,
                                              long total) {
    long idx = (long)blockIdx.x * 256 + threadIdx.x;
    if (idx >= total) return;
    long n = idx >> 10; int i = (int)(idx & 1023);
    float sc = scal[idx];
    const float4* s4 = (const float4*)(spl + idx * 8);
    float4 s0 = s4[0], s1 = s4[1];
    float ch[9] = {base[idx], s0.x * sc, s0.y * sc, s0.z * sc, s0.w * sc,
                   s1.x * sc, s1.y * sc, s1.z * sc, s1.w * sc};
    ushort_t* oh = hi + n * (long)KAUG + i;
#pragma unroll
    for (int c = 0; c < 9; ++c) oh[(long)c * 1024] = f2bf(ch[c]);
    if (lo) {
        ushort_t* ol = lo + n * (long)KAUG + i;
#pragma unroll
        for (int c = 0; c < 9; ++c) {
            unsigned short h = f2bf(ch[c]);
            ol[(long)c * 1024] = f2bf(ch[c] - bf2f(h));
        }
    }
}

// ---------------- g = g1*g2 then bspline-pack -> augmented bf16 (hi only)
__global__ __launch_bounds__(256) void mul_pack(const float* __restrict__ g12,
                                                ushort_t* __restrict__ hi) {
    long idx = (long)blockIdx.x * 256 + threadIdx.x;
    long m = idx >> 10; int i = (int)(idx & 1023);
    float v = g12[m * 2048 + i] * g12[m * 2048 + 1024 + i];
    float ch[9];
    ch[0] = v * sigmoidf_(v);
    bspline8(v, ch + 1);
    ushort_t* oh = hi + m * (long)KAUG + i;
#pragma unroll
    for (int c = 0; c < 9; ++c) oh[(long)c * 1024] = f2bf(ch[c]);
}

// ---------------- elementwise f32 -> bf16 hi/lo split
__global__ __launch_bounds__(256) void split_pack(const float* __restrict__ in,
                                                  ushort_t* __restrict__ hi,
                                                  ushort_t* __restrict__ lo, long n) {
    long i = (long)blockIdx.x * 256 + threadIdx.x;
    if (i >= n) return;
    float v = in[i];
    unsigned short h = f2bf(v);
    hi[i] = h;
    lo[i] = f2bf(v - bf2f(h));
}

// =====================================================================
// MFMA GEMM (m97 structure): C(M,N) = A(M,K) @ B(N,K)^T, bf16 ops fp32 acc.
// BM x 128 tile, BK=32, 4 waves (2x2), wave tile (BM/2) x 64.
// 2-bit XOR chunk swizzle on LDS (pre-swizzled global source, rule #21).
// SPLIT: 3-pass hi/lo (fp32-class). MODE 0: C=acc; 1: C+=rowScale[row*4]*acc;
// 2: C = res[row*N+col] + bias[col] + acc.
// =====================================================================
#define GLD(gp, lp) __builtin_amdgcn_global_load_lds( \
    (const __attribute__((address_space(1))) void*)(gp), \
    (__attribute__((address_space(3))) void*)(lp), 16, 0, 0)

template<int BM, int SPLIT, int MODE>
__global__ __launch_bounds__(256) void mfma_gemm2(const ushort_t* __restrict__ Ah,
                                                  const ushort_t* __restrict__ Al,
                                                  const ushort_t* __restrict__ Bh,
                                                  const ushort_t* __restrict__ Bl,
                                                  float* __restrict__ C,
                                                  const float* __restrict__ rowScale,
                                                  const float* __restrict__ bias,
                                                  const float* __restrict__ res,
                                                  int N, int K) {
    constexpr int NM = BM / 32;            // A fragments per wave (4 or 2)
    __shared__ __align__(16) ushort_t AsH[BM * 32];
    __shared__ __align__(16) ushort_t BsH[128 * 32];
    __shared__ __align__(16) ushort_t AsL[SPLIT ? BM * 32 : 16];
    __shared__ __align__(16) ushort_t BsL[SPLIT ? 128 * 32 : 16];
    const int bm = blockIdx.y * BM, bn = blockIdx.x * 128;
    const int tid = threadIdx.x;
    const int w = tid >> 6, l = tid & 63;
    const int wr = w >> 1, wc = w & 1;
    const int half = l >> 4, lr = l & 15;
    const size_t rb = (size_t)K * 2;       // row bytes

    // staging source pointers (swizzled chunk within 64B row)
    const int rowB0 = w * 32 + (l >> 2), rowB1 = rowB0 + 16;   // B rows (128)
    const int cch = l & 3;
    const char* gB0 = (const char*)Bh + (size_t)(bn + rowB0) * rb + ((cch ^ (rowB0 & 3)) * 16);
    const char* gB1 = (const char*)Bh + (size_t)(bn + rowB1) * rb + ((cch ^ (rowB1 & 3)) * 16);
    const char* gB0l = SPLIT ? (const char*)Bl + (size_t)(bn + rowB0) * rb + ((cch ^ (rowB0 & 3)) * 16) : nullptr;
    const char* gB1l = SPLIT ? (const char*)Bl + (size_t)(bn + rowB1) * rb + ((cch ^ (rowB1 & 3)) * 16) : nullptr;
    int rowA0, rowA1;
    if constexpr (BM == 128) { rowA0 = w * 32 + (l >> 2); rowA1 = rowA0 + 16; }
    else                     { rowA0 = w * 16 + (l >> 2); rowA1 = 0; }
    const char* gA0 = (const char*)Ah + (size_t)(bm + rowA0) * rb + ((cch ^ (rowA0 & 3)) * 16);
    const char* gA1 = (BM == 128) ? (const char*)Ah + (size_t)(bm + rowA1) * rb + ((cch ^ (rowA1 & 3)) * 16) : nullptr;
    const char* gA0l = SPLIT ? (const char*)Al + (size_t)(bm + rowA0) * rb + ((cch ^ (rowA0 & 3)) * 16) : nullptr;
    const char* gA1l = (SPLIT && BM == 128) ? (const char*)Al + (size_t)(bm + rowA1) * rb + ((cch ^ (rowA1 & 3)) * 16) : nullptr;

    f32x4 acc[NM][4] = {};
    for (int k0 = 0; k0 < K; k0 += 32) {
        const size_t kb = (size_t)k0 * 2;
        GLD(gA0 + kb, (char*)AsH + ((BM == 128) ? w * 2048 : w * 1024) + l * 16);
        if constexpr (BM == 128) GLD(gA1 + kb, (char*)AsH + w * 2048 + 1024 + l * 16);
        GLD(gB0 + kb, (char*)BsH + w * 2048 + l * 16);
        GLD(gB1 + kb, (char*)BsH + w * 2048 + 1024 + l * 16);
        if constexpr (SPLIT) {
            GLD(gA0l + kb, (char*)AsL + ((BM == 128) ? w * 2048 : w * 1024) + l * 16);
            if constexpr (BM == 128) GLD(gA1l + kb, (char*)AsL + w * 2048 + 1024 + l * 16);
            GLD(gB0l + kb, (char*)BsL + w * 2048 + l * 16);
            GLD(gB1l + kb, (char*)BsL + w * 2048 + 1024 + l * 16);
        }
        __syncthreads();
        bf16x8 ah[NM], bh[4];
#pragma unroll
        for (int mi = 0; mi < NM; ++mi) {
            int r = wr * (BM / 2) + mi * 16 + lr;
            ah[mi] = *(const bf16x8*)((const char*)AsH + r * 64 + ((half ^ (r & 3)) * 16));
        }
#pragma unroll
        for (int ni = 0; ni < 4; ++ni) {
            int r = wc * 64 + ni * 16 + lr;
            bh[ni] = *(const bf16x8*)((const char*)BsH + r * 64 + ((half ^ (r & 3)) * 16));
        }
#pragma unroll
        for (int mi = 0; mi < NM; ++mi)
#pragma unroll
            for (int ni = 0; ni < 4; ++ni)
                acc[mi][ni] = __builtin_amdgcn_mfma_f32_16x16x32_bf16(ah[mi], bh[ni],
                                                                      acc[mi][ni], 0, 0, 0);
        if constexpr (SPLIT) {
            bf16x8 al[NM], bl[4];
#pragma unroll
            for (int mi = 0; mi < NM; ++mi) {
                int r = wr * (BM / 2) + mi * 16 + lr;
                al[mi] = *(const bf16x8*)((const char*)AsL + r * 64 + ((half ^ (r & 3)) * 16));
            }
#pragma unroll
            for (int ni = 0; ni < 4; ++ni) {
                int r = wc * 64 + ni * 16 + lr;
                bl[ni] = *(const bf16x8*)((const char*)BsL + r * 64 + ((half ^ (r & 3)) * 16));
            }
#pragma unroll
            for (int mi = 0; mi < NM; ++mi)
#pragma unroll
                for (int ni = 0; ni < 4; ++ni) {
                    acc[mi][ni] = __builtin_amdgcn_mfma_f32_16x16x32_bf16(ah[mi], bl[ni],
                                                                          acc[mi][ni], 0, 0, 0);
                    acc[mi][ni] = __builtin_amdgcn_mfma_f32_16x16x32_bf16(al[mi], bh[ni],
                                                                          acc[mi][ni], 0, 0, 0);
                }
        }
        __syncthreads();
    }
    // epilogue: C/D layout col=lane&15, row=(lane>>4)*4+reg
#pragma unroll
    for (int mi = 0; mi < NM; ++mi)
#pragma unroll
        for (int r = 0; r < 4; ++r) {
            int row = bm + wr * (BM / 2) + mi * 16 + half * 4 + r;
            float rs = (MODE == 1) ? rowScale[(size_t)row * 4] : 0.0f;
#pragma unroll
            for (int ni = 0; ni < 4; ++ni) {
                int col = bn + wc * 64 + ni * 16 + lr;
                size_t ix = (size_t)row * N + col;
                if constexpr (MODE == 0)      C[ix] = acc[mi][ni][r];
                else if constexpr (MODE == 1) C[ix] += rs * acc[mi][ni][r];
                else                          C[ix] = res[ix] + bias[col] + acc[mi][ni][r];
            }
        }
}

// ---------------- fused rope + split-bf16 pack of q,k (q pre-scaled by 1/8)
// qkv fp32 [t][3072] -> Qh/Ql/Kh/Kl [b][h][s][64] bf16
__global__ __launch_bounds__(256) void qk_pack(const float* __restrict__ qkv,
                                               const float* __restrict__ cs,
                                               const float* __restrict__ sn,
                                               ushort_t* __restrict__ Qh, ushort_t* __restrict__ Ql,
                                               ushort_t* __restrict__ Kh, ushort_t* __restrict__ Kl) {
    int idx = blockIdx.x * 256 + threadIdx.x;   // B*S*NH*32 = 1M
    int p = idx & 31;
    int h = (idx >> 5) & 15;
    int s = (idx >> 9) & (S_SEQ - 1);
    int b = idx >> 19;
    float c = cs[s * 32 + p], si = sn[s * 32 + p];
    long base = ((long)(b * S_SEQ + s)) * 3072 + h * 192;
    long dst = (((long)(b * NHEAD + h)) * S_SEQ + s) * 64 + 2 * p;
    float re = qkv[base + 2 * p], im = qkv[base + 2 * p + 1];
    float qre = (re * c - im * si) * 0.125f;
    float qim = (re * si + im * c) * 0.125f;
    unsigned short hh = f2bf(qre);
    Qh[dst] = hh; Ql[dst] = f2bf(qre - bf2f(hh));
    hh = f2bf(qim);
    Qh[dst + 1] = hh; Ql[dst + 1] = f2bf(qim - bf2f(hh));
    re = qkv[base + 64 + 2 * p]; im = qkv[base + 64 + 2 * p + 1];
    float kre = re * c - im * si;
    float kim = re * si + im * c;
    hh = f2bf(kre);
    Kh[dst] = hh; Kl[dst] = f2bf(kre - bf2f(hh));
    hh = f2bf(kim);
    Kh[dst + 1] = hh; Kl[dst + 1] = f2bf(kim - bf2f(hh));
}

// ---------------- V transpose + split: qkv v-part -> Vt [b][h][64 d][1024 s]
__global__ __launch_bounds__(256) void v_trans(const float* __restrict__ qkv,
                                               ushort_t* __restrict__ Vth,
                                               ushort_t* __restrict__ Vtl) {
    __shared__ float t[64][65];
    const int s0 = blockIdx.x * 64, h = blockIdx.y, b = blockIdx.z;
    const int tid = threadIdx.x;
#pragma unroll
    for (int i = 0; i < 16; ++i) {
        int e = tid + i * 256;
        int sl = e >> 6, d = e & 63;
        t[d][sl] = qkv[((long)(b * S_SEQ + s0 + sl)) * 3072 + h * 192 + 128 + d];
    }
    __syncthreads();
#pragma unroll
    for (int i = 0; i < 16; ++i) {
        int e = tid + i * 256;
        int d = e >> 6, sl = e & 63;
        float v = t[d][sl];
        long o = (((long)(b * NHEAD + h)) * 64 + d) * S_SEQ + s0 + sl;
        unsigned short hh = f2bf(v);
        Vth[o] = hh;
        Vtl[o] = f2bf(v - bf2f(hh));
    }
}

// =====================================================================
// MFMA flash attention, full hi/lo split (fp32-class accuracy).
// Block: 256 thr (4 waves), 64 q-rows per block (16 per wave), KV tiles of 64.
// K/V LDS rows 128B with 3-bit XOR chunk swizzle (pre-swizzled global src).
// =====================================================================
__device__ __forceinline__ bf16x8 lds_frag(const ushort_t* base, int row, int chunk) {
    return *(const bf16x8*)((const char*)base + row * 128 + ((chunk ^ (row & 7)) * 16));
}

__global__ __launch_bounds__(256) void attn_mfma(const ushort_t* __restrict__ Qh,
                                                 const ushort_t* __restrict__ Ql,
                                                 const ushort_t* __restrict__ Kh,
                                                 const ushort_t* __restrict__ Kl,
                                                 const ushort_t* __restrict__ Vth,
                                                 const ushort_t* __restrict__ Vtl,
                                                 float* __restrict__ ctx) {
    __shared__ __align__(16) ushort_t KsH[64 * 64], KsL[64 * 64];
    __shared__ __align__(16) ushort_t VsH[64 * 64], VsL[64 * 64];
    __shared__ __align__(16) ushort_t Ps[4][2][16][72];   // per-wave P hi/lo, padded
    const int qb = blockIdx.x * 64, h = blockIdx.y, b = blockIdx.z;
    const int tid = threadIdx.x;
    const int w = tid >> 6, l = tid & 63;
    const int lr = l & 15, g = l >> 4;
    const long bh = b * NHEAD + h;

    // Q fragments in registers (wave owns q rows qb + w*16 .. +15)
    const long qoff = (bh * S_SEQ + qb + w * 16 + lr) * 64 + g * 8;
    bf16x8 qh0 = *(const bf16x8*)(Qh + qoff);
    bf16x8 qh1 = *(const bf16x8*)(Qh + qoff + 32);
    bf16x8 ql0 = *(const bf16x8*)(Ql + qoff);
    bf16x8 ql1 = *(const bf16x8*)(Ql + qoff + 32);

    // staging maps: per tensor, wave stages rows w*16..w*16+15 (2 GLDs)
    const int rowS0 = w * 16 + (l >> 3), rowS1 = rowS0 + 8;
    const int cch = l & 7;
    const char* gK0 = (const char*)Kh + (bh * S_SEQ + rowS0) * 128 + ((cch ^ (rowS0 & 7)) * 16);
    const char* gK1 = (const char*)Kh + (bh * S_SEQ + rowS1) * 128 + ((cch ^ (rowS1 & 7)) * 16);
    const char* gKl0 = (const char*)Kl + (bh * S_SEQ + rowS0) * 128 + ((cch ^ (rowS0 & 7)) * 16);
    const char* gKl1 = (const char*)Kl + (bh * S_SEQ + rowS1) * 128 + ((cch ^ (rowS1 & 7)) * 16);
    const char* gV0 = (const char*)Vth + (bh * 64 + rowS0) * 2048 + ((cch ^ (rowS0 & 7)) * 16);
    const char* gV1 = (const char*)Vth + (bh * 64 + rowS1) * 2048 + ((cch ^ (rowS1 & 7)) * 16);
    const char* gVl0 = (const char*)Vtl + (bh * 64 + rowS0) * 2048 + ((cch ^ (rowS0 & 7)) * 16);
    const char* gVl1 = (const char*)Vtl + (bh * 64 + rowS1) * 2048 + ((cch ^ (rowS1 & 7)) * 16);

    float m_run[4] = {-1e30f, -1e30f, -1e30f, -1e30f};
    float l_run[4] = {0.f, 0.f, 0.f, 0.f};
    f32x4 acco[4] = {};

    for (int k0 = 0; k0 < S_SEQ; k0 += 64) {
        // stage K/V tile (K rows advance by k0*128B; V cols advance by k0*2B)
        GLD(gK0 + (size_t)k0 * 128, (char*)KsH + w * 2048 + l * 16);
        GLD(gK1 + (size_t)k0 * 128, (char*)KsH + w * 2048 + 1024 + l * 16);
        GLD(gKl0 + (size_t)k0 * 128, (char*)KsL + w * 2048 + l * 16);
        GLD(gKl1 + (size_t)k0 * 128, (char*)KsL + w * 2048 + 1024 + l * 16);
        GLD(gV0 + (size_t)k0 * 2, (char*)VsH + w * 2048 + l * 16);
        GLD(gV1 + (size_t)k0 * 2, (char*)VsH + w * 2048 + 1024 + l * 16);
        GLD(gVl0 + (size_t)k0 * 2, (char*)VsL + w * 2048 + l * 16);
        GLD(gVl1 + (size_t)k0 * 2, (char*)VsL + w * 2048 + 1024 + l * 16);
        __syncthreads();

        // S = Q K^T (split 3-pass); scores pre-scaled via Q
        f32x4 accs[4] = {};
#pragma unroll
        for (int n = 0; n < 4; ++n) {
            bf16x8 bkh0 = lds_frag(KsH, n * 16 + lr, g);
            bf16x8 bkh1 = lds_frag(KsH, n * 16 + lr, g + 4);
            bf16x8 bkl0 = lds_frag(KsL, n * 16 + lr, g);
            bf16x8 bkl1 = lds_frag(KsL, n * 16 + lr, g + 4);
            accs[n] = __builtin_amdgcn_mfma_f32_16x16x32_bf16(qh0, bkh0, accs[n], 0, 0, 0);
            accs[n] = __builtin_amdgcn_mfma_f32_16x16x32_bf16(qh1, bkh1, accs[n], 0, 0, 0);
            accs[n] = __builtin_amdgcn_mfma_f32_16x16x32_bf16(qh0, bkl0, accs[n], 0, 0, 0);
            accs[n] = __builtin_amdgcn_mfma_f32_16x16x32_bf16(qh1, bkl1, accs[n], 0, 0, 0);
            accs[n] = __builtin_amdgcn_mfma_f32_16x16x32_bf16(ql0, bkh0, accs[n], 0, 0, 0);
            accs[n] = __builtin_amdgcn_mfma_f32_16x16x32_bf16(ql1, bkh1, accs[n], 0, 0, 0);
        }
        // online softmax: lane holds rows q = g*4 + r, cols n*16 + lr
        float alpha[4];
#pragma unroll
        for (int r = 0; r < 4; ++r) {
            float mx = fmaxf(fmaxf(accs[0][r], accs[1][r]), fmaxf(accs[2][r], accs[3][r]));
#pragma unroll
            for (int msk = 1; msk < 16; msk <<= 1) mx = fmaxf(mx, __shfl_xor(mx, msk, 64));
            float m_new = fmaxf(m_run[r], mx);
            float ps = 0.f;
#pragma unroll
            for (int n = 0; n < 4; ++n) {
                float p = __expf(accs[n][r] - m_new);
                accs[n][r] = p;
                ps += p;
            }
#pragma unroll
            for (int msk = 1; msk < 16; msk <<= 1) ps += __shfl_xor(ps, msk, 64);
            alpha[r] = __expf(m_run[r] - m_new);
            l_run[r] = l_run[r] * alpha[r] + ps;
            m_run[r] = m_new;
        }
#pragma unroll
        for (int nd = 0; nd < 4; ++nd)
#pragma unroll
            for (int r = 0; r < 4; ++r) acco[nd][r] *= alpha[r];
        // write P (hi/lo) to per-wave LDS for A-operand relayout
#pragma unroll
        for (int n = 0; n < 4; ++n)
#pragma unroll
            for (int r = 0; r < 4; ++r) {
                float p = accs[n][r];
                unsigned short hh = f2bf(p);
                Ps[w][0][g * 4 + r][n * 16 + lr] = hh;
                Ps[w][1][g * 4 + r][n * 16 + lr] = f2bf(p - bf2f(hh));
            }
        __syncthreads();
        // PV: out += P(16x64) @ V(64x64), split 3-pass
        bf16x8 pah0 = *(const bf16x8*)&Ps[w][0][lr][g * 8];
        bf16x8 pah1 = *(const bf16x8*)&Ps[w][0][lr][32 + g * 8];
        bf16x8 pal0 = *(const bf16x8*)&Ps[w][1][lr][g * 8];
        bf16x8 pal1 = *(const bf16x8*)&Ps[w][1][lr][32 + g * 8];
#pragma unroll
        for (int nd = 0; nd < 4; ++nd) {
            bf16x8 bvh0 = lds_frag(VsH, nd * 16 + lr, g);
            bf16x8 bvh1 = lds_frag(VsH, nd * 16 + lr, g + 4);
            bf16x8 bvl0 = lds_frag(VsL, nd * 16 + lr, g);
            bf16x8 bvl1 = lds_frag(VsL, nd * 16 + lr, g + 4);
            acco[nd] = __builtin_amdgcn_mfma_f32_16x16x32_bf16(pah0, bvh0, acco[nd], 0, 0, 0);
            acco[nd] = __builtin_amdgcn_mfma_f32_16x16x32_bf16(pah1, bvh1, acco[nd], 0, 0, 0);
            acco[nd] = __builtin_amdgcn_mfma_f32_16x16x32_bf16(pah0, bvl0, acco[nd], 0, 0, 0);
            acco[nd] = __builtin_amdgcn_mfma_f32_16x16x32_bf16(pah1, bvl1, acco[nd], 0, 0, 0);
            acco[nd] = __builtin_amdgcn_mfma_f32_16x16x32_bf16(pal0, bvh0, acco[nd], 0, 0, 0);
            acco[nd] = __builtin_amdgcn_mfma_f32_16x16x32_bf16(pal1, bvh1, acco[nd], 0, 0, 0);
        }
        __syncthreads();
    }
    // write ctx [b][s][h*64+d]
#pragma unroll
    for (int r = 0; r < 4; ++r) {
        float inv = 1.0f / l_run[r];
        long row = (long)b * S_SEQ + qb + w * 16 + g * 4 + r;
#pragma unroll
        for (int nd = 0; nd < 4; ++nd)
            ctx[row * H_DIM + h * 64 + nd * 16 + lr] = acco[nd][r] * inv;
    }
}

// ---------------- gate: top-2 softmax weights (zeros elsewhere)
__global__ __launch_bounds__(256) void gate_kernel(const float* __restrict__ h2,
                                                   const float* __restrict__ gate_w,
                                                   float* __restrict__ gw) {
    long t = blockIdx.x;
    float sum[4] = {0, 0, 0, 0};
    for (int i = threadIdx.x; i < H_DIM; i += 256) {
        float v = h2[t * H_DIM + i];
#pragma unroll
        for (int e = 0; e < 4; ++e) sum[e] = fmaf(v, gate_w[e * H_DIM + i], sum[e]);
    }
#pragma unroll
    for (int w = 1; w < 64; w <<= 1)
#pragma unroll
        for (int e = 0; e < 4; ++e) sum[e] += __shfl_xor(sum[e], w, 64);
    __shared__ float part[4][4];
    if ((threadIdx.x & 63) == 0)
#pragma unroll
        for (int e = 0; e < 4; ++e) part[e][threadIdx.x >> 6] = sum[e];
    __syncthreads();
    if (threadIdx.x == 0) {
        float lg[4];
#pragma unroll
        for (int e = 0; e < 4; ++e) lg[e] = part[e][0] + part[e][1] + part[e][2] + part[e][3];
        int i0 = 0;
        for (int e = 1; e < 4; ++e) if (lg[e] > lg[i0]) i0 = e;
        int i1 = -1;
        for (int e = 0; e < 4; ++e) if (e != i0 && (i1 < 0 || lg[e] > lg[i1])) i1 = e;
        float mx = fmaxf(lg[i0], lg[i1]);
        float e0 = __expf(lg[i0] - mx), e1 = __expf(lg[i1] - mx);
        float inv = 1.0f / (e0 + e1);
        float o[4] = {0, 0, 0, 0};
        o[i0] = e0 * inv; o[i1] = e1 * inv;
#pragma unroll
        for (int e = 0; e < 4; ++e) gw[t * 4 + e] = o[e];
    }
}

// ================= fallback-only kernels (round-0 fp32 path) =================
#define KI 8
#define BKK 72
__global__ __launch_bounds__(256) void kan_gemm(const float* __restrict__ Act,
                                                const float* __restrict__ baseW,
                                                const float* __restrict__ splW,
                                                const float* __restrict__ scal,
                                                float* __restrict__ C,
                                                const float* __restrict__ rowScale,
                                                int rsStride, int N, int mode) {
    __shared__ float As[BKK][64];
    __shared__ float Bs[BKK][64];
    const int bm = blockIdx.y * 64;
    const int bn = blockIdx.x * 64;
    const int tid = threadIdx.x;
    const int tx = tid & 15, ty = tid >> 4;
    float acc[4][4] = {};
    for (int i0 = 0; i0 < H_DIM; i0 += KI) {
        for (int e = tid; e < 64 * KI; e += 256) {
            int m = e >> 3, ii = e & 7;
            float xv = Act[(long)(bm + m) * H_DIM + i0 + ii];
            float sp[8];
            bspline8(xv, sp);
            As[ii * 9][m] = xv * sigmoidf_(xv);
#pragma unroll
            for (int c = 0; c < 8; ++c) As[ii * 9 + 1 + c][m] = sp[c];
        }
        for (int e = tid; e < 64 * KI; e += 256) {
            int n = e >> 3, ii = e & 7;
            long w = (long)(bn + n) * H_DIM + i0 + ii;
            float sc = scal[w];
            Bs[ii * 9][n] = baseW[w];
            const float4* sp4 = (const float4*)(splW + w * 8);
            float4 s0 = sp4[0], s1 = sp4[1];
            Bs[ii * 9 + 1][n] = s0.x * sc; Bs[ii * 9 + 2][n] = s0.y * sc;
            Bs[ii * 9 + 3][n] = s0.z * sc; Bs[ii * 9 + 4][n] = s0.w * sc;
            Bs[ii * 9 + 5][n] = s1.x * sc; Bs[ii * 9 + 6][n] = s1.y * sc;
            Bs[ii * 9 + 7][n] = s1.z * sc; Bs[ii * 9 + 8][n] = s1.w * sc;
        }
        __syncthreads();
#pragma unroll 8
        for (int k = 0; k < BKK; ++k) {
            float4 a = *(const float4*)&As[k][ty * 4];
            float4 b = *(const float4*)&Bs[k][tx * 4];
            float av[4] = {a.x, a.y, a.z, a.w};
            float bv[4] = {b.x, b.y, b.z, b.w};
#pragma unroll
            for (int i = 0; i < 4; ++i)
#pragma unroll
                for (int j = 0; j < 4; ++j) acc[i][j] = fmaf(av[i], bv[j], acc[i][j]);
        }
        __syncthreads();
    }
#pragma unroll
    for (int i = 0; i < 4; ++i) {
        long m = bm + ty * 4 + i;
        float rs = (mode == 1) ? rowScale[m * rsStride] : 0.0f;
#pragma unroll
        for (int j = 0; j < 4; ++j) {
            long idx = m * (long)N + bn + tx * 4 + j;
            if (mode == 0) C[idx] = acc[i][j];
            else           C[idx] += rs * acc[i][j];
        }
    }
}

__global__ __launch_bounds__(256) void gemm_bias_res(const float* __restrict__ A,
                                                     const float* __restrict__ Bw,
                                                     const float* __restrict__ bias,
                                                     const float* __restrict__ res,
                                                     float* __restrict__ C) {
    __shared__ float As[16][64];
    __shared__ float Bs[16][64];
    const int bm = blockIdx.y * 64, bn = blockIdx.x * 64;
    const int tid = threadIdx.x;
    const int tx = tid & 15, ty = tid >> 4;
    float acc[4][4] = {};
    for (int k0 = 0; k0 < 1024; k0 += 16) {
        for (int e = tid; e < 1024; e += 256) {
            int r = e >> 4, kk = e & 15;
            As[kk][r] = A[(long)(bm + r) * 1024 + k0 + kk];
            Bs[kk][r] = Bw[(long)(bn + r) * 1024 + k0 + kk];
        }
        __syncthreads();
#pragma unroll
        for (int k = 0; k < 16; ++k) {
            float4 a = *(const float4*)&As[k][ty * 4];
            float4 b = *(const float4*)&Bs[k][tx * 4];
            float av[4] = {a.x, a.y, a.z, a.w};
            float bv[4] = {b.x, b.y, b.z, b.w};
#pragma unroll
            for (int i = 0; i < 4; ++i)
#pragma unroll
                for (int j = 0; j < 4; ++j) acc[i][j] = fmaf(av[i], bv[j], acc[i][j]);
        }
        __syncthreads();
    }
#pragma unroll
    for (int i = 0; i < 4; ++i) {
        long m = bm + ty * 4 + i;
#pragma unroll
        for (int j = 0; j < 4; ++j) {
            long n = bn + tx * 4 + j;
            C[m * 1024 + n] = res[m * 1024 + n] + bias[n] + acc[i][j];
        }
    }
}

__global__ __launch_bounds__(256) void rope_kernel(float* __restrict__ qkv,
                                                   const float* __restrict__ cs,
                                                   const float* __restrict__ sn) {
    int idx = blockIdx.x * 256 + threadIdx.x;
    if (idx >= T_TOK * NHEAD * 32) return;
    int p = idx & 31;
    int n = (idx >> 5) & 15;
    int t = idx >> 9;
    int s = t & (S_SEQ - 1);
    float c = cs[s * 32 + p], si = sn[s * 32 + p];
    long base = (long)t * 3072 + n * 192;
    float re = qkv[base + 2 * p], im = qkv[base + 2 * p + 1];
    qkv[base + 2 * p]     = re * c - im * si;
    qkv[base + 2 * p + 1] = re * si + im * c;
    re = qkv[base + 64 + 2 * p]; im = qkv[base + 64 + 2 * p + 1];
    qkv[base + 64 + 2 * p]     = re * c - im * si;
    qkv[base + 64 + 2 * p + 1] = re * si + im * c;
}

__global__ __launch_bounds__(256) void attn_kernel(const float* __restrict__ qkv,
                                                   float* __restrict__ ctx) {
    const int qb = blockIdx.x * 32;
    const int h = blockIdx.y, b = blockIdx.z;
    __shared__ float Qs[32][64];
    __shared__ float Ks[64][64];
    __shared__ float Vs[64][64];
    __shared__ float Ss[32][64];
    const int tid = threadIdx.x;
    const int q = tid >> 3, g = tid & 7;
    for (int e = tid; e < 32 * 64; e += 256) {
        int r = e >> 6, d = e & 63;
        Qs[r][d] = qkv[(long)(b * S_SEQ + qb + r) * 3072 + h * 192 + d];
    }
    float m_run = -1e30f, l_run = 0.0f;
    float acc[8] = {};
    for (int k0 = 0; k0 < S_SEQ; k0 += 64) {
        for (int e = tid; e < 64 * 64; e += 256) {
            int r = e >> 6, d = e & 63;
            long base = (long)(b * S_SEQ + k0 + r) * 3072 + h * 192;
            Ks[r][d] = qkv[base + 64 + d];
            Vs[r][d] = qkv[base + 128 + d];
        }
        __syncthreads();
        float s[8];
#pragma unroll
        for (int kk = 0; kk < 8; ++kk) {
            int k = g * 8 + kk;
            float dot = 0.0f;
#pragma unroll
            for (int d = 0; d < 64; ++d) dot = fmaf(Qs[q][d], Ks[k][d], dot);
            s[kk] = dot * 0.125f;
        }
        float mx = s[0];
#pragma unroll
        for (int kk = 1; kk < 8; ++kk) mx = fmaxf(mx, s[kk]);
#pragma unroll
        for (int w = 1; w < 8; w <<= 1) mx = fmaxf(mx, __shfl_xor(mx, w, 64));
        float m_new = fmaxf(m_run, mx);
        float p[8], ls = 0.0f;
#pragma unroll
        for (int kk = 0; kk < 8; ++kk) { p[kk] = __expf(s[kk] - m_new); ls += p[kk]; }
#pragma unroll
        for (int w = 1; w < 8; w <<= 1) ls += __shfl_xor(ls, w, 64);
        float alpha = __expf(m_run - m_new);
        l_run = l_run * alpha + ls;
        m_run = m_new;
#pragma unroll
        for (int kk = 0; kk < 8; ++kk) Ss[q][g * 8 + kk] = p[kk];
        __syncthreads();
#pragma unroll
        for (int j = 0; j < 8; ++j) acc[j] *= alpha;
        for (int k = 0; k < 64; ++k) {
            float pv = Ss[q][k];
#pragma unroll
            for (int j = 0; j < 8; ++j) acc[j] = fmaf(pv, Vs[k][g * 8 + j], acc[j]);
        }
        __syncthreads();
    }
    float inv = 1.0f / l_run;
#pragma unroll
    for (int j = 0; j < 8; ++j)
        ctx[(long)(b * S_SEQ + qb + q) * H_DIM + h * 64 + g * 8 + j] = acc[j] * inv;
}

__global__ __launch_bounds__(256) void mul_kernel(const float* __restrict__ a,
                                                  const float* __restrict__ b,
                                                  float* __restrict__ c, int n) {
    int i = blockIdx.x * 256 + threadIdx.x;
    if (i < n) c[i] = a[i] * b[i];
}

extern "C" void kernel_launch(void* const* d_in, const int* in_sizes, int n_in,
                              void* d_out, int out_size, void* d_ws, size_t ws_size,
                              hipStream_t stream) {
    const float* x          = (const float*)d_in[0];
    const float* rot_cos    = (const float*)d_in[1];
    const float* rot_sin    = (const float*)d_in[2];
    const float* norm1_w    = (const float*)d_in[3];
    const float* norm2_w    = (const float*)d_in[4];
    const float* qkv_base   = (const float*)d_in[5];
    const float* qkv_spline = (const float*)d_in[6];
    const float* qkv_scaler = (const float*)d_in[7];
    const float* out_w      = (const float*)d_in[8];
    const float* out_b      = (const float*)d_in[9];
    const float* gate_w     = (const float*)d_in[10];
    const float* w1_base    = (const float*)d_in[11];
    const float* w1_spline  = (const float*)d_in[12];
    const float* w1_scaler  = (const float*)d_in[13];
    const float* w2_base    = (const float*)d_in[14];
    const float* w2_spline  = (const float*)d_in[15];
    const float* w2_scaler  = (const float*)d_in[16];
    const float* w3_base    = (const float*)d_in[17];
    const float* w3_spline  = (const float*)d_in[18];
    const float* w3_scaler  = (const float*)d_in[19];
    float* out = (float*)d_out;

    const size_t SZ_AUG  = (size_t)T_TOK * KAUG * 2;   // 37.7 MB
    const size_t SZ_WQ   = (size_t)3072 * KAUG * 2;    // 56.6 MB
    const size_t SZ_QKV  = (size_t)T_TOK * 3072 * 4;   // 25.2 MB
    const size_t SZ_G12  = (size_t)T_TOK * 2048 * 4;   // 16.8 MB
    const size_t SZ_TOK  = (size_t)T_TOK * H_DIM * 4;  //  8.4 MB
    const size_t NEED = 2 * SZ_AUG + 2 * SZ_WQ + SZ_QKV + SZ_G12 + 2 * SZ_TOK + 32768;

    if (ws_size >= NEED) {
        char* p = (char*)d_ws;
        ushort_t* A_hi = (ushort_t*)p; p += SZ_AUG;
        ushort_t* A_lo = (ushort_t*)p; p += SZ_AUG;   // reused as G_hi in MoE
        char* W1p = p; p += SZ_WQ;                    // qkv weight hi; later Q/K/V packs; later MoE w1/w2
        char* W2p = p; p += SZ_WQ;                    // qkv weight lo; later ctx/out_w packs; later MoE w3
        float* qkv = (float*)p; p += SZ_QKV;
        float* g12 = (float*)p; p += SZ_G12;
        float* ctx = (float*)p; p += SZ_TOK;
        float* tok = (float*)p; p += SZ_TOK;          // hn, later h2
        float* gw  = (float*)p; p += 32768;
        ushort_t* G_hi = A_lo;
        ushort_t* W1b = (ushort_t*)W1p;
        ushort_t* W2b = (ushort_t*)W2p;
        // attention packed buffers overlay W1p (24 MB < 56.6 MB)
        const size_t SZ_P = (size_t)T_TOK * 1024 * 2;  // 4 MB each
        ushort_t* Qh  = (ushort_t*)W1p;
        ushort_t* Ql  = (ushort_t*)(W1p + SZ_P);
        ushort_t* Kh  = (ushort_t*)(W1p + 2 * SZ_P);
        ushort_t* Kl  = (ushort_t*)(W1p + 3 * SZ_P);
        ushort_t* Vth = (ushort_t*)(W1p + 4 * SZ_P);
        ushort_t* Vtl = (ushort_t*)(W1p + 5 * SZ_P);
        // out-proj packed buffers overlay W2p (12 MB < 56.6 MB)
        ushort_t* CtxH = (ushort_t*)W2p;
        ushort_t* CtxL = (ushort_t*)(W2p + SZ_P);
        ushort_t* OWh  = (ushort_t*)(W2p + 2 * SZ_P);
        ushort_t* OWl  = (ushort_t*)(W2p + 2 * SZ_P + SZ_P / 2);

        // --- attention branch: split-bf16 everywhere upstream of the gate ---
        rmsnorm_kernel<<<T_TOK, 256, 0, stream>>>(x, norm1_w, tok);
        pack_act<<<(T_TOK * 1024) / 256, 256, 0, stream>>>(tok, A_hi, A_lo);
        pack_w<<<(3072 * 1024) / 256, 256, 0, stream>>>(qkv_base, qkv_spline, qkv_scaler,
                                                        W1b, W2b, (long)3072 * 1024);
        mfma_gemm2<128, 1, 0><<<dim3(3072 / 128, T_TOK / 128), 256, 0, stream>>>(
            A_hi, A_lo, W1b, W2b, qkv, nullptr, nullptr, nullptr, 3072, KAUG);
        qk_pack<<<(T_TOK * NHEAD * 32) / 256, 256, 0, stream>>>(qkv, rot_cos, rot_sin,
                                                                Qh, Ql, Kh, Kl);
        v_trans<<<dim3(S_SEQ / 64, NHEAD, 2), 256, 0, stream>>>(qkv, Vth, Vtl);
        attn_mfma<<<dim3(S_SEQ / 64, NHEAD, 2), 256, 0, stream>>>(Qh, Ql, Kh, Kl,
                                                                  Vth, Vtl, ctx);
        split_pack<<<(T_TOK * 1024) / 256, 256, 0, stream>>>(ctx, CtxH, CtxL,
                                                             (long)T_TOK * 1024);
        split_pack<<<(1024 * 1024) / 256, 256, 0, stream>>>(out_w, OWh, OWl,
                                                            (long)1024 * 1024);
        mfma_gemm2<128, 1, 2><<<dim3(1024 / 128, T_TOK / 128), 256, 0, stream>>>(
            CtxH, CtxL, OWh, OWl, out, nullptr, out_b, x, 1024, 1024);
        rmsnorm_kernel<<<T_TOK, 256, 0, stream>>>(out, norm2_w, tok);
        gate_kernel<<<T_TOK, 256, 0, stream>>>(tok, gate_w, gw);

        // --- MoE: plain bf16 (downstream of gate) ---
        pack_act<<<(T_TOK * 1024) / 256, 256, 0, stream>>>(tok, A_hi, nullptr);
        for (int e = 0; e < E_EXP; ++e) {
            long wo = (long)e * DFF_ * H_DIM;
            pack_w<<<(1024 * 1024) / 256, 256, 0, stream>>>(
                w1_base + wo, w1_spline + wo * 8, w1_scaler + wo, W1b, nullptr,
                (long)1024 * 1024);
            pack_w<<<(1024 * 1024) / 256, 256, 0, stream>>>(
                w2_base + wo, w2_spline + wo * 8, w2_scaler + wo,
                W1b + (size_t)1024 * KAUG, nullptr, (long)1024 * 1024);
            mfma_gemm2<128, 0, 0><<<dim3(2048 / 128, T_TOK / 128), 256, 0, stream>>>(
                A_hi, nullptr, W1b, nullptr, g12, nullptr, nullptr, nullptr, 2048, KAUG);
            mul_pack<<<(T_TOK * 1024) / 256, 256, 0, stream>>>(g12, G_hi);
            pack_w<<<(1024 * 1024) / 256, 256, 0, stream>>>(
                w3_base + wo, w3_spline + wo * 8, w3_scaler + wo, W2b, nullptr,
                (long)1024 * 1024);
            mfma_gemm2<64, 0, 1><<<dim3(1024 / 128, T_TOK / 64), 256, 0, stream>>>(
                G_hi, nullptr, W2b, nullptr, out, gw + e, nullptr, nullptr, 1024, KAUG);
        }
        return;
    }

    // ---- fallback: fp32 path ----
    char* ws = (char*)d_ws;
    float* hn  = (float*)ws; ws += (size_t)T_TOK * H_DIM * 4;
    float* qkv = (float*)ws; ws += (size_t)T_TOK * 3072 * 4;
    float* ctx = (float*)ws; ws += (size_t)T_TOK * H_DIM * 4;
    float* h2  = (float*)ws; ws += (size_t)T_TOK * H_DIM * 4;
    float* gw  = (float*)ws; ws += (size_t)T_TOK * E_EXP * 4;
    float* g1  = (float*)ws; ws += (size_t)T_TOK * DFF_ * 4;
    float* g2  = (float*)ws; ws += (size_t)T_TOK * DFF_ * 4;
    float* gm  = (float*)ws; ws += (size_t)T_TOK * DFF_ * 4;

    rmsnorm_kernel<<<T_TOK, 256, 0, stream>>>(x, norm1_w, hn);
    dim3 gq(3072 / 64, T_TOK / 64);
    kan_gemm<<<gq, 256, 0, stream>>>(hn, qkv_base, qkv_spline, qkv_scaler, qkv,
                                     nullptr, 0, 3072, 0);
    rope_kernel<<<(T_TOK * NHEAD * 32) / 256, 256, 0, stream>>>(qkv, rot_cos, rot_sin);
    dim3 ga(S_SEQ / 32, NHEAD, 2);
    attn_kernel<<<ga, 256, 0, stream>>>(qkv, ctx);
    dim3 go(1024 / 64, T_TOK / 64);
    gemm_bias_res<<<go, 256, 0, stream>>>(ctx, out_w, out_b, x, out);
    rmsnorm_kernel<<<T_TOK, 256, 0, stream>>>(out, norm2_w, h2);
    gate_kernel<<<T_TOK, 256, 0, stream>>>(h2, gate_w, gw);
    dim3 ge(1024 / 64, T_TOK / 64);
    for (int e = 0; e < E_EXP; ++e) {
        long wo = (long)e * DFF_ * H_DIM;
        kan_gemm<<<ge, 256, 0, stream>>>(h2, w1_base + wo, w1_spline + wo * 8,
                                         w1_scaler + wo, g1, nullptr, 0, DFF_, 0);
        kan_gemm<<<ge, 256, 0, stream>>>(h2, w2_base + wo, w2_spline + wo * 8,
                                         w2_scaler + wo, g2, nullptr, 0, DFF_, 0);
        mul_kernel<<<(T_TOK * DFF_) / 256, 256, 0, stream>>>(g1, g2, gm, T_TOK * DFF_);
        kan_gemm<<<ge, 256, 0, stream>>>(gm, w3_base + wo, w3_spline + wo * 8,
                                         w3_scaler + wo, out, gw + e, E_EXP, H_DIM, 1);
    }
}

// Round 4
// 1587.831 us; speedup vs baseline: 7.5999x; 1.3821x over previous
//
#include <hip/hip_runtime.h>
#include <hip/hip_bf16.h>

// KANBlock: B=2,S=1024,H=1024,NH=16,HD=64,DFF=1024,E=4,TOPK=2, NB=8 spline bases
#define T_TOK 2048
#define H_DIM 1024
#define S_SEQ 1024
#define NHEAD 16
#define E_EXP 4
#define DFF_  1024
#define KAUG  9216   // 9*1024 augmented K (k = c*1024 + i; c=0 silu, c=1..8 splines)

typedef __bf16 bf16x8 __attribute__((ext_vector_type(8)));
typedef float  f32x4  __attribute__((ext_vector_type(4)));
typedef unsigned short ushort_t;

__device__ __forceinline__ float sigmoidf_(float x) { return 1.0f / (1.0f + __expf(-x)); }

__device__ __forceinline__ unsigned short f2bf(float f) {   // RNE f32 -> bf16 bits
    unsigned int u = __float_as_uint(f);
    u = (u + 0x7fffu + ((u >> 16) & 1u)) >> 16;
    return (unsigned short)u;
}
__device__ __forceinline__ float bf2f(unsigned short h) {
    return __uint_as_float(((unsigned int)h) << 16);
}

// Cubic B-spline bases, matches reference b_splines() (verified round 0)
__device__ __forceinline__ void bspline8(float x, float* o) {
    float b[11];
#pragma unroll
    for (int m = 0; m < 11; ++m) {
        float g0 = 0.4f * (float)(m - 3) - 1.0f;
        float g1 = 0.4f * (float)(m - 2) - 1.0f;
        b[m] = (x >= g0 && x < g1) ? 1.0f : 0.0f;
    }
#pragma unroll
    for (int j = 1; j <= 3; ++j) {
        float inv = 1.0f / (0.4f * (float)j);
#pragma unroll
        for (int m = 0; m + j < 11; ++m) {
            float gm   = 0.4f * (float)(m - 3) - 1.0f;
            float gmj1 = 0.4f * (float)(m + j - 2) - 1.0f;
            b[m] = ((x - gm) * b[m] + (gmj1 - x) * b[m + 1]) * inv;
        }
    }
#pragma unroll
    for (int c = 0; c < 8; ++c) o[c] = b[c];
}

// ---------------- RMSNorm
__global__ __launch_bounds__(256) void rmsnorm_kernel(const float* __restrict__ x,
                                                      const float* __restrict__ w,
                                                      float* __restrict__ out) {
    long t = blockIdx.x;
    float4 v = ((const float4*)(x + t * H_DIM))[threadIdx.x];
    float ss = v.x * v.x + v.y * v.y + v.z * v.z + v.w * v.w;
#pragma unroll
    for (int m = 1; m < 64; m <<= 1) ss += __shfl_xor(ss, m, 64);
    __shared__ float wsum[4];
    if ((threadIdx.x & 63) == 0) wsum[threadIdx.x >> 6] = ss;
    __syncthreads();
    ss = wsum[0] + wsum[1] + wsum[2] + wsum[3];
    float sc = rsqrtf(ss * (1.0f / (float)H_DIM) + 1e-6f);
    float4 wv = ((const float4*)w)[threadIdx.x];
    float4 r;
    r.x = v.x * sc * wv.x; r.y = v.y * sc * wv.y;
    r.z = v.z * sc * wv.z; r.w = v.w * sc * wv.w;
    ((float4*)(out + t * H_DIM))[threadIdx.x] = r;
}

// ---------------- pack activations -> augmented bf16 (hi, optional lo)
__global__ __launch_bounds__(256) void pack_act(const float* __restrict__ act,
                                                ushort_t* __restrict__ hi,
                                                ushort_t* __restrict__ lo) {
    long idx = (long)blockIdx.x * 256 + threadIdx.x;
    long m = idx >> 10; int i = (int)(idx & 1023);
    float v = act[idx];
    float ch[9];
    ch[0] = v * sigmoidf_(v);
    bspline8(v, ch + 1);
    ushort_t* oh = hi + m * (long)KAUG + i;
#pragma unroll
    for (int c = 0; c < 9; ++c) oh[(long)c * 1024] = f2bf(ch[c]);
    if (lo) {
        ushort_t* ol = lo + m * (long)KAUG + i;
#pragma unroll
        for (int c = 0; c < 9; ++c) {
            unsigned short h = f2bf(ch[c]);
            ol[(long)c * 1024] = f2bf(ch[c] - bf2f(h));
        }
    }
}

// ---------------- pack weights -> augmented bf16: [base | spline*scaler]
__global__ __launch_bounds__(256) void pack_w(const float* __restrict__ base,
                                              const float* __restrict__ spl,
                                              const float* __restrict__ scal,
                                              ushort_t* __restrict__ hi,
                                              ushort_t* __restrict__ lo,
                                              long total) {
    long idx = (long)blockIdx.x * 256 + threadIdx.x;
    if (idx >= total) return;
    long n = idx >> 10; int i = (int)(idx & 1023);
    float sc = scal[idx];
    const float4* s4 = (const float4*)(spl + idx * 8);
    float4 s0 = s4[0], s1 = s4[1];
    float ch[9] = {base[idx], s0.x * sc, s0.y * sc, s0.z * sc, s0.w * sc,
                   s1.x * sc, s1.y * sc, s1.z * sc, s1.w * sc};
    ushort_t* oh = hi + n * (long)KAUG + i;
#pragma unroll
    for (int c = 0; c < 9; ++c) oh[(long)c * 1024] = f2bf(ch[c]);
    if (lo) {
        ushort_t* ol = lo + n * (long)KAUG + i;
#pragma unroll
        for (int c = 0; c < 9; ++c) {
            unsigned short h = f2bf(ch[c]);
            ol[(long)c * 1024] = f2bf(ch[c] - bf2f(h));
        }
    }
}

// ---------------- batched: v = g1all*g2all -> 4 per-expert augmented bf16 G's
__global__ __launch_bounds__(256) void mul_pack4(const float* __restrict__ g1,
                                                 const float* __restrict__ g2,
                                                 ushort_t* __restrict__ G) {
    long idx = (long)blockIdx.x * 256 + threadIdx.x;   // T_TOK*4096
    long t = idx >> 12; int ei = (int)(idx & 4095);
    int e = ei >> 10, i = ei & 1023;
    float v = g1[idx] * g2[idx];
    float ch[9];
    ch[0] = v * sigmoidf_(v);
    bspline8(v, ch + 1);
    ushort_t* oh = G + ((long)e * T_TOK + t) * (long)KAUG + i;
#pragma unroll
    for (int c = 0; c < 9; ++c) oh[(long)c * 1024] = f2bf(ch[c]);
}

// ---------------- elementwise f32 -> bf16 hi/lo split
__global__ __launch_bounds__(256) void split_pack(const float* __restrict__ in,
                                                  ushort_t* __restrict__ hi,
                                                  ushort_t* __restrict__ lo, long n) {
    long i = (long)blockIdx.x * 256 + threadIdx.x;
    if (i >= n) return;
    float v = in[i];
    unsigned short h = f2bf(v);
    hi[i] = h;
    lo[i] = f2bf(v - bf2f(h));
}

// =====================================================================
// MFMA GEMM (m97 structure): C(M,N) = A(M,K) @ B(N,K)^T, bf16 ops fp32 acc.
// BM x 128 tile, BK=32, 4 waves (2x2), wave tile (BM/2) x 64.
// 2-bit XOR chunk swizzle on LDS (pre-swizzled global source, rule #21).
// Bijective XCD-swizzle on (x,y) block ids (T1, m204).
// SPLIT: 3-pass hi/lo (fp32-class).
// MODE 0: C=acc; 1: C+=rowScale[row*4]*acc; 2: C=res+bias+acc;
// 3: batched-expert (z): A+=z*M*K, B+=z*N*K, rowScale+=z, atomicAdd into C.
// =====================================================================
#define GLD(gp, lp) __builtin_amdgcn_global_load_lds( \
    (const __attribute__((address_space(1))) void*)(gp), \
    (__attribute__((address_space(3))) void*)(lp), 16, 0, 0)

template<int BM, int SPLIT, int MODE>
__global__ __launch_bounds__(256) void mfma_gemm2(const ushort_t* __restrict__ Ah,
                                                  const ushort_t* __restrict__ Al,
                                                  const ushort_t* __restrict__ Bh,
                                                  const ushort_t* __restrict__ Bl,
                                                  float* __restrict__ C,
                                                  const float* __restrict__ rowScale,
                                                  const float* __restrict__ bias,
                                                  const float* __restrict__ res,
                                                  int N, int K) {
    constexpr int NM = BM / 32;            // A fragments per wave
    __shared__ __align__(16) ushort_t AsH[BM * 32];
    __shared__ __align__(16) ushort_t BsH[128 * 32];
    __shared__ __align__(16) ushort_t AsL[SPLIT ? BM * 32 : 16];
    __shared__ __align__(16) ushort_t BsL[SPLIT ? 128 * 32 : 16];
    // XCD-aware bijective block remap (all grids here have nwg % 8 == 0)
    const int nx = gridDim.x;
    const int nwg = nx * gridDim.y;
    const int bid = blockIdx.y * nx + blockIdx.x;
    const int q8 = nwg >> 3, r8 = nwg & 7;
    const int xc = bid & 7, dd = bid >> 3;
    const int nid = (xc < r8 ? xc * (q8 + 1) : r8 * (q8 + 1) + (xc - r8) * q8) + dd;
    const int bm = (nid / nx) * BM, bn = (nid % nx) * 128;

    const ushort_t* Ap = Ah;
    const ushort_t* Bp = Bh;
    const float* rsp = rowScale;
    if constexpr (MODE == 3) {
        Ap  += (size_t)blockIdx.z * (size_t)gridDim.y * BM * (size_t)K;
        Bp  += (size_t)blockIdx.z * (size_t)N * (size_t)K;
        rsp += blockIdx.z;
    }

    const int tid = threadIdx.x;
    const int w = tid >> 6, l = tid & 63;
    const int wr = w >> 1, wc = w & 1;
    const int half = l >> 4, lr = l & 15;
    const size_t rb = (size_t)K * 2;       // row bytes

    const int rowB0 = w * 32 + (l >> 2), rowB1 = rowB0 + 16;
    const int cch = l & 3;
    const char* gB0 = (const char*)Bp + (size_t)(bn + rowB0) * rb + ((cch ^ (rowB0 & 3)) * 16);
    const char* gB1 = (const char*)Bp + (size_t)(bn + rowB1) * rb + ((cch ^ (rowB1 & 3)) * 16);
    const char* gB0l = SPLIT ? (const char*)Bl + (size_t)(bn + rowB0) * rb + ((cch ^ (rowB0 & 3)) * 16) : nullptr;
    const char* gB1l = SPLIT ? (const char*)Bl + (size_t)(bn + rowB1) * rb + ((cch ^ (rowB1 & 3)) * 16) : nullptr;
    int rowA0, rowA1;
    if constexpr (BM == 128) { rowA0 = w * 32 + (l >> 2); rowA1 = rowA0 + 16; }
    else                     { rowA0 = w * 16 + (l >> 2); rowA1 = 0; }
    const char* gA0 = (const char*)Ap + (size_t)(bm + rowA0) * rb + ((cch ^ (rowA0 & 3)) * 16);
    const char* gA1 = (BM == 128) ? (const char*)Ap + (size_t)(bm + rowA1) * rb + ((cch ^ (rowA1 & 3)) * 16) : nullptr;
    const char* gA0l = SPLIT ? (const char*)Al + (size_t)(bm + rowA0) * rb + ((cch ^ (rowA0 & 3)) * 16) : nullptr;
    const char* gA1l = (SPLIT && BM == 128) ? (const char*)Al + (size_t)(bm + rowA1) * rb + ((cch ^ (rowA1 & 3)) * 16) : nullptr;

    f32x4 acc[NM][4] = {};
    for (int k0 = 0; k0 < K; k0 += 32) {
        const size_t kb = (size_t)k0 * 2;
        GLD(gA0 + kb, (char*)AsH + ((BM == 128) ? w * 2048 : w * 1024) + l * 16);
        if constexpr (BM == 128) GLD(gA1 + kb, (char*)AsH + w * 2048 + 1024 + l * 16);
        GLD(gB0 + kb, (char*)BsH + w * 2048 + l * 16);
        GLD(gB1 + kb, (char*)BsH + w * 2048 + 1024 + l * 16);
        if constexpr (SPLIT) {
            GLD(gA0l + kb, (char*)AsL + ((BM == 128) ? w * 2048 : w * 1024) + l * 16);
            if constexpr (BM == 128) GLD(gA1l + kb, (char*)AsL + w * 2048 + 1024 + l * 16);
            GLD(gB0l + kb, (char*)BsL + w * 2048 + l * 16);
            GLD(gB1l + kb, (char*)BsL + w * 2048 + 1024 + l * 16);
        }
        __syncthreads();
        bf16x8 ah[NM], bh[4];
#pragma unroll
        for (int mi = 0; mi < NM; ++mi) {
            int r = wr * (BM / 2) + mi * 16 + lr;
            ah[mi] = *(const bf16x8*)((const char*)AsH + r * 64 + ((half ^ (r & 3)) * 16));
        }
#pragma unroll
        for (int ni = 0; ni < 4; ++ni) {
            int r = wc * 64 + ni * 16 + lr;
            bh[ni] = *(const bf16x8*)((const char*)BsH + r * 64 + ((half ^ (r & 3)) * 16));
        }
#pragma unroll
        for (int mi = 0; mi < NM; ++mi)
#pragma unroll
            for (int ni = 0; ni < 4; ++ni)
                acc[mi][ni] = __builtin_amdgcn_mfma_f32_16x16x32_bf16(ah[mi], bh[ni],
                                                                      acc[mi][ni], 0, 0, 0);
        if constexpr (SPLIT) {
            bf16x8 al[NM], bl[4];
#pragma unroll
            for (int mi = 0; mi < NM; ++mi) {
                int r = wr * (BM / 2) + mi * 16 + lr;
                al[mi] = *(const bf16x8*)((const char*)AsL + r * 64 + ((half ^ (r & 3)) * 16));
            }
#pragma unroll
            for (int ni = 0; ni < 4; ++ni) {
                int r = wc * 64 + ni * 16 + lr;
                bl[ni] = *(const bf16x8*)((const char*)BsL + r * 64 + ((half ^ (r & 3)) * 16));
            }
#pragma unroll
            for (int mi = 0; mi < NM; ++mi)
#pragma unroll
                for (int ni = 0; ni < 4; ++ni) {
                    acc[mi][ni] = __builtin_amdgcn_mfma_f32_16x16x32_bf16(ah[mi], bl[ni],
                                                                          acc[mi][ni], 0, 0, 0);
                    acc[mi][ni] = __builtin_amdgcn_mfma_f32_16x16x32_bf16(al[mi], bh[ni],
                                                                          acc[mi][ni], 0, 0, 0);
                }
        }
        __syncthreads();
    }
    // epilogue: C/D layout col=lane&15, row=(lane>>4)*4+reg
#pragma unroll
    for (int mi = 0; mi < NM; ++mi)
#pragma unroll
        for (int r = 0; r < 4; ++r) {
            int row = bm + wr * (BM / 2) + mi * 16 + half * 4 + r;
            float rs = (MODE == 1 || MODE == 3) ? rsp[(size_t)row * 4] : 0.0f;
#pragma unroll
            for (int ni = 0; ni < 4; ++ni) {
                int col = bn + wc * 64 + ni * 16 + lr;
                size_t ix = (size_t)row * N + col;
                if constexpr (MODE == 0)      C[ix] = acc[mi][ni][r];
                else if constexpr (MODE == 1) C[ix] += rs * acc[mi][ni][r];
                else if constexpr (MODE == 2) C[ix] = res[ix] + bias[col] + acc[mi][ni][r];
                else                          unsafeAtomicAdd(&C[ix], rs * acc[mi][ni][r]);
            }
        }
}

// ---------------- fused rope + split-bf16 pack of q,k (q pre-scaled by 1/8)
__global__ __launch_bounds__(256) void qk_pack(const float* __restrict__ qkv,
                                               const float* __restrict__ cs,
                                               const float* __restrict__ sn,
                                               ushort_t* __restrict__ Qh, ushort_t* __restrict__ Ql,
                                               ushort_t* __restrict__ Kh, ushort_t* __restrict__ Kl) {
    int idx = blockIdx.x * 256 + threadIdx.x;   // B*S*NH*32 = 1M
    int p = idx & 31;
    int h = (idx >> 5) & 15;
    int s = (idx >> 9) & (S_SEQ - 1);
    int b = idx >> 19;
    float c = cs[s * 32 + p], si = sn[s * 32 + p];
    long base = ((long)(b * S_SEQ + s)) * 3072 + h * 192;
    long dst = (((long)(b * NHEAD + h)) * S_SEQ + s) * 64 + 2 * p;
    float re = qkv[base + 2 * p], im = qkv[base + 2 * p + 1];
    float qre = (re * c - im * si) * 0.125f;
    float qim = (re * si + im * c) * 0.125f;
    unsigned short hh = f2bf(qre);
    Qh[dst] = hh; Ql[dst] = f2bf(qre - bf2f(hh));
    hh = f2bf(qim);
    Qh[dst + 1] = hh; Ql[dst + 1] = f2bf(qim - bf2f(hh));
    re = qkv[base + 64 + 2 * p]; im = qkv[base + 64 + 2 * p + 1];
    float kre = re * c - im * si;
    float kim = re * si + im * c;
    hh = f2bf(kre);
    Kh[dst] = hh; Kl[dst] = f2bf(kre - bf2f(hh));
    hh = f2bf(kim);
    Kh[dst + 1] = hh; Kl[dst + 1] = f2bf(kim - bf2f(hh));
}

// ---------------- V transpose + split: qkv v-part -> Vt [b][h][64 d][1024 s]
__global__ __launch_bounds__(256) void v_trans(const float* __restrict__ qkv,
                                               ushort_t* __restrict__ Vth,
                                               ushort_t* __restrict__ Vtl) {
    __shared__ float t[64][65];
    const int s0 = blockIdx.x * 64, h = blockIdx.y, b = blockIdx.z;
    const int tid = threadIdx.x;
#pragma unroll
    for (int i = 0; i < 16; ++i) {
        int e = tid + i * 256;
        int sl = e >> 6, d = e & 63;
        t[d][sl] = qkv[((long)(b * S_SEQ + s0 + sl)) * 3072 + h * 192 + 128 + d];
    }
    __syncthreads();
#pragma unroll
    for (int i = 0; i < 16; ++i) {
        int e = tid + i * 256;
        int d = e >> 6, sl = e & 63;
        float v = t[d][sl];
        long o = (((long)(b * NHEAD + h)) * 64 + d) * S_SEQ + s0 + sl;
        unsigned short hh = f2bf(v);
        Vth[o] = hh;
        Vtl[o] = f2bf(v - bf2f(hh));
    }
}

// =====================================================================
// MFMA flash attention, full hi/lo split (fp32-class accuracy).
// =====================================================================
__device__ __forceinline__ bf16x8 lds_frag(const ushort_t* base, int row, int chunk) {
    return *(const bf16x8*)((const char*)base + row * 128 + ((chunk ^ (row & 7)) * 16));
}

__global__ __launch_bounds__(256) void attn_mfma(const ushort_t* __restrict__ Qh,
                                                 const ushort_t* __restrict__ Ql,
                                                 const ushort_t* __restrict__ Kh,
                                                 const ushort_t* __restrict__ Kl,
                                                 const ushort_t* __restrict__ Vth,
                                                 const ushort_t* __restrict__ Vtl,
                                                 float* __restrict__ ctx) {
    __shared__ __align__(16) ushort_t KsH[64 * 64], KsL[64 * 64];
    __shared__ __align__(16) ushort_t VsH[64 * 64], VsL[64 * 64];
    __shared__ __align__(16) ushort_t Ps[4][2][16][72];
    const int qb = blockIdx.x * 64, h = blockIdx.y, b = blockIdx.z;
    const int tid = threadIdx.x;
    const int w = tid >> 6, l = tid & 63;
    const int lr = l & 15, g = l >> 4;
    const long bh = b * NHEAD + h;

    const long qoff = (bh * S_SEQ + qb + w * 16 + lr) * 64 + g * 8;
    bf16x8 qh0 = *(const bf16x8*)(Qh + qoff);
    bf16x8 qh1 = *(const bf16x8*)(Qh + qoff + 32);
    bf16x8 ql0 = *(const bf16x8*)(Ql + qoff);
    bf16x8 ql1 = *(const bf16x8*)(Ql + qoff + 32);

    const int rowS0 = w * 16 + (l >> 3), rowS1 = rowS0 + 8;
    const int cch = l & 7;
    const char* gK0 = (const char*)Kh + (bh * S_SEQ + rowS0) * 128 + ((cch ^ (rowS0 & 7)) * 16);
    const char* gK1 = (const char*)Kh + (bh * S_SEQ + rowS1) * 128 + ((cch ^ (rowS1 & 7)) * 16);
    const char* gKl0 = (const char*)Kl + (bh * S_SEQ + rowS0) * 128 + ((cch ^ (rowS0 & 7)) * 16);
    const char* gKl1 = (const char*)Kl + (bh * S_SEQ + rowS1) * 128 + ((cch ^ (rowS1 & 7)) * 16);
    const char* gV0 = (const char*)Vth + (bh * 64 + rowS0) * 2048 + ((cch ^ (rowS0 & 7)) * 16);
    const char* gV1 = (const char*)Vth + (bh * 64 + rowS1) * 2048 + ((cch ^ (rowS1 & 7)) * 16);
    const char* gVl0 = (const char*)Vtl + (bh * 64 + rowS0) * 2048 + ((cch ^ (rowS0 & 7)) * 16);
    const char* gVl1 = (const char*)Vtl + (bh * 64 + rowS1) * 2048 + ((cch ^ (rowS1 & 7)) * 16);

    float m_run[4] = {-1e30f, -1e30f, -1e30f, -1e30f};
    float l_run[4] = {0.f, 0.f, 0.f, 0.f};
    f32x4 acco[4] = {};

    for (int k0 = 0; k0 < S_SEQ; k0 += 64) {
        GLD(gK0 + (size_t)k0 * 128, (char*)KsH + w * 2048 + l * 16);
        GLD(gK1 + (size_t)k0 * 128, (char*)KsH + w * 2048 + 1024 + l * 16);
        GLD(gKl0 + (size_t)k0 * 128, (char*)KsL + w * 2048 + l * 16);
        GLD(gKl1 + (size_t)k0 * 128, (char*)KsL + w * 2048 + 1024 + l * 16);
        GLD(gV0 + (size_t)k0 * 2, (char*)VsH + w * 2048 + l * 16);
        GLD(gV1 + (size_t)k0 * 2, (char*)VsH + w * 2048 + 1024 + l * 16);
        GLD(gVl0 + (size_t)k0 * 2, (char*)VsL + w * 2048 + l * 16);
        GLD(gVl1 + (size_t)k0 * 2, (char*)VsL + w * 2048 + 1024 + l * 16);
        __syncthreads();

        f32x4 accs[4] = {};
#pragma unroll
        for (int n = 0; n < 4; ++n) {
            bf16x8 bkh0 = lds_frag(KsH, n * 16 + lr, g);
            bf16x8 bkh1 = lds_frag(KsH, n * 16 + lr, g + 4);
            bf16x8 bkl0 = lds_frag(KsL, n * 16 + lr, g);
            bf16x8 bkl1 = lds_frag(KsL, n * 16 + lr, g + 4);
            accs[n] = __builtin_amdgcn_mfma_f32_16x16x32_bf16(qh0, bkh0, accs[n], 0, 0, 0);
            accs[n] = __builtin_amdgcn_mfma_f32_16x16x32_bf16(qh1, bkh1, accs[n], 0, 0, 0);
            accs[n] = __builtin_amdgcn_mfma_f32_16x16x32_bf16(qh0, bkl0, accs[n], 0, 0, 0);
            accs[n] = __builtin_amdgcn_mfma_f32_16x16x32_bf16(qh1, bkl1, accs[n], 0, 0, 0);
            accs[n] = __builtin_amdgcn_mfma_f32_16x16x32_bf16(ql0, bkh0, accs[n], 0, 0, 0);
            accs[n] = __builtin_amdgcn_mfma_f32_16x16x32_bf16(ql1, bkh1, accs[n], 0, 0, 0);
        }
        float alpha[4];
#pragma unroll
        for (int r = 0; r < 4; ++r) {
            float mx = fmaxf(fmaxf(accs[0][r], accs[1][r]), fmaxf(accs[2][r], accs[3][r]));
#pragma unroll
            for (int msk = 1; msk < 16; msk <<= 1) mx = fmaxf(mx, __shfl_xor(mx, msk, 64));
            float m_new = fmaxf(m_run[r], mx);
            float ps = 0.f;
#pragma unroll
            for (int n = 0; n < 4; ++n) {
                float p = __expf(accs[n][r] - m_new);
                accs[n][r] = p;
                ps += p;
            }
#pragma unroll
            for (int msk = 1; msk < 16; msk <<= 1) ps += __shfl_xor(ps, msk, 64);
            alpha[r] = __expf(m_run[r] - m_new);
            l_run[r] = l_run[r] * alpha[r] + ps;
            m_run[r] = m_new;
        }
#pragma unroll
        for (int nd = 0; nd < 4; ++nd)
#pragma unroll
            for (int r = 0; r < 4; ++r) acco[nd][r] *= alpha[r];
#pragma unroll
        for (int n = 0; n < 4; ++n)
#pragma unroll
            for (int r = 0; r < 4; ++r) {
                float p = accs[n][r];
                unsigned short hh = f2bf(p);
                Ps[w][0][g * 4 + r][n * 16 + lr] = hh;
                Ps[w][1][g * 4 + r][n * 16 + lr] = f2bf(p - bf2f(hh));
            }
        __syncthreads();
        bf16x8 pah0 = *(const bf16x8*)&Ps[w][0][lr][g * 8];
        bf16x8 pah1 = *(const bf16x8*)&Ps[w][0][lr][32 + g * 8];
        bf16x8 pal0 = *(const bf16x8*)&Ps[w][1][lr][g * 8];
        bf16x8 pal1 = *(const bf16x8*)&Ps[w][1][lr][32 + g * 8];
#pragma unroll
        for (int nd = 0; nd < 4; ++nd) {
            bf16x8 bvh0 = lds_frag(VsH, nd * 16 + lr, g);
            bf16x8 bvh1 = lds_frag(VsH, nd * 16 + lr, g + 4);
            bf16x8 bvl0 = lds_frag(VsL, nd * 16 + lr, g);
            bf16x8 bvl1 = lds_frag(VsL, nd * 16 + lr, g + 4);
            acco[nd] = __builtin_amdgcn_mfma_f32_16x16x32_bf16(pah0, bvh0, acco[nd], 0, 0, 0);
            acco[nd] = __builtin_amdgcn_mfma_f32_16x16x32_bf16(pah1, bvh1, acco[nd], 0, 0, 0);
            acco[nd] = __builtin_amdgcn_mfma_f32_16x16x32_bf16(pah0, bvl0, acco[nd], 0, 0, 0);
            acco[nd] = __builtin_amdgcn_mfma_f32_16x16x32_bf16(pah1, bvl1, acco[nd], 0, 0, 0);
            acco[nd] = __builtin_amdgcn_mfma_f32_16x16x32_bf16(pal0, bvh0, acco[nd], 0, 0, 0);
            acco[nd] = __builtin_amdgcn_mfma_f32_16x16x32_bf16(pal1, bvh1, acco[nd], 0, 0, 0);
        }
        __syncthreads();
    }
#pragma unroll
    for (int r = 0; r < 4; ++r) {
        float inv = 1.0f / l_run[r];
        long row = (long)b * S_SEQ + qb + w * 16 + g * 4 + r;
#pragma unroll
        for (int nd = 0; nd < 4; ++nd)
            ctx[row * H_DIM + h * 64 + nd * 16 + lr] = acco[nd][r] * inv;
    }
}

// ---------------- gate: top-2 softmax weights (zeros elsewhere)
__global__ __launch_bounds__(256) void gate_kernel(const float* __restrict__ h2,
                                                   const float* __restrict__ gate_w,
                                                   float* __restrict__ gw) {
    long t = blockIdx.x;
    float sum[4] = {0, 0, 0, 0};
    for (int i = threadIdx.x; i < H_DIM; i += 256) {
        float v = h2[t * H_DIM + i];
#pragma unroll
        for (int e = 0; e < 4; ++e) sum[e] = fmaf(v, gate_w[e * H_DIM + i], sum[e]);
    }
#pragma unroll
    for (int w = 1; w < 64; w <<= 1)
#pragma unroll
        for (int e = 0; e < 4; ++e) sum[e] += __shfl_xor(sum[e], w, 64);
    __shared__ float part[4][4];
    if ((threadIdx.x & 63) == 0)
#pragma unroll
        for (int e = 0; e < 4; ++e) part[e][threadIdx.x >> 6] = sum[e];
    __syncthreads();
    if (threadIdx.x == 0) {
        float lg[4];
#pragma unroll
        for (int e = 0; e < 4; ++e) lg[e] = part[e][0] + part[e][1] + part[e][2] + part[e][3];
        int i0 = 0;
        for (int e = 1; e < 4; ++e) if (lg[e] > lg[i0]) i0 = e;
        int i1 = -1;
        for (int e = 0; e < 4; ++e) if (e != i0 && (i1 < 0 || lg[e] > lg[i1])) i1 = e;
        float mx = fmaxf(lg[i0], lg[i1]);
        float e0 = __expf(lg[i0] - mx), e1 = __expf(lg[i1] - mx);
        float inv = 1.0f / (e0 + e1);
        float o[4] = {0, 0, 0, 0};
        o[i0] = e0 * inv; o[i1] = e1 * inv;
#pragma unroll
        for (int e = 0; e < 4; ++e) gw[t * 4 + e] = o[e];
    }
}

// ================= fallback-only kernels (round-0 fp32 path) =================
#define KI 8
#define BKK 72
__global__ __launch_bounds__(256) void kan_gemm(const float* __restrict__ Act,
                                                const float* __restrict__ baseW,
                                                const float* __restrict__ splW,
                                                const float* __restrict__ scal,
                                                float* __restrict__ C,
                                                const float* __restrict__ rowScale,
                                                int rsStride, int N, int mode) {
    __shared__ float As[BKK][64];
    __shared__ float Bs[BKK][64];
    const int bm = blockIdx.y * 64;
    const int bn = blockIdx.x * 64;
    const int tid = threadIdx.x;
    const int tx = tid & 15, ty = tid >> 4;
    float acc[4][4] = {};
    for (int i0 = 0; i0 < H_DIM; i0 += KI) {
        for (int e = tid; e < 64 * KI; e += 256) {
            int m = e >> 3, ii = e & 7;
            float xv = Act[(long)(bm + m) * H_DIM + i0 + ii];
            float sp[8];
            bspline8(xv, sp);
            As[ii * 9][m] = xv * sigmoidf_(xv);
#pragma unroll
            for (int c = 0; c < 8; ++c) As[ii * 9 + 1 + c][m] = sp[c];
        }
        for (int e = tid; e < 64 * KI; e += 256) {
            int n = e >> 3, ii = e & 7;
            long w = (long)(bn + n) * H_DIM + i0 + ii;
            float sc = scal[w];
            Bs[ii * 9][n] = baseW[w];
            const float4* sp4 = (const float4*)(splW + w * 8);
            float4 s0 = sp4[0], s1 = sp4[1];
            Bs[ii * 9 + 1][n] = s0.x * sc; Bs[ii * 9 + 2][n] = s0.y * sc;
            Bs[ii * 9 + 3][n] = s0.z * sc; Bs[ii * 9 + 4][n] = s0.w * sc;
            Bs[ii * 9 + 5][n] = s1.x * sc; Bs[ii * 9 + 6][n] = s1.y * sc;
            Bs[ii * 9 + 7][n] = s1.z * sc; Bs[ii * 9 + 8][n] = s1.w * sc;
        }
        __syncthreads();
#pragma unroll 8
        for (int k = 0; k < BKK; ++k) {
            float4 a = *(const float4*)&As[k][ty * 4];
            float4 b = *(const float4*)&Bs[k][tx * 4];
            float av[4] = {a.x, a.y, a.z, a.w};
            float bv[4] = {b.x, b.y, b.z, b.w};
#pragma unroll
            for (int i = 0; i < 4; ++i)
#pragma unroll
                for (int j = 0; j < 4; ++j) acc[i][j] = fmaf(av[i], bv[j], acc[i][j]);
        }
        __syncthreads();
    }
#pragma unroll
    for (int i = 0; i < 4; ++i) {
        long m = bm + ty * 4 + i;
        float rs = (mode == 1) ? rowScale[m * rsStride] : 0.0f;
#pragma unroll
        for (int j = 0; j < 4; ++j) {
            long idx = m * (long)N + bn + tx * 4 + j;
            if (mode == 0) C[idx] = acc[i][j];
            else           C[idx] += rs * acc[i][j];
        }
    }
}

__global__ __launch_bounds__(256) void gemm_bias_res(const float* __restrict__ A,
                                                     const float* __restrict__ Bw,
                                                     const float* __restrict__ bias,
                                                     const float* __restrict__ res,
                                                     float* __restrict__ C) {
    __shared__ float As[16][64];
    __shared__ float Bs[16][64];
    const int bm = blockIdx.y * 64, bn = blockIdx.x * 64;
    const int tid = threadIdx.x;
    const int tx = tid & 15, ty = tid >> 4;
    float acc[4][4] = {};
    for (int k0 = 0; k0 < 1024; k0 += 16) {
        for (int e = tid; e < 1024; e += 256) {
            int r = e >> 4, kk = e & 15;
            As[kk][r] = A[(long)(bm + r) * 1024 + k0 + kk];
            Bs[kk][r] = Bw[(long)(bn + r) * 1024 + k0 + kk];
        }
        __syncthreads();
#pragma unroll
        for (int k = 0; k < 16; ++k) {
            float4 a = *(const float4*)&As[k][ty * 4];
            float4 b = *(const float4*)&Bs[k][tx * 4];
            float av[4] = {a.x, a.y, a.z, a.w};
            float bv[4] = {b.x, b.y, b.z, b.w};
#pragma unroll
            for (int i = 0; i < 4; ++i)
#pragma unroll
                for (int j = 0; j < 4; ++j) acc[i][j] = fmaf(av[i], bv[j], acc[i][j]);
        }
        __syncthreads();
    }
#pragma unroll
    for (int i = 0; i < 4; ++i) {
        long m = bm + ty * 4 + i;
#pragma unroll
        for (int j = 0; j < 4; ++j) {
            long n = bn + tx * 4 + j;
            C[m * 1024 + n] = res[m * 1024 + n] + bias[n] + acc[i][j];
        }
    }
}

__global__ __launch_bounds__(256) void rope_kernel(float* __restrict__ qkv,
                                                   const float* __restrict__ cs,
                                                   const float* __restrict__ sn) {
    int idx = blockIdx.x * 256 + threadIdx.x;
    if (idx >= T_TOK * NHEAD * 32) return;
    int p = idx & 31;
    int n = (idx >> 5) & 15;
    int t = idx >> 9;
    int s = t & (S_SEQ - 1);
    float c = cs[s * 32 + p], si = sn[s * 32 + p];
    long base = (long)t * 3072 + n * 192;
    float re = qkv[base + 2 * p], im = qkv[base + 2 * p + 1];
    qkv[base + 2 * p]     = re * c - im * si;
    qkv[base + 2 * p + 1] = re * si + im * c;
    re = qkv[base + 64 + 2 * p]; im = qkv[base + 64 + 2 * p + 1];
    qkv[base + 64 + 2 * p]     = re * c - im * si;
    qkv[base + 64 + 2 * p + 1] = re * si + im * c;
}

__global__ __launch_bounds__(256) void attn_kernel(const float* __restrict__ qkv,
                                                   float* __restrict__ ctx) {
    const int qb = blockIdx.x * 32;
    const int h = blockIdx.y, b = blockIdx.z;
    __shared__ float Qs[32][64];
    __shared__ float Ks[64][64];
    __shared__ float Vs[64][64];
    __shared__ float Ss[32][64];
    const int tid = threadIdx.x;
    const int q = tid >> 3, g = tid & 7;
    for (int e = tid; e < 32 * 64; e += 256) {
        int r = e >> 6, d = e & 63;
        Qs[r][d] = qkv[(long)(b * S_SEQ + qb + r) * 3072 + h * 192 + d];
    }
    float m_run = -1e30f, l_run = 0.0f;
    float acc[8] = {};
    for (int k0 = 0; k0 < S_SEQ; k0 += 64) {
        for (int e = tid; e < 64 * 64; e += 256) {
            int r = e >> 6, d = e & 63;
            long base = (long)(b * S_SEQ + k0 + r) * 3072 + h * 192;
            Ks[r][d] = qkv[base + 64 + d];
            Vs[r][d] = qkv[base + 128 + d];
        }
        __syncthreads();
        float s[8];
#pragma unroll
        for (int kk = 0; kk < 8; ++kk) {
            int k = g * 8 + kk;
            float dot = 0.0f;
#pragma unroll
            for (int d = 0; d < 64; ++d) dot = fmaf(Qs[q][d], Ks[k][d], dot);
            s[kk] = dot * 0.125f;
        }
        float mx = s[0];
#pragma unroll
        for (int kk = 1; kk < 8; ++kk) mx = fmaxf(mx, s[kk]);
#pragma unroll
        for (int w = 1; w < 8; w <<= 1) mx = fmaxf(mx, __shfl_xor(mx, w, 64));
        float m_new = fmaxf(m_run, mx);
        float p[8], ls = 0.0f;
#pragma unroll
        for (int kk = 0; kk < 8; ++kk) { p[kk] = __expf(s[kk] - m_new); ls += p[kk]; }
#pragma unroll
        for (int w = 1; w < 8; w <<= 1) ls += __shfl_xor(ls, w, 64);
        float alpha = __expf(m_run - m_new);
        l_run = l_run * alpha + ls;
        m_run = m_new;
#pragma unroll
        for (int kk = 0; kk < 8; ++kk) Ss[q][g * 8 + kk] = p[kk];
        __syncthreads();
#pragma unroll
        for (int j = 0; j < 8; ++j) acc[j] *= alpha;
        for (int k = 0; k < 64; ++k) {
            float pv = Ss[q][k];
#pragma unroll
            for (int j = 0; j < 8; ++j) acc[j] = fmaf(pv, Vs[k][g * 8 + j], acc[j]);
        }
        __syncthreads();
    }
    float inv = 1.0f / l_run;
#pragma unroll
    for (int j = 0; j < 8; ++j)
        ctx[(long)(b * S_SEQ + qb + q) * H_DIM + h * 64 + g * 8 + j] = acc[j] * inv;
}

__global__ __launch_bounds__(256) void mul_kernel(const float* __restrict__ a,
                                                  const float* __restrict__ b,
                                                  float* __restrict__ c, int n) {
    int i = blockIdx.x * 256 + threadIdx.x;
    if (i < n) c[i] = a[i] * b[i];
}

extern "C" void kernel_launch(void* const* d_in, const int* in_sizes, int n_in,
                              void* d_out, int out_size, void* d_ws, size_t ws_size,
                              hipStream_t stream) {
    const float* x          = (const float*)d_in[0];
    const float* rot_cos    = (const float*)d_in[1];
    const float* rot_sin    = (const float*)d_in[2];
    const float* norm1_w    = (const float*)d_in[3];
    const float* norm2_w    = (const float*)d_in[4];
    const float* qkv_base   = (const float*)d_in[5];
    const float* qkv_spline = (const float*)d_in[6];
    const float* qkv_scaler = (const float*)d_in[7];
    const float* out_w      = (const float*)d_in[8];
    const float* out_b      = (const float*)d_in[9];
    const float* gate_w     = (const float*)d_in[10];
    const float* w1_base    = (const float*)d_in[11];
    const float* w1_spline  = (const float*)d_in[12];
    const float* w1_scaler  = (const float*)d_in[13];
    const float* w2_base    = (const float*)d_in[14];
    const float* w2_spline  = (const float*)d_in[15];
    const float* w2_scaler  = (const float*)d_in[16];
    const float* w3_base    = (const float*)d_in[17];
    const float* w3_spline  = (const float*)d_in[18];
    const float* w3_scaler  = (const float*)d_in[19];
    float* out = (float*)d_out;

    const size_t SZ_AUG  = (size_t)T_TOK * KAUG * 2;   // 37,748,736
    const size_t SZ_WQ   = (size_t)3072 * KAUG * 2;    // 56,623,104
    const size_t SZ_QKV  = (size_t)T_TOK * 3072 * 4;   // 25,165,824
    const size_t SZ_G12  = (size_t)T_TOK * 2048 * 4;   // 16,777,216
    const size_t SZ_TOK  = (size_t)T_TOK * H_DIM * 4;  //  8,388,608
    const size_t NEED = 2 * SZ_AUG + 2 * SZ_WQ + SZ_QKV + SZ_G12 + 2 * SZ_TOK + 32768;

    if (ws_size >= NEED) {
        char* pool = (char*)d_ws;
        // ---- attention-phase overlay (same addresses as round 3) ----
        ushort_t* A_hi = (ushort_t*)pool;
        ushort_t* A_lo = (ushort_t*)(pool + SZ_AUG);
        char* W1p = pool + 2 * SZ_AUG;
        char* W2p = pool + 2 * SZ_AUG + SZ_WQ;
        float* qkv = (float*)(pool + 2 * SZ_AUG + 2 * SZ_WQ);
        float* ctx = (float*)(pool + 2 * SZ_AUG + 2 * SZ_WQ + SZ_QKV + SZ_G12);
        float* tok = (float*)(pool + 2 * SZ_AUG + 2 * SZ_WQ + SZ_QKV + SZ_G12 + SZ_TOK);
        float* gw  = (float*)(pool + NEED - 32768);
        ushort_t* W1b = (ushort_t*)W1p;
        ushort_t* W2b = (ushort_t*)W2p;
        const size_t SZ_P = (size_t)T_TOK * 1024 * 2;  // 4 MB
        ushort_t* Qh  = (ushort_t*)W1p;
        ushort_t* Ql  = (ushort_t*)(W1p + SZ_P);
        ushort_t* Kh  = (ushort_t*)(W1p + 2 * SZ_P);
        ushort_t* Kl  = (ushort_t*)(W1p + 3 * SZ_P);
        ushort_t* Vth = (ushort_t*)(W1p + 4 * SZ_P);
        ushort_t* Vtl = (ushort_t*)(W1p + 5 * SZ_P);
        ushort_t* CtxH = (ushort_t*)W2p;
        ushort_t* CtxL = (ushort_t*)(W2p + SZ_P);
        ushort_t* OWh  = (ushort_t*)(W2p + 2 * SZ_P);
        ushort_t* OWl  = (ushort_t*)(W2p + 2 * SZ_P + SZ_P / 2);
        // ---- MoE-phase overlay (lifetimes verified disjoint, stream-ordered) ----
        const size_t SZ_G4 = (size_t)T_TOK * 4096 * 4;          // 33,554,432
        ushort_t* A2   = (ushort_t*)pool;                       // h2 packed     [0, 37.7M)
        ushort_t* W12  = (ushort_t*)(pool + SZ_AUG);            // 4096xKAUG     [37.7, 113.2M)
        float*    g1a  = (float*)(pool + NEED - 32768 - 2 * SZ_G4);  // [180.4, 213.9M)
        float*    g2a  = (float*)(pool + NEED - 32768 - SZ_G4);      // [213.9, 247.5M)
        ushort_t* Gall = (ushort_t*)pool;                       // 4x(T x KAUG)  [0, 151.0M)
        ushort_t* W3a  = (ushort_t*)(pool + 4 * SZ_AUG);        // 4096xKAUG     [151.0, 226.5M)

        // --- attention branch: split-bf16 everywhere upstream of the gate ---
        rmsnorm_kernel<<<T_TOK, 256, 0, stream>>>(x, norm1_w, tok);
        pack_act<<<(T_TOK * 1024) / 256, 256, 0, stream>>>(tok, A_hi, A_lo);
        pack_w<<<(3072 * 1024) / 256, 256, 0, stream>>>(qkv_base, qkv_spline, qkv_scaler,
                                                        W1b, W2b, (long)3072 * 1024);
        mfma_gemm2<128, 1, 0><<<dim3(3072 / 128, T_TOK / 128), 256, 0, stream>>>(
            A_hi, A_lo, W1b, W2b, qkv, nullptr, nullptr, nullptr, 3072, KAUG);
        qk_pack<<<(T_TOK * NHEAD * 32) / 256, 256, 0, stream>>>(qkv, rot_cos, rot_sin,
                                                                Qh, Ql, Kh, Kl);
        v_trans<<<dim3(S_SEQ / 64, NHEAD, 2), 256, 0, stream>>>(qkv, Vth, Vtl);
        attn_mfma<<<dim3(S_SEQ / 64, NHEAD, 2), 256, 0, stream>>>(Qh, Ql, Kh, Kl,
                                                                  Vth, Vtl, ctx);
        split_pack<<<(T_TOK * 1024) / 256, 256, 0, stream>>>(ctx, CtxH, CtxL,
                                                             (long)T_TOK * 1024);
        split_pack<<<(1024 * 1024) / 256, 256, 0, stream>>>(out_w, OWh, OWl,
                                                            (long)1024 * 1024);
        mfma_gemm2<128, 1, 2><<<dim3(1024 / 128, T_TOK / 128), 256, 0, stream>>>(
            CtxH, CtxL, OWh, OWl, out, nullptr, out_b, x, 1024, 1024);
        rmsnorm_kernel<<<T_TOK, 256, 0, stream>>>(out, norm2_w, tok);
        gate_kernel<<<T_TOK, 256, 0, stream>>>(tok, gate_w, gw);

        // --- MoE: batched across experts, plain bf16 (downstream of gate) ---
        pack_act<<<(T_TOK * 1024) / 256, 256, 0, stream>>>(tok, A2, nullptr);
        // w1 of all 4 experts (E-major layout is already row-contiguous)
        pack_w<<<(4 * 1024 * 1024) / 256, 256, 0, stream>>>(
            w1_base, w1_spline, w1_scaler, W12, nullptr, (long)4 * 1024 * 1024);
        mfma_gemm2<128, 0, 0><<<dim3(4096 / 128, T_TOK / 128), 256, 0, stream>>>(
            A2, nullptr, W12, nullptr, g1a, nullptr, nullptr, nullptr, 4096, KAUG);
        pack_w<<<(4 * 1024 * 1024) / 256, 256, 0, stream>>>(
            w2_base, w2_spline, w2_scaler, W12, nullptr, (long)4 * 1024 * 1024);
        mfma_gemm2<128, 0, 0><<<dim3(4096 / 128, T_TOK / 128), 256, 0, stream>>>(
            A2, nullptr, W12, nullptr, g2a, nullptr, nullptr, nullptr, 4096, KAUG);
        // G_e = augment(g1*g2) for all experts (overwrites A2/W12 - both dead)
        mul_pack4<<<(T_TOK * 4096) / 256, 256, 0, stream>>>(g1a, g2a, Gall);
        // w3 of all 4 experts (overwrites g-region tails - dead after mul_pack4)
        pack_w<<<(4 * 1024 * 1024) / 256, 256, 0, stream>>>(
            w3_base, w3_spline, w3_scaler, W3a, nullptr, (long)4 * 1024 * 1024);
        // batched w3: out += gw[t,e] * (G_e @ W3_e^T), z = expert, atomicAdd
        mfma_gemm2<128, 0, 3><<<dim3(1024 / 128, T_TOK / 128, E_EXP), 256, 0, stream>>>(
            Gall, nullptr, W3a, nullptr, out, gw, nullptr, nullptr, 1024, KAUG);
        return;
    }

    // ---- fallback: fp32 path ----
    char* ws = (char*)d_ws;
    float* hn  = (float*)ws; ws += (size_t)T_TOK * H_DIM * 4;
    float* qkv = (float*)ws; ws += (size_t)T_TOK * 3072 * 4;
    float* ctx = (float*)ws; ws += (size_t)T_TOK * H_DIM * 4;
    float* h2  = (float*)ws; ws += (size_t)T_TOK * H_DIM * 4;
    float* gw  = (float*)ws; ws += (size_t)T_TOK * E_EXP * 4;
    float* g1  = (float*)ws; ws += (size_t)T_TOK * DFF_ * 4;
    float* g2  = (float*)ws; ws += (size_t)T_TOK * DFF_ * 4;
    float* gm  = (float*)ws; ws += (size_t)T_TOK * DFF_ * 4;

    rmsnorm_kernel<<<T_TOK, 256, 0, stream>>>(x, norm1_w, hn);
    dim3 gq(3072 / 64, T_TOK / 64);
    kan_gemm<<<gq, 256, 0, stream>>>(hn, qkv_base, qkv_spline, qkv_scaler, qkv,
                                     nullptr, 0, 3072, 0);
    rope_kernel<<<(T_TOK * NHEAD * 32) / 256, 256, 0, stream>>>(qkv, rot_cos, rot_sin);
    dim3 ga(S_SEQ / 32, NHEAD, 2);
    attn_kernel<<<ga, 256, 0, stream>>>(qkv, ctx);
    dim3 go(1024 / 64, T_TOK / 64);
    gemm_bias_res<<<go, 256, 0, stream>>>(ctx, out_w, out_b, x, out);
    rmsnorm_kernel<<<T_TOK, 256, 0, stream>>>(out, norm2_w, h2);
    gate_kernel<<<T_TOK, 256, 0, stream>>>(h2, gate_w, gw);
    dim3 ge(1024 / 64, T_TOK / 64);
    for (int e = 0; e < E_EXP; ++e) {
        long wo = (long)e * DFF_ * H_DIM;
        kan_gemm<<<ge, 256, 0, stream>>>(h2, w1_base + wo, w1_spline + wo * 8,
                                         w1_scaler + wo, g1, nullptr, 0, DFF_, 0);
        kan_gemm<<<ge, 256, 0, stream>>>(h2, w2_base + wo, w2_spline + wo * 8,
                                         w2_scaler + wo, g2, nullptr, 0, DFF_, 0);
        mul_kernel<<<(T_TOK * DFF_) / 256, 256, 0, stream>>>(g1, g2, gm, T_TOK * DFF_);
        kan_gemm<<<ge, 256, 0, stream>>>(gm, w3_base + wo, w3_spline + wo * 8,
                                         w3_scaler + wo, out, gw + e, E_EXP, H_DIM, 1);
    }
}

// Round 5
// 1490.454 us; speedup vs baseline: 8.0965x; 1.0653x over previous
//
#include <hip/hip_runtime.h>
#include <hip/hip_bf16.h>

// KANBlock: B=2,S=1024,H=1024,NH=16,HD=64,DFF=1024,E=4,TOPK=2, NB=8 spline bases
#define T_TOK 2048
#define H_DIM 1024
#define S_SEQ 1024
#define NHEAD 16
#define E_EXP 4
#define DFF_  1024
#define KAUG  9216   // 9*1024 augmented K (k = c*1024 + i; c=0 silu, c=1..8 splines)

typedef __bf16 bf16x8 __attribute__((ext_vector_type(8)));
typedef float  f32x4  __attribute__((ext_vector_type(4)));
typedef unsigned short ushort_t;

__device__ __forceinline__ float sigmoidf_(float x) { return 1.0f / (1.0f + __expf(-x)); }

__device__ __forceinline__ unsigned short f2bf(float f) {   // RNE f32 -> bf16 bits
    unsigned int u = __float_as_uint(f);
    u = (u + 0x7fffu + ((u >> 16) & 1u)) >> 16;
    return (unsigned short)u;
}
__device__ __forceinline__ float bf2f(unsigned short h) {
    return __uint_as_float(((unsigned int)h) << 16);
}

// Cubic B-spline bases, matches reference b_splines() (verified round 0)
__device__ __forceinline__ void bspline8(float x, float* o) {
    float b[11];
#pragma unroll
    for (int m = 0; m < 11; ++m) {
        float g0 = 0.4f * (float)(m - 3) - 1.0f;
        float g1 = 0.4f * (float)(m - 2) - 1.0f;
        b[m] = (x >= g0 && x < g1) ? 1.0f : 0.0f;
    }
#pragma unroll
    for (int j = 1; j <= 3; ++j) {
        float inv = 1.0f / (0.4f * (float)j);
#pragma unroll
        for (int m = 0; m + j < 11; ++m) {
            float gm   = 0.4f * (float)(m - 3) - 1.0f;
            float gmj1 = 0.4f * (float)(m + j - 2) - 1.0f;
            b[m] = ((x - gm) * b[m] + (gmj1 - x) * b[m + 1]) * inv;
        }
    }
#pragma unroll
    for (int c = 0; c < 8; ++c) o[c] = b[c];
}

// ---------------- RMSNorm
__global__ __launch_bounds__(256) void rmsnorm_kernel(const float* __restrict__ x,
                                                      const float* __restrict__ w,
                                                      float* __restrict__ out) {
    long t = blockIdx.x;
    float4 v = ((const float4*)(x + t * H_DIM))[threadIdx.x];
    float ss = v.x * v.x + v.y * v.y + v.z * v.z + v.w * v.w;
#pragma unroll
    for (int m = 1; m < 64; m <<= 1) ss += __shfl_xor(ss, m, 64);
    __shared__ float wsum[4];
    if ((threadIdx.x & 63) == 0) wsum[threadIdx.x >> 6] = ss;
    __syncthreads();
    ss = wsum[0] + wsum[1] + wsum[2] + wsum[3];
    float sc = rsqrtf(ss * (1.0f / (float)H_DIM) + 1e-6f);
    float4 wv = ((const float4*)w)[threadIdx.x];
    float4 r;
    r.x = v.x * sc * wv.x; r.y = v.y * sc * wv.y;
    r.z = v.z * sc * wv.z; r.w = v.w * sc * wv.w;
    ((float4*)(out + t * H_DIM))[threadIdx.x] = r;
}

// ---------------- out prefill: out = x + bias (before atomic split-K out-proj)
__global__ __launch_bounds__(256) void prefill_out(const float* __restrict__ x,
                                                   const float* __restrict__ bias,
                                                   float* __restrict__ out) {
    long i = (long)blockIdx.x * 256 + threadIdx.x;   // T*H/4
    float4 xv = ((const float4*)x)[i];
    float4 bv = ((const float4*)bias)[i & 255];
    float4 r;
    r.x = xv.x + bv.x; r.y = xv.y + bv.y; r.z = xv.z + bv.z; r.w = xv.w + bv.w;
    ((float4*)out)[i] = r;
}

// ---------------- pack activations -> augmented bf16 (hi, optional lo)
__global__ __launch_bounds__(256) void pack_act(const float* __restrict__ act,
                                                ushort_t* __restrict__ hi,
                                                ushort_t* __restrict__ lo) {
    long idx = (long)blockIdx.x * 256 + threadIdx.x;
    long m = idx >> 10; int i = (int)(idx & 1023);
    float v = act[idx];
    float ch[9];
    ch[0] = v * sigmoidf_(v);
    bspline8(v, ch + 1);
    ushort_t* oh = hi + m * (long)KAUG + i;
#pragma unroll
    for (int c = 0; c < 9; ++c) oh[(long)c * 1024] = f2bf(ch[c]);
    if (lo) {
        ushort_t* ol = lo + m * (long)KAUG + i;
#pragma unroll
        for (int c = 0; c < 9; ++c) {
            unsigned short h = f2bf(ch[c]);
            ol[(long)c * 1024] = f2bf(ch[c] - bf2f(h));
        }
    }
}

// ---------------- pack weights -> augmented bf16: [base | spline*scaler]
__global__ __launch_bounds__(256) void pack_w(const float* __restrict__ base,
                                              const float* __restrict__ spl,
                                              const float* __restrict__ scal,
                                              ushort_t* __restrict__ hi,
                                              ushort_t* __restrict__ lo,
                                              long total) {
    long idx = (long)blockIdx.x * 256 + threadIdx.x;
    if (idx >= total) return;
    long n = idx >> 10; int i = (int)(idx & 1023);
    float sc = scal[idx];
    const float4* s4 = (const float4*)(spl + idx * 8);
    float4 s0 = s4[0], s1 = s4[1];
    float ch[9] = {base[idx], s0.x * sc, s0.y * sc, s0.z * sc, s0.w * sc,
                   s1.x * sc, s1.y * sc, s1.z * sc, s1.w * sc};
    ushort_t* oh = hi + n * (long)KAUG + i;
#pragma unroll
    for (int c = 0; c < 9; ++c) oh[(long)c * 1024] = f2bf(ch[c]);
    if (lo) {
        ushort_t* ol = lo + n * (long)KAUG + i;
#pragma unroll
        for (int c = 0; c < 9; ++c) {
            unsigned short h = f2bf(ch[c]);
            ol[(long)c * 1024] = f2bf(ch[c] - bf2f(h));
        }
    }
}

// ---------------- batched: v = g1*g2 (bf16 inputs from merged g12) -> 4 G's
// g12 layout [t][8192]: cols 0..4095 = w1 out (e*1024+d), 4096.. = w2 out
__global__ __launch_bounds__(256) void mul_pack4(const ushort_t* __restrict__ g12,
                                                 ushort_t* __restrict__ G) {
    long idx = (long)blockIdx.x * 256 + threadIdx.x;   // T_TOK*4096
    long t = idx >> 12; int ei = (int)(idx & 4095);
    int e = ei >> 10, i = ei & 1023;
    float g1 = bf2f(g12[t * 8192 + ei]);
    float g2 = bf2f(g12[t * 8192 + 4096 + ei]);
    float v = g1 * g2;
    float ch[9];
    ch[0] = v * sigmoidf_(v);
    bspline8(v, ch + 1);
    ushort_t* oh = G + ((long)e * T_TOK + t) * (long)KAUG + i;
#pragma unroll
    for (int c = 0; c < 9; ++c) oh[(long)c * 1024] = f2bf(ch[c]);
}

// ---------------- elementwise f32 -> bf16 hi/lo split
__global__ __launch_bounds__(256) void split_pack(const float* __restrict__ in,
                                                  ushort_t* __restrict__ hi,
                                                  ushort_t* __restrict__ lo, long n) {
    long i = (long)blockIdx.x * 256 + threadIdx.x;
    if (i >= n) return;
    float v = in[i];
    unsigned short h = f2bf(v);
    hi[i] = h;
    lo[i] = f2bf(v - bf2f(h));
}

// =====================================================================
// MFMA GEMM (m97 structure): C(M,N) = A(M,K) @ B(N,K)^T, bf16 ops fp32 acc.
// BM x 128 tile, BK=32, 4 waves (2x2). 2-bit XOR chunk swizzle on LDS
// (pre-swizzled global source). SPLIT: 3-pass hi/lo (fp32-class).
// MODE 0: C = acc (fp32)
// MODE 3: expert+splitK batched: z=(e,kk); A+=e*M*K, B+=e*N*K;
//         atomicAdd C += rowScale[row*4+e]*acc
// MODE 5: splitK: z=kk; atomicAdd C += acc (C pre-zeroed/prefilled)
// MODE 6: C bf16 = acc (merged w1w2 output)
// =====================================================================
#define GLD(gp, lp) __builtin_amdgcn_global_load_lds( \
    (const __attribute__((address_space(1))) void*)(gp), \
    (__attribute__((address_space(3))) void*)(lp), 16, 0, 0)

template<int BM, int SPLIT, int MODE, int KSPLIT>
__global__ __launch_bounds__(256) void mfma_gemm2(const ushort_t* __restrict__ Ah,
                                                  const ushort_t* __restrict__ Al,
                                                  const ushort_t* __restrict__ Bh,
                                                  const ushort_t* __restrict__ Bl,
                                                  float* __restrict__ C,
                                                  const float* __restrict__ rowScale,
                                                  int N, int K) {
    constexpr int NM = BM / 32;            // A fragments per wave
    __shared__ __align__(16) ushort_t AsH[BM * 32];
    __shared__ __align__(16) ushort_t BsH[128 * 32];
    __shared__ __align__(16) ushort_t AsL[SPLIT ? BM * 32 : 16];
    __shared__ __align__(16) ushort_t BsL[SPLIT ? 128 * 32 : 16];
    const int bm = blockIdx.y * BM, bn = blockIdx.x * 128;

    const int KC = K / KSPLIT;
    int e = 0, kk = 0;
    if constexpr (MODE == 3) { e = blockIdx.z / KSPLIT; kk = blockIdx.z % KSPLIT; }
    else if constexpr (KSPLIT > 1) { kk = blockIdx.z; }
    const ushort_t* Ap = Ah + (MODE == 3 ? (size_t)e * (size_t)gridDim.y * BM * K : 0)
                            + (size_t)kk * KC;
    const ushort_t* Bp = Bh + (MODE == 3 ? (size_t)e * (size_t)N * K : 0)
                            + (size_t)kk * KC;
    const ushort_t* Alp = SPLIT ? Al + (size_t)kk * KC : nullptr;
    const ushort_t* Blp = SPLIT ? Bl + (size_t)kk * KC : nullptr;
    const float* rsp = rowScale + (MODE == 3 ? e : 0);

    const int tid = threadIdx.x;
    const int w = tid >> 6, l = tid & 63;
    const int wr = w >> 1, wc = w & 1;
    const int half = l >> 4, lr = l & 15;
    const size_t rb = (size_t)K * 2;       // full row bytes

    const int rowB0 = w * 32 + (l >> 2), rowB1 = rowB0 + 16;
    const int cch = l & 3;
    const char* gB0 = (const char*)Bp + (size_t)(bn + rowB0) * rb + ((cch ^ (rowB0 & 3)) * 16);
    const char* gB1 = (const char*)Bp + (size_t)(bn + rowB1) * rb + ((cch ^ (rowB1 & 3)) * 16);
    const char* gB0l = SPLIT ? (const char*)Blp + (size_t)(bn + rowB0) * rb + ((cch ^ (rowB0 & 3)) * 16) : nullptr;
    const char* gB1l = SPLIT ? (const char*)Blp + (size_t)(bn + rowB1) * rb + ((cch ^ (rowB1 & 3)) * 16) : nullptr;
    int rowA0, rowA1;
    if constexpr (BM == 128) { rowA0 = w * 32 + (l >> 2); rowA1 = rowA0 + 16; }
    else                     { rowA0 = w * 16 + (l >> 2); rowA1 = 0; }
    const char* gA0 = (const char*)Ap + (size_t)(bm + rowA0) * rb + ((cch ^ (rowA0 & 3)) * 16);
    const char* gA1 = (BM == 128) ? (const char*)Ap + (size_t)(bm + rowA1) * rb + ((cch ^ (rowA1 & 3)) * 16) : nullptr;
    const char* gA0l = SPLIT ? (const char*)Alp + (size_t)(bm + rowA0) * rb + ((cch ^ (rowA0 & 3)) * 16) : nullptr;
    const char* gA1l = (SPLIT && BM == 128) ? (const char*)Alp + (size_t)(bm + rowA1) * rb + ((cch ^ (rowA1 & 3)) * 16) : nullptr;

    f32x4 acc[NM][4] = {};
    for (int k0 = 0; k0 < KC; k0 += 32) {
        const size_t kb = (size_t)k0 * 2;
        GLD(gA0 + kb, (char*)AsH + ((BM == 128) ? w * 2048 : w * 1024) + l * 16);
        if constexpr (BM == 128) GLD(gA1 + kb, (char*)AsH + w * 2048 + 1024 + l * 16);
        GLD(gB0 + kb, (char*)BsH + w * 2048 + l * 16);
        GLD(gB1 + kb, (char*)BsH + w * 2048 + 1024 + l * 16);
        if constexpr (SPLIT) {
            GLD(gA0l + kb, (char*)AsL + ((BM == 128) ? w * 2048 : w * 1024) + l * 16);
            if constexpr (BM == 128) GLD(gA1l + kb, (char*)AsL + w * 2048 + 1024 + l * 16);
            GLD(gB0l + kb, (char*)BsL + w * 2048 + l * 16);
            GLD(gB1l + kb, (char*)BsL + w * 2048 + 1024 + l * 16);
        }
        __syncthreads();
        bf16x8 ah[NM], bh[4];
#pragma unroll
        for (int mi = 0; mi < NM; ++mi) {
            int r = wr * (BM / 2) + mi * 16 + lr;
            ah[mi] = *(const bf16x8*)((const char*)AsH + r * 64 + ((half ^ (r & 3)) * 16));
        }
#pragma unroll
        for (int ni = 0; ni < 4; ++ni) {
            int r = wc * 64 + ni * 16 + lr;
            bh[ni] = *(const bf16x8*)((const char*)BsH + r * 64 + ((half ^ (r & 3)) * 16));
        }
#pragma unroll
        for (int mi = 0; mi < NM; ++mi)
#pragma unroll
            for (int ni = 0; ni < 4; ++ni)
                acc[mi][ni] = __builtin_amdgcn_mfma_f32_16x16x32_bf16(ah[mi], bh[ni],
                                                                      acc[mi][ni], 0, 0, 0);
        if constexpr (SPLIT) {
            bf16x8 al[NM], bl[4];
#pragma unroll
            for (int mi = 0; mi < NM; ++mi) {
                int r = wr * (BM / 2) + mi * 16 + lr;
                al[mi] = *(const bf16x8*)((const char*)AsL + r * 64 + ((half ^ (r & 3)) * 16));
            }
#pragma unroll
            for (int ni = 0; ni < 4; ++ni) {
                int r = wc * 64 + ni * 16 + lr;
                bl[ni] = *(const bf16x8*)((const char*)BsL + r * 64 + ((half ^ (r & 3)) * 16));
            }
#pragma unroll
            for (int mi = 0; mi < NM; ++mi)
#pragma unroll
                for (int ni = 0; ni < 4; ++ni) {
                    acc[mi][ni] = __builtin_amdgcn_mfma_f32_16x16x32_bf16(ah[mi], bl[ni],
                                                                          acc[mi][ni], 0, 0, 0);
                    acc[mi][ni] = __builtin_amdgcn_mfma_f32_16x16x32_bf16(al[mi], bh[ni],
                                                                          acc[mi][ni], 0, 0, 0);
                }
        }
        __syncthreads();
    }
    // epilogue: C/D layout col=lane&15, row=(lane>>4)*4+reg
#pragma unroll
    for (int mi = 0; mi < NM; ++mi)
#pragma unroll
        for (int r = 0; r < 4; ++r) {
            int row = bm + wr * (BM / 2) + mi * 16 + half * 4 + r;
            float rs = (MODE == 3) ? rsp[(size_t)row * 4] : 0.0f;
#pragma unroll
            for (int ni = 0; ni < 4; ++ni) {
                int col = bn + wc * 64 + ni * 16 + lr;
                size_t ix = (size_t)row * N + col;
                if constexpr (MODE == 0)      C[ix] = acc[mi][ni][r];
                else if constexpr (MODE == 3) unsafeAtomicAdd(&C[ix], rs * acc[mi][ni][r]);
                else if constexpr (MODE == 5) unsafeAtomicAdd(&C[ix], acc[mi][ni][r]);
                else                          ((ushort_t*)C)[ix] = f2bf(acc[mi][ni][r]);
            }
        }
}

// ---------------- fused rope + split-bf16 pack of q,k (q pre-scaled by 1/8)
__global__ __launch_bounds__(256) void qk_pack(const float* __restrict__ qkv,
                                               const float* __restrict__ cs,
                                               const float* __restrict__ sn,
                                               ushort_t* __restrict__ Qh, ushort_t* __restrict__ Ql,
                                               ushort_t* __restrict__ Kh, ushort_t* __restrict__ Kl) {
    int idx = blockIdx.x * 256 + threadIdx.x;   // B*S*NH*32 = 1M
    int p = idx & 31;
    int h = (idx >> 5) & 15;
    int s = (idx >> 9) & (S_SEQ - 1);
    int b = idx >> 19;
    float c = cs[s * 32 + p], si = sn[s * 32 + p];
    long base = ((long)(b * S_SEQ + s)) * 3072 + h * 192;
    long dst = (((long)(b * NHEAD + h)) * S_SEQ + s) * 64 + 2 * p;
    float re = qkv[base + 2 * p], im = qkv[base + 2 * p + 1];
    float qre = (re * c - im * si) * 0.125f;
    float qim = (re * si + im * c) * 0.125f;
    unsigned short hh = f2bf(qre);
    Qh[dst] = hh; Ql[dst] = f2bf(qre - bf2f(hh));
    hh = f2bf(qim);
    Qh[dst + 1] = hh; Ql[dst + 1] = f2bf(qim - bf2f(hh));
    re = qkv[base + 64 + 2 * p]; im = qkv[base + 64 + 2 * p + 1];
    float kre = re * c - im * si;
    float kim = re * si + im * c;
    hh = f2bf(kre);
    Kh[dst] = hh; Kl[dst] = f2bf(kre - bf2f(hh));
    hh = f2bf(kim);
    Kh[dst + 1] = hh; Kl[dst + 1] = f2bf(kim - bf2f(hh));
}

// ---------------- V transpose + split: qkv v-part -> Vt [b][h][64 d][1024 s]
__global__ __launch_bounds__(256) void v_trans(const float* __restrict__ qkv,
                                               ushort_t* __restrict__ Vth,
                                               ushort_t* __restrict__ Vtl) {
    __shared__ float t[64][65];
    const int s0 = blockIdx.x * 64, h = blockIdx.y, b = blockIdx.z;
    const int tid = threadIdx.x;
#pragma unroll
    for (int i = 0; i < 16; ++i) {
        int e = tid + i * 256;
        int sl = e >> 6, d = e & 63;
        t[d][sl] = qkv[((long)(b * S_SEQ + s0 + sl)) * 3072 + h * 192 + 128 + d];
    }
    __syncthreads();
#pragma unroll
    for (int i = 0; i < 16; ++i) {
        int e = tid + i * 256;
        int d = e >> 6, sl = e & 63;
        float v = t[d][sl];
        long o = (((long)(b * NHEAD + h)) * 64 + d) * S_SEQ + s0 + sl;
        unsigned short hh = f2bf(v);
        Vth[o] = hh;
        Vtl[o] = f2bf(v - bf2f(hh));
    }
}

// =====================================================================
// MFMA flash attention, full hi/lo split (fp32-class accuracy).
// =====================================================================
__device__ __forceinline__ bf16x8 lds_frag(const ushort_t* base, int row, int chunk) {
    return *(const bf16x8*)((const char*)base + row * 128 + ((chunk ^ (row & 7)) * 16));
}

__global__ __launch_bounds__(256) void attn_mfma(const ushort_t* __restrict__ Qh,
                                                 const ushort_t* __restrict__ Ql,
                                                 const ushort_t* __restrict__ Kh,
                                                 const ushort_t* __restrict__ Kl,
                                                 const ushort_t* __restrict__ Vth,
                                                 const ushort_t* __restrict__ Vtl,
                                                 float* __restrict__ ctx) {
    __shared__ __align__(16) ushort_t KsH[64 * 64], KsL[64 * 64];
    __shared__ __align__(16) ushort_t VsH[64 * 64], VsL[64 * 64];
    __shared__ __align__(16) ushort_t Ps[4][2][16][72];
    const int qb = blockIdx.x * 64, h = blockIdx.y, b = blockIdx.z;
    const int tid = threadIdx.x;
    const int w = tid >> 6, l = tid & 63;
    const int lr = l & 15, g = l >> 4;
    const long bh = b * NHEAD + h;

    const long qoff = (bh * S_SEQ + qb + w * 16 + lr) * 64 + g * 8;
    bf16x8 qh0 = *(const bf16x8*)(Qh + qoff);
    bf16x8 qh1 = *(const bf16x8*)(Qh + qoff + 32);
    bf16x8 ql0 = *(const bf16x8*)(Ql + qoff);
    bf16x8 ql1 = *(const bf16x8*)(Ql + qoff + 32);

    const int rowS0 = w * 16 + (l >> 3), rowS1 = rowS0 + 8;
    const int cch = l & 7;
    const char* gK0 = (const char*)Kh + (bh * S_SEQ + rowS0) * 128 + ((cch ^ (rowS0 & 7)) * 16);
    const char* gK1 = (const char*)Kh + (bh * S_SEQ + rowS1) * 128 + ((cch ^ (rowS1 & 7)) * 16);
    const char* gKl0 = (const char*)Kl + (bh * S_SEQ + rowS0) * 128 + ((cch ^ (rowS0 & 7)) * 16);
    const char* gKl1 = (const char*)Kl + (bh * S_SEQ + rowS1) * 128 + ((cch ^ (rowS1 & 7)) * 16);
    const char* gV0 = (const char*)Vth + (bh * 64 + rowS0) * 2048 + ((cch ^ (rowS0 & 7)) * 16);
    const char* gV1 = (const char*)Vth + (bh * 64 + rowS1) * 2048 + ((cch ^ (rowS1 & 7)) * 16);
    const char* gVl0 = (const char*)Vtl + (bh * 64 + rowS0) * 2048 + ((cch ^ (rowS0 & 7)) * 16);
    const char* gVl1 = (const char*)Vtl + (bh * 64 + rowS1) * 2048 + ((cch ^ (rowS1 & 7)) * 16);

    float m_run[4] = {-1e30f, -1e30f, -1e30f, -1e30f};
    float l_run[4] = {0.f, 0.f, 0.f, 0.f};
    f32x4 acco[4] = {};

    for (int k0 = 0; k0 < S_SEQ; k0 += 64) {
        GLD(gK0 + (size_t)k0 * 128, (char*)KsH + w * 2048 + l * 16);
        GLD(gK1 + (size_t)k0 * 128, (char*)KsH + w * 2048 + 1024 + l * 16);
        GLD(gKl0 + (size_t)k0 * 128, (char*)KsL + w * 2048 + l * 16);
        GLD(gKl1 + (size_t)k0 * 128, (char*)KsL + w * 2048 + 1024 + l * 16);
        GLD(gV0 + (size_t)k0 * 2, (char*)VsH + w * 2048 + l * 16);
        GLD(gV1 + (size_t)k0 * 2, (char*)VsH + w * 2048 + 1024 + l * 16);
        GLD(gVl0 + (size_t)k0 * 2, (char*)VsL + w * 2048 + l * 16);
        GLD(gVl1 + (size_t)k0 * 2, (char*)VsL + w * 2048 + 1024 + l * 16);
        __syncthreads();

        f32x4 accs[4] = {};
#pragma unroll
        for (int n = 0; n < 4; ++n) {
            bf16x8 bkh0 = lds_frag(KsH, n * 16 + lr, g);
            bf16x8 bkh1 = lds_frag(KsH, n * 16 + lr, g + 4);
            bf16x8 bkl0 = lds_frag(KsL, n * 16 + lr, g);
            bf16x8 bkl1 = lds_frag(KsL, n * 16 + lr, g + 4);
            accs[n] = __builtin_amdgcn_mfma_f32_16x16x32_bf16(qh0, bkh0, accs[n], 0, 0, 0);
            accs[n] = __builtin_amdgcn_mfma_f32_16x16x32_bf16(qh1, bkh1, accs[n], 0, 0, 0);
            accs[n] = __builtin_amdgcn_mfma_f32_16x16x32_bf16(qh0, bkl0, accs[n], 0, 0, 0);
            accs[n] = __builtin_amdgcn_mfma_f32_16x16x32_bf16(qh1, bkl1, accs[n], 0, 0, 0);
            accs[n] = __builtin_amdgcn_mfma_f32_16x16x32_bf16(ql0, bkh0, accs[n], 0, 0, 0);
            accs[n] = __builtin_amdgcn_mfma_f32_16x16x32_bf16(ql1, bkh1, accs[n], 0, 0, 0);
        }
        float alpha[4];
#pragma unroll
        for (int r = 0; r < 4; ++r) {
            float mx = fmaxf(fmaxf(accs[0][r], accs[1][r]), fmaxf(accs[2][r], accs[3][r]));
#pragma unroll
            for (int msk = 1; msk < 16; msk <<= 1) mx = fmaxf(mx, __shfl_xor(mx, msk, 64));
            float m_new = fmaxf(m_run[r], mx);
            float ps = 0.f;
#pragma unroll
            for (int n = 0; n < 4; ++n) {
                float p = __expf(accs[n][r] - m_new);
                accs[n][r] = p;
                ps += p;
            }
#pragma unroll
            for (int msk = 1; msk < 16; msk <<= 1) ps += __shfl_xor(ps, msk, 64);
            alpha[r] = __expf(m_run[r] - m_new);
            l_run[r] = l_run[r] * alpha[r] + ps;
            m_run[r] = m_new;
        }
#pragma unroll
        for (int nd = 0; nd < 4; ++nd)
#pragma unroll
            for (int r = 0; r < 4; ++r) acco[nd][r] *= alpha[r];
#pragma unroll
        for (int n = 0; n < 4; ++n)
#pragma unroll
            for (int r = 0; r < 4; ++r) {
                float p = accs[n][r];
                unsigned short hh = f2bf(p);
                Ps[w][0][g * 4 + r][n * 16 + lr] = hh;
                Ps[w][1][g * 4 + r][n * 16 + lr] = f2bf(p - bf2f(hh));
            }
        __syncthreads();
        bf16x8 pah0 = *(const bf16x8*)&Ps[w][0][lr][g * 8];
        bf16x8 pah1 = *(const bf16x8*)&Ps[w][0][lr][32 + g * 8];
        bf16x8 pal0 = *(const bf16x8*)&Ps[w][1][lr][g * 8];
        bf16x8 pal1 = *(const bf16x8*)&Ps[w][1][lr][32 + g * 8];
#pragma unroll
        for (int nd = 0; nd < 4; ++nd) {
            bf16x8 bvh0 = lds_frag(VsH, nd * 16 + lr, g);
            bf16x8 bvh1 = lds_frag(VsH, nd * 16 + lr, g + 4);
            bf16x8 bvl0 = lds_frag(VsL, nd * 16 + lr, g);
            bf16x8 bvl1 = lds_frag(VsL, nd * 16 + lr, g + 4);
            acco[nd] = __builtin_amdgcn_mfma_f32_16x16x32_bf16(pah0, bvh0, acco[nd], 0, 0, 0);
            acco[nd] = __builtin_amdgcn_mfma_f32_16x16x32_bf16(pah1, bvh1, acco[nd], 0, 0, 0);
            acco[nd] = __builtin_amdgcn_mfma_f32_16x16x32_bf16(pah0, bvl0, acco[nd], 0, 0, 0);
            acco[nd] = __builtin_amdgcn_mfma_f32_16x16x32_bf16(pah1, bvl1, acco[nd], 0, 0, 0);
            acco[nd] = __builtin_amdgcn_mfma_f32_16x16x32_bf16(pal0, bvh0, acco[nd], 0, 0, 0);
            acco[nd] = __builtin_amdgcn_mfma_f32_16x16x32_bf16(pal1, bvh1, acco[nd], 0, 0, 0);
        }
        __syncthreads();
    }
#pragma unroll
    for (int r = 0; r < 4; ++r) {
        float inv = 1.0f / l_run[r];
        long row = (long)b * S_SEQ + qb + w * 16 + g * 4 + r;
#pragma unroll
        for (int nd = 0; nd < 4; ++nd)
            ctx[row * H_DIM + h * 64 + nd * 16 + lr] = acco[nd][r] * inv;
    }
}

// ---------------- gate: top-2 softmax weights (zeros elsewhere)
__global__ __launch_bounds__(256) void gate_kernel(const float* __restrict__ h2,
                                                   const float* __restrict__ gate_w,
                                                   float* __restrict__ gw) {
    long t = blockIdx.x;
    float sum[4] = {0, 0, 0, 0};
    for (int i = threadIdx.x; i < H_DIM; i += 256) {
        float v = h2[t * H_DIM + i];
#pragma unroll
        for (int e = 0; e < 4; ++e) sum[e] = fmaf(v, gate_w[e * H_DIM + i], sum[e]);
    }
#pragma unroll
    for (int w = 1; w < 64; w <<= 1)
#pragma unroll
        for (int e = 0; e < 4; ++e) sum[e] += __shfl_xor(sum[e], w, 64);
    __shared__ float part[4][4];
    if ((threadIdx.x & 63) == 0)
#pragma unroll
        for (int e = 0; e < 4; ++e) part[e][threadIdx.x >> 6] = sum[e];
    __syncthreads();
    if (threadIdx.x == 0) {
        float lg[4];
#pragma unroll
        for (int e = 0; e < 4; ++e) lg[e] = part[e][0] + part[e][1] + part[e][2] + part[e][3];
        int i0 = 0;
        for (int e = 1; e < 4; ++e) if (lg[e] > lg[i0]) i0 = e;
        int i1 = -1;
        for (int e = 0; e < 4; ++e) if (e != i0 && (i1 < 0 || lg[e] > lg[i1])) i1 = e;
        float mx = fmaxf(lg[i0], lg[i1]);
        float e0 = __expf(lg[i0] - mx), e1 = __expf(lg[i1] - mx);
        float inv = 1.0f / (e0 + e1);
        float o[4] = {0, 0, 0, 0};
        o[i0] = e0 * inv; o[i1] = e1 * inv;
#pragma unroll
        for (int e = 0; e < 4; ++e) gw[t * 4 + e] = o[e];
    }
}

// ================= fallback-only kernels (round-0 fp32 path) =================
#define KI 8
#define BKK 72
__global__ __launch_bounds__(256) void kan_gemm(const float* __restrict__ Act,
                                                const float* __restrict__ baseW,
                                                const float* __restrict__ splW,
                                                const float* __restrict__ scal,
                                                float* __restrict__ C,
                                                const float* __restrict__ rowScale,
                                                int rsStride, int N, int mode) {
    __shared__ float As[BKK][64];
    __shared__ float Bs[BKK][64];
    const int bm = blockIdx.y * 64;
    const int bn = blockIdx.x * 64;
    const int tid = threadIdx.x;
    const int tx = tid & 15, ty = tid >> 4;
    float acc[4][4] = {};
    for (int i0 = 0; i0 < H_DIM; i0 += KI) {
        for (int e = tid; e < 64 * KI; e += 256) {
            int m = e >> 3, ii = e & 7;
            float xv = Act[(long)(bm + m) * H_DIM + i0 + ii];
            float sp[8];
            bspline8(xv, sp);
            As[ii * 9][m] = xv * sigmoidf_(xv);
#pragma unroll
            for (int c = 0; c < 8; ++c) As[ii * 9 + 1 + c][m] = sp[c];
        }
        for (int e = tid; e < 64 * KI; e += 256) {
            int n = e >> 3, ii = e & 7;
            long w = (long)(bn + n) * H_DIM + i0 + ii;
            float sc = scal[w];
            Bs[ii * 9][n] = baseW[w];
            const float4* sp4 = (const float4*)(splW + w * 8);
            float4 s0 = sp4[0], s1 = sp4[1];
            Bs[ii * 9 + 1][n] = s0.x * sc; Bs[ii * 9 + 2][n] = s0.y * sc;
            Bs[ii * 9 + 3][n] = s0.z * sc; Bs[ii * 9 + 4][n] = s0.w * sc;
            Bs[ii * 9 + 5][n] = s1.x * sc; Bs[ii * 9 + 6][n] = s1.y * sc;
            Bs[ii * 9 + 7][n] = s1.z * sc; Bs[ii * 9 + 8][n] = s1.w * sc;
        }
        __syncthreads();
#pragma unroll 8
        for (int k = 0; k < BKK; ++k) {
            float4 a = *(const float4*)&As[k][ty * 4];
            float4 b = *(const float4*)&Bs[k][tx * 4];
            float av[4] = {a.x, a.y, a.z, a.w};
            float bv[4] = {b.x, b.y, b.z, b.w};
#pragma unroll
            for (int i = 0; i < 4; ++i)
#pragma unroll
                for (int j = 0; j < 4; ++j) acc[i][j] = fmaf(av[i], bv[j], acc[i][j]);
        }
        __syncthreads();
    }
#pragma unroll
    for (int i = 0; i < 4; ++i) {
        long m = bm + ty * 4 + i;
        float rs = (mode == 1) ? rowScale[m * rsStride] : 0.0f;
#pragma unroll
        for (int j = 0; j < 4; ++j) {
            long idx = m * (long)N + bn + tx * 4 + j;
            if (mode == 0) C[idx] = acc[i][j];
            else           C[idx] += rs * acc[i][j];
        }
    }
}

__global__ __launch_bounds__(256) void gemm_bias_res(const float* __restrict__ A,
                                                     const float* __restrict__ Bw,
                                                     const float* __restrict__ bias,
                                                     const float* __restrict__ res,
                                                     float* __restrict__ C) {
    __shared__ float As[16][64];
    __shared__ float Bs[16][64];
    const int bm = blockIdx.y * 64, bn = blockIdx.x * 64;
    const int tid = threadIdx.x;
    const int tx = tid & 15, ty = tid >> 4;
    float acc[4][4] = {};
    for (int k0 = 0; k0 < 1024; k0 += 16) {
        for (int e = tid; e < 1024; e += 256) {
            int r = e >> 4, kk = e & 15;
            As[kk][r] = A[(long)(bm + r) * 1024 + k0 + kk];
            Bs[kk][r] = Bw[(long)(bn + r) * 1024 + k0 + kk];
        }
        __syncthreads();
#pragma unroll
        for (int k = 0; k < 16; ++k) {
            float4 a = *(const float4*)&As[k][ty * 4];
            float4 b = *(const float4*)&Bs[k][tx * 4];
            float av[4] = {a.x, a.y, a.z, a.w};
            float bv[4] = {b.x, b.y, b.z, b.w};
#pragma unroll
            for (int i = 0; i < 4; ++i)
#pragma unroll
                for (int j = 0; j < 4; ++j) acc[i][j] = fmaf(av[i], bv[j], acc[i][j]);
        }
        __syncthreads();
    }
#pragma unroll
    for (int i = 0; i < 4; ++i) {
        long m = bm + ty * 4 + i;
#pragma unroll
        for (int j = 0; j < 4; ++j) {
            long n = bn + tx * 4 + j;
            C[m * 1024 + n] = res[m * 1024 + n] + bias[n] + acc[i][j];
        }
    }
}

__global__ __launch_bounds__(256) void rope_kernel(float* __restrict__ qkv,
                                                   const float* __restrict__ cs,
                                                   const float* __restrict__ sn) {
    int idx = blockIdx.x * 256 + threadIdx.x;
    if (idx >= T_TOK * NHEAD * 32) return;
    int p = idx & 31;
    int n = (idx >> 5) & 15;
    int t = idx >> 9;
    int s = t & (S_SEQ - 1);
    float c = cs[s * 32 + p], si = sn[s * 32 + p];
    long base = (long)t * 3072 + n * 192;
    float re = qkv[base + 2 * p], im = qkv[base + 2 * p + 1];
    qkv[base + 2 * p]     = re * c - im * si;
    qkv[base + 2 * p + 1] = re * si + im * c;
    re = qkv[base + 64 + 2 * p]; im = qkv[base + 64 + 2 * p + 1];
    qkv[base + 64 + 2 * p]     = re * c - im * si;
    qkv[base + 64 + 2 * p + 1] = re * si + im * c;
}

__global__ __launch_bounds__(256) void attn_kernel(const float* __restrict__ qkv,
                                                   float* __restrict__ ctx) {
    const int qb = blockIdx.x * 32;
    const int h = blockIdx.y, b = blockIdx.z;
    __shared__ float Qs[32][64];
    __shared__ float Ks[64][64];
    __shared__ float Vs[64][64];
    __shared__ float Ss[32][64];
    const int tid = threadIdx.x;
    const int q = tid >> 3, g = tid & 7;
    for (int e = tid; e < 32 * 64; e += 256) {
        int r = e >> 6, d = e & 63;
        Qs[r][d] = qkv[(long)(b * S_SEQ + qb + r) * 3072 + h * 192 + d];
    }
    float m_run = -1e30f, l_run = 0.0f;
    float acc[8] = {};
    for (int k0 = 0; k0 < S_SEQ; k0 += 64) {
        for (int e = tid; e < 64 * 64; e += 256) {
            int r = e >> 6, d = e & 63;
            long base = (long)(b * S_SEQ + k0 + r) * 3072 + h * 192;
            Ks[r][d] = qkv[base + 64 + d];
            Vs[r][d] = qkv[base + 128 + d];
        }
        __syncthreads();
        float s[8];
#pragma unroll
        for (int kk = 0; kk < 8; ++kk) {
            int k = g * 8 + kk;
            float dot = 0.0f;
#pragma unroll
            for (int d = 0; d < 64; ++d) dot = fmaf(Qs[q][d], Ks[k][d], dot);
            s[kk] = dot * 0.125f;
        }
        float mx = s[0];
#pragma unroll
        for (int kk = 1; kk < 8; ++kk) mx = fmaxf(mx, s[kk]);
#pragma unroll
        for (int w = 1; w < 8; w <<= 1) mx = fmaxf(mx, __shfl_xor(mx, w, 64));
        float m_new = fmaxf(m_run, mx);
        float p[8], ls = 0.0f;
#pragma unroll
        for (int kk = 0; kk < 8; ++kk) { p[kk] = __expf(s[kk] - m_new); ls += p[kk]; }
#pragma unroll
        for (int w = 1; w < 8; w <<= 1) ls += __shfl_xor(ls, w, 64);
        float alpha = __expf(m_run - m_new);
        l_run = l_run * alpha + ls;
        m_run = m_new;
#pragma unroll
        for (int kk = 0; kk < 8; ++kk) Ss[q][g * 8 + kk] = p[kk];
        __syncthreads();
#pragma unroll
        for (int j = 0; j < 8; ++j) acc[j] *= alpha;
        for (int k = 0; k < 64; ++k) {
            float pv = Ss[q][k];
#pragma unroll
            for (int j = 0; j < 8; ++j) acc[j] = fmaf(pv, Vs[k][g * 8 + j], acc[j]);
        }
        __syncthreads();
    }
    float inv = 1.0f / l_run;
#pragma unroll
    for (int j = 0; j < 8; ++j)
        ctx[(long)(b * S_SEQ + qb + q) * H_DIM + h * 64 + g * 8 + j] = acc[j] * inv;
}

__global__ __launch_bounds__(256) void mul_kernel(const float* __restrict__ a,
                                                  const float* __restrict__ b,
                                                  float* __restrict__ c, int n) {
    int i = blockIdx.x * 256 + threadIdx.x;
    if (i < n) c[i] = a[i] * b[i];
}

extern "C" void kernel_launch(void* const* d_in, const int* in_sizes, int n_in,
                              void* d_out, int out_size, void* d_ws, size_t ws_size,
                              hipStream_t stream) {
    const float* x          = (const float*)d_in[0];
    const float* rot_cos    = (const float*)d_in[1];
    const float* rot_sin    = (const float*)d_in[2];
    const float* norm1_w    = (const float*)d_in[3];
    const float* norm2_w    = (const float*)d_in[4];
    const float* qkv_base   = (const float*)d_in[5];
    const float* qkv_spline = (const float*)d_in[6];
    const float* qkv_scaler = (const float*)d_in[7];
    const float* out_w      = (const float*)d_in[8];
    const float* out_b      = (const float*)d_in[9];
    const float* gate_w     = (const float*)d_in[10];
    const float* w1_base    = (const float*)d_in[11];
    const float* w1_spline  = (const float*)d_in[12];
    const float* w1_scaler  = (const float*)d_in[13];
    const float* w2_base    = (const float*)d_in[14];
    const float* w2_spline  = (const float*)d_in[15];
    const float* w2_scaler  = (const float*)d_in[16];
    const float* w3_base    = (const float*)d_in[17];
    const float* w3_spline  = (const float*)d_in[18];
    const float* w3_scaler  = (const float*)d_in[19];
    float* out = (float*)d_out;

    const size_t SZ_AUG  = (size_t)T_TOK * KAUG * 2;   // 37,748,736
    const size_t SZ_WQ   = (size_t)3072 * KAUG * 2;    // 56,623,104
    const size_t SZ_QKV  = (size_t)T_TOK * 3072 * 4;   // 25,165,824
    const size_t SZ_G12  = (size_t)T_TOK * 2048 * 4;   // 16,777,216
    const size_t SZ_TOK  = (size_t)T_TOK * H_DIM * 4;  //  8,388,608
    const size_t NEED = 2 * SZ_AUG + 2 * SZ_WQ + SZ_QKV + SZ_G12 + 2 * SZ_TOK + 32768;

    if (ws_size >= NEED) {
        char* pool = (char*)d_ws;
        // ---- attention-phase overlay ----
        ushort_t* A_hi = (ushort_t*)pool;
        ushort_t* A_lo = (ushort_t*)(pool + SZ_AUG);
        char* W1p = pool + 2 * SZ_AUG;
        char* W2p = pool + 2 * SZ_AUG + SZ_WQ;
        float* qkv = (float*)(pool + 2 * SZ_AUG + 2 * SZ_WQ);
        float* ctx = (float*)(pool + 2 * SZ_AUG + 2 * SZ_WQ + SZ_QKV + SZ_G12);
        float* tok = (float*)(pool + 2 * SZ_AUG + 2 * SZ_WQ + SZ_QKV + SZ_G12 + SZ_TOK);
        float* gw  = (float*)(pool + NEED - 32768);
        ushort_t* W1b = (ushort_t*)W1p;
        ushort_t* W2b = (ushort_t*)W2p;
        const size_t SZ_P = (size_t)T_TOK * 1024 * 2;  // 4 MB
        ushort_t* Qh  = (ushort_t*)W1p;
        ushort_t* Ql  = (ushort_t*)(W1p + SZ_P);
        ushort_t* Kh  = (ushort_t*)(W1p + 2 * SZ_P);
        ushort_t* Kl  = (ushort_t*)(W1p + 3 * SZ_P);
        ushort_t* Vth = (ushort_t*)(W1p + 4 * SZ_P);
        ushort_t* Vtl = (ushort_t*)(W1p + 5 * SZ_P);
        ushort_t* CtxH = (ushort_t*)W2p;
        ushort_t* CtxL = (ushort_t*)(W2p + SZ_P);
        ushort_t* OWh  = (ushort_t*)(W2p + 2 * SZ_P);
        ushort_t* OWl  = (ushort_t*)(W2p + 2 * SZ_P + SZ_P / 2);
        // ---- MoE-phase overlay (lifetimes disjoint, stream-ordered) ----
        const size_t SZ_W12 = (size_t)8192 * KAUG * 2;          // 150,994,944
        ushort_t* A2   = (ushort_t*)pool;                       // [0, 37.7M)
        ushort_t* W12  = (ushort_t*)(pool + SZ_AUG);            // [37.7, 188.7M)
        ushort_t* g12  = (ushort_t*)(pool + SZ_AUG + SZ_W12);   // [188.7, 222.3M) bf16
        ushort_t* Gall = (ushort_t*)pool;                       // [0, 151.0M)
        ushort_t* W3a  = (ushort_t*)(pool + 4 * SZ_AUG);        // [151.0, 226.5M)

        // --- attention branch: split-bf16 everywhere upstream of the gate ---
        rmsnorm_kernel<<<T_TOK, 256, 0, stream>>>(x, norm1_w, tok);
        pack_act<<<(T_TOK * 1024) / 256, 256, 0, stream>>>(tok, A_hi, A_lo);
        pack_w<<<(3072 * 1024) / 256, 256, 0, stream>>>(qkv_base, qkv_spline, qkv_scaler,
                                                        W1b, W2b, (long)3072 * 1024);
        hipMemsetAsync(qkv, 0, SZ_QKV, stream);
        mfma_gemm2<128, 1, 5, 4><<<dim3(3072 / 128, T_TOK / 128, 4), 256, 0, stream>>>(
            A_hi, A_lo, W1b, W2b, qkv, nullptr, 3072, KAUG);
        qk_pack<<<(T_TOK * NHEAD * 32) / 256, 256, 0, stream>>>(qkv, rot_cos, rot_sin,
                                                                Qh, Ql, Kh, Kl);
        v_trans<<<dim3(S_SEQ / 64, NHEAD, 2), 256, 0, stream>>>(qkv, Vth, Vtl);
        attn_mfma<<<dim3(S_SEQ / 64, NHEAD, 2), 256, 0, stream>>>(Qh, Ql, Kh, Kl,
                                                                  Vth, Vtl, ctx);
        split_pack<<<(T_TOK * 1024) / 256, 256, 0, stream>>>(ctx, CtxH, CtxL,
                                                             (long)T_TOK * 1024);
        split_pack<<<(1024 * 1024) / 256, 256, 0, stream>>>(out_w, OWh, OWl,
                                                            (long)1024 * 1024);
        prefill_out<<<(T_TOK * H_DIM / 4) / 256, 256, 0, stream>>>(x, out_b, out);
        mfma_gemm2<128, 1, 5, 4><<<dim3(1024 / 128, T_TOK / 128, 4), 256, 0, stream>>>(
            CtxH, CtxL, OWh, OWl, out, nullptr, 1024, 1024);
        rmsnorm_kernel<<<T_TOK, 256, 0, stream>>>(out, norm2_w, tok);
        gate_kernel<<<T_TOK, 256, 0, stream>>>(tok, gate_w, gw);

        // --- MoE: all-expert batched, plain bf16 (downstream of gate) ---
        pack_act<<<(T_TOK * 1024) / 256, 256, 0, stream>>>(tok, A2, nullptr);
        // merged w1|w2 pack: rows 0..4095 = w1 (e*1024+d), 4096..8191 = w2
        pack_w<<<(4 * 1024 * 1024) / 256, 256, 0, stream>>>(
            w1_base, w1_spline, w1_scaler, W12, nullptr, (long)4 * 1024 * 1024);
        pack_w<<<(4 * 1024 * 1024) / 256, 256, 0, stream>>>(
            w2_base, w2_spline, w2_scaler, W12 + (size_t)4096 * KAUG, nullptr,
            (long)4 * 1024 * 1024);
        // one N=8192 GEMM -> bf16 g12 (1024 blocks = 4/CU)
        mfma_gemm2<128, 0, 6, 1><<<dim3(8192 / 128, T_TOK / 128), 256, 0, stream>>>(
            A2, nullptr, W12, nullptr, (float*)g12, nullptr, 8192, KAUG);
        // G_e = augment(g1*g2) (overwrites A2/W12 - dead)
        mul_pack4<<<(T_TOK * 4096) / 256, 256, 0, stream>>>(g12, Gall);
        // w3 pack (overwrites g12 tail - dead)
        pack_w<<<(4 * 1024 * 1024) / 256, 256, 0, stream>>>(
            w3_base, w3_spline, w3_scaler, W3a, nullptr, (long)4 * 1024 * 1024);
        // batched w3: out += gw[t,e] * (G_e @ W3_e^T); z=(e,kk), 1024 blocks
        mfma_gemm2<128, 0, 3, 2><<<dim3(1024 / 128, T_TOK / 128, E_EXP * 2), 256, 0, stream>>>(
            Gall, nullptr, W3a, nullptr, out, gw, 1024, KAUG);
        return;
    }

    // ---- fallback: fp32 path ----
    char* ws = (char*)d_ws;
    float* hn  = (float*)ws; ws += (size_t)T_TOK * H_DIM * 4;
    float* qkv = (float*)ws; ws += (size_t)T_TOK * 3072 * 4;
    float* ctx = (float*)ws; ws += (size_t)T_TOK * H_DIM * 4;
    float* h2  = (float*)ws; ws += (size_t)T_TOK * H_DIM * 4;
    float* gw  = (float*)ws; ws += (size_t)T_TOK * E_EXP * 4;
    float* g1  = (float*)ws; ws += (size_t)T_TOK * DFF_ * 4;
    float* g2  = (float*)ws; ws += (size_t)T_TOK * DFF_ * 4;
    float* gm  = (float*)ws; ws += (size_t)T_TOK * DFF_ * 4;

    rmsnorm_kernel<<<T_TOK, 256, 0, stream>>>(x, norm1_w, hn);
    dim3 gq(3072 / 64, T_TOK / 64);
    kan_gemm<<<gq, 256, 0, stream>>>(hn, qkv_base, qkv_spline, qkv_scaler, qkv,
                                     nullptr, 0, 3072, 0);
    rope_kernel<<<(T_TOK * NHEAD * 32) / 256, 256, 0, stream>>>(qkv, rot_cos, rot_sin);
    dim3 ga(S_SEQ / 32, NHEAD, 2);
    attn_kernel<<<ga, 256, 0, stream>>>(qkv, ctx);
    dim3 go(1024 / 64, T_TOK / 64);
    gemm_bias_res<<<go, 256, 0, stream>>>(ctx, out_w, out_b, x, out);
    rmsnorm_kernel<<<T_TOK, 256, 0, stream>>>(out, norm2_w, h2);
    gate_kernel<<<T_TOK, 256, 0, stream>>>(h2, gate_w, gw);
    dim3 ge(1024 / 64, T_TOK / 64);
    for (int e = 0; e < E_EXP; ++e) {
        long wo = (long)e * DFF_ * H_DIM;
        kan_gemm<<<ge, 256, 0, stream>>>(h2, w1_base + wo, w1_spline + wo * 8,
                                         w1_scaler + wo, g1, nullptr, 0, DFF_, 0);
        kan_gemm<<<ge, 256, 0, stream>>>(h2, w2_base + wo, w2_spline + wo * 8,
                                         w2_scaler + wo, g2, nullptr, 0, DFF_, 0);
        mul_kernel<<<(T_TOK * DFF_) / 256, 256, 0, stream>>>(g1, g2, gm, T_TOK * DFF_);
        kan_gemm<<<ge, 256, 0, stream>>>(gm, w3_base + wo, w3_spline + wo * 8,
                                         w3_scaler + wo, out, gw + e, E_EXP, H_DIM, 1);
    }
}

// Round 6
// 1300.561 us; speedup vs baseline: 9.2786x; 1.1460x over previous
//
#include <hip/hip_runtime.h>
#include <hip/hip_bf16.h>

// KANBlock: B=2,S=1024,H=1024,NH=16,HD=64,DFF=1024,E=4,TOPK=2, NB=8 spline bases
#define T_TOK 2048
#define H_DIM 1024
#define S_SEQ 1024
#define NHEAD 16
#define E_EXP 4
#define DFF_  1024
#define KAUG  9216   // 9*1024 augmented K (k = c*1024 + i; c=0 silu, c=1..8 splines)
#define MROWS 4608   // 2*T + 4*127 padded, rounded to 36*128
#define NRB   36     // row blocks of 128

typedef __bf16 bf16x8 __attribute__((ext_vector_type(8)));
typedef float  f32x4  __attribute__((ext_vector_type(4)));
typedef unsigned short ushort_t;

__device__ __forceinline__ float sigmoidf_(float x) { return 1.0f / (1.0f + __expf(-x)); }

__device__ __forceinline__ unsigned short f2bf(float f) {   // RNE f32 -> bf16 bits
    unsigned int u = __float_as_uint(f);
    u = (u + 0x7fffu + ((u >> 16) & 1u)) >> 16;
    return (unsigned short)u;
}
__device__ __forceinline__ float bf2f(unsigned short h) {
    return __uint_as_float(((unsigned int)h) << 16);
}

// Cubic B-spline bases, matches reference b_splines() (verified round 0)
__device__ __forceinline__ void bspline8(float x, float* o) {
    float b[11];
#pragma unroll
    for (int m = 0; m < 11; ++m) {
        float g0 = 0.4f * (float)(m - 3) - 1.0f;
        float g1 = 0.4f * (float)(m - 2) - 1.0f;
        b[m] = (x >= g0 && x < g1) ? 1.0f : 0.0f;
    }
#pragma unroll
    for (int j = 1; j <= 3; ++j) {
        float inv = 1.0f / (0.4f * (float)j);
#pragma unroll
        for (int m = 0; m + j < 11; ++m) {
            float gm   = 0.4f * (float)(m - 3) - 1.0f;
            float gmj1 = 0.4f * (float)(m + j - 2) - 1.0f;
            b[m] = ((x - gm) * b[m] + (gmj1 - x) * b[m + 1]) * inv;
        }
    }
#pragma unroll
    for (int c = 0; c < 8; ++c) o[c] = b[c];
}

// ---------------- RMSNorm
__global__ __launch_bounds__(256) void rmsnorm_kernel(const float* __restrict__ x,
                                                      const float* __restrict__ w,
                                                      float* __restrict__ out) {
    long t = blockIdx.x;
    float4 v = ((const float4*)(x + t * H_DIM))[threadIdx.x];
    float ss = v.x * v.x + v.y * v.y + v.z * v.z + v.w * v.w;
#pragma unroll
    for (int m = 1; m < 64; m <<= 1) ss += __shfl_xor(ss, m, 64);
    __shared__ float wsum[4];
    if ((threadIdx.x & 63) == 0) wsum[threadIdx.x >> 6] = ss;
    __syncthreads();
    ss = wsum[0] + wsum[1] + wsum[2] + wsum[3];
    float sc = rsqrtf(ss * (1.0f / (float)H_DIM) + 1e-6f);
    float4 wv = ((const float4*)w)[threadIdx.x];
    float4 r;
    r.x = v.x * sc * wv.x; r.y = v.y * sc * wv.y;
    r.z = v.z * sc * wv.z; r.w = v.w * sc * wv.w;
    ((float4*)(out + t * H_DIM))[threadIdx.x] = r;
}

// ---------------- out prefill: out = x + bias
__global__ __launch_bounds__(256) void prefill_out(const float* __restrict__ x,
                                                   const float* __restrict__ bias,
                                                   float* __restrict__ out) {
    long i = (long)blockIdx.x * 256 + threadIdx.x;   // T*H/4
    float4 xv = ((const float4*)x)[i];
    float4 bv = ((const float4*)bias)[i & 255];
    float4 r;
    r.x = xv.x + bv.x; r.y = xv.y + bv.y; r.z = xv.z + bv.z; r.w = xv.w + bv.w;
    ((float4*)out)[i] = r;
}

// ---------------- pack activations -> augmented bf16 (hi, optional lo)
__global__ __launch_bounds__(256) void pack_act(const float* __restrict__ act,
                                                ushort_t* __restrict__ hi,
                                                ushort_t* __restrict__ lo) {
    long idx = (long)blockIdx.x * 256 + threadIdx.x;
    long m = idx >> 10; int i = (int)(idx & 1023);
    float v = act[idx];
    float ch[9];
    ch[0] = v * sigmoidf_(v);
    bspline8(v, ch + 1);
    ushort_t* oh = hi + m * (long)KAUG + i;
#pragma unroll
    for (int c = 0; c < 9; ++c) oh[(long)c * 1024] = f2bf(ch[c]);
    if (lo) {
        ushort_t* ol = lo + m * (long)KAUG + i;
#pragma unroll
        for (int c = 0; c < 9; ++c) {
            unsigned short h = f2bf(ch[c]);
            ol[(long)c * 1024] = f2bf(ch[c] - bf2f(h));
        }
    }
}

// ---------------- pack weights -> augmented bf16: [base | spline*scaler]
__global__ __launch_bounds__(256) void pack_w(const float* __restrict__ base,
                                              const float* __restrict__ spl,
                                              const float* __restrict__ scal,
                                              ushort_t* __restrict__ hi,
                                              ushort_t* __restrict__ lo,
                                              long total) {
    long idx = (long)blockIdx.x * 256 + threadIdx.x;
    if (idx >= total) return;
    long n = idx >> 10; int i = (int)(idx & 1023);
    float sc = scal[idx];
    const float4* s4 = (const float4*)(spl + idx * 8);
    float4 s0 = s4[0], s1 = s4[1];
    float ch[9] = {base[idx], s0.x * sc, s0.y * sc, s0.z * sc, s0.w * sc,
                   s1.x * sc, s1.y * sc, s1.z * sc, s1.w * sc};
    ushort_t* oh = hi + n * (long)KAUG + i;
#pragma unroll
    for (int c = 0; c < 9; ++c) oh[(long)c * 1024] = f2bf(ch[c]);
    if (lo) {
        ushort_t* ol = lo + n * (long)KAUG + i;
#pragma unroll
        for (int c = 0; c < 9; ++c) {
            unsigned short h = f2bf(ch[c]);
            ol[(long)c * 1024] = f2bf(ch[c] - bf2f(h));
        }
    }
}

// ---------------- grouped weight pack: expert-major [e][w1|w2] rows of 2048
// input row n = e*1024 + d ; output row = e*2048 + grpOff + d
__global__ __launch_bounds__(256) void pack_w_g(const float* __restrict__ base,
                                                const float* __restrict__ spl,
                                                const float* __restrict__ scal,
                                                ushort_t* __restrict__ hi,
                                                int grpOff) {
    long idx = (long)blockIdx.x * 256 + threadIdx.x;   // 4M exact
    long n = idx >> 10; int i = (int)(idx & 1023);
    long e = n >> 10, d = n & 1023;
    float sc = scal[idx];
    const float4* s4 = (const float4*)(spl + idx * 8);
    float4 s0 = s4[0], s1 = s4[1];
    float ch[9] = {base[idx], s0.x * sc, s0.y * sc, s0.z * sc, s0.w * sc,
                   s1.x * sc, s1.y * sc, s1.z * sc, s1.w * sc};
    ushort_t* oh = hi + (e * 2048 + grpOff + d) * (long)KAUG + i;
#pragma unroll
    for (int c = 0; c < 9; ++c) oh[(long)c * 1024] = f2bf(ch[c]);
}

// ---------------- grouped: v = g1*g2 (bf16, row-local) -> augmented bf16 G rows
__global__ __launch_bounds__(256) void mul_pack_g(const ushort_t* __restrict__ g12,
                                                  ushort_t* __restrict__ G) {
    long idx = (long)blockIdx.x * 256 + threadIdx.x;   // MROWS*1024
    long p = idx >> 10; int i = (int)(idx & 1023);
    float v = bf2f(g12[p * 2048 + i]) * bf2f(g12[p * 2048 + 1024 + i]);
    float ch[9];
    ch[0] = v * sigmoidf_(v);
    bspline8(v, ch + 1);
    ushort_t* oh = G + p * (long)KAUG + i;
#pragma unroll
    for (int c = 0; c < 9; ++c) oh[(long)c * 1024] = f2bf(ch[c]);
}

// ---------------- elementwise f32 -> bf16 hi/lo split
__global__ __launch_bounds__(256) void split_pack(const float* __restrict__ in,
                                                  ushort_t* __restrict__ hi,
                                                  ushort_t* __restrict__ lo, long n) {
    long i = (long)blockIdx.x * 256 + threadIdx.x;
    if (i >= n) return;
    float v = in[i];
    unsigned short h = f2bf(v);
    hi[i] = h;
    lo[i] = f2bf(v - bf2f(h));
}

// =====================================================================
// MFMA GEMM (m97 structure): C(M,N) = A(M,K) @ B(N,K)^T, bf16 ops fp32 acc.
// BM x 128 tile, BK=32, 4 waves (2x2). 2-bit XOR chunk swizzle on LDS
// (pre-swizzled global source). SPLIT: 3-pass hi/lo (fp32-class).
// MODE 0: C = acc (fp32)
// MODE 5: splitK (z=kk): atomicAdd C += acc  (C pre-zeroed/prefilled)
// MODE 6: C bf16 = acc
// MODE 7: grouped-MoE w1w2: e=eblk[by]; A row gathered via rmap; B+=e*2048*K;
//         C bf16 (N=2048)
// MODE 8: grouped-MoE w3 (z=kk): e=eblk[by]; B+=e*1024*K;
//         atomicAdd out[rmap[row]*N+col] += rwgt[row]*acc
// =====================================================================
#define GLD(gp, lp) __builtin_amdgcn_global_load_lds( \
    (const __attribute__((address_space(1))) void*)(gp), \
    (__attribute__((address_space(3))) void*)(lp), 16, 0, 0)

template<int BM, int SPLIT, int MODE, int KSPLIT>
__global__ __launch_bounds__(256) void mfma_gemm2(const ushort_t* __restrict__ Ah,
                                                  const ushort_t* __restrict__ Al,
                                                  const ushort_t* __restrict__ Bh,
                                                  const ushort_t* __restrict__ Bl,
                                                  float* __restrict__ C,
                                                  const int* __restrict__ rmap,
                                                  const int* __restrict__ eblk,
                                                  const float* __restrict__ rwgt,
                                                  int N, int K) {
    constexpr int NM = BM / 32;            // A fragments per wave
    __shared__ __align__(16) ushort_t AsH[BM * 32];
    __shared__ __align__(16) ushort_t BsH[128 * 32];
    __shared__ __align__(16) ushort_t AsL[SPLIT ? BM * 32 : 16];
    __shared__ __align__(16) ushort_t BsL[SPLIT ? 128 * 32 : 16];
    const int bm = blockIdx.y * BM, bn = blockIdx.x * 128;

    const int KC = K / KSPLIT;
    int kk = (KSPLIT > 1) ? blockIdx.z : 0;
    int e = 0;
    if constexpr (MODE == 7 || MODE == 8) e = eblk[blockIdx.y];
    const ushort_t* Ap = Ah + (size_t)kk * KC;
    const ushort_t* Bp = Bh + (size_t)kk * KC
                            + (MODE == 7 ? (size_t)e * 2048 * (size_t)K : 0)
                            + (MODE == 8 ? (size_t)e * 1024 * (size_t)K : 0);
    const ushort_t* Alp = SPLIT ? Al + (size_t)kk * KC : nullptr;
    const ushort_t* Blp = SPLIT ? Bl + (size_t)kk * KC : nullptr;

    const int tid = threadIdx.x;
    const int w = tid >> 6, l = tid & 63;
    const int wr = w >> 1, wc = w & 1;
    const int half = l >> 4, lr = l & 15;
    const size_t rb = (size_t)K * 2;       // full row bytes

    const int rowB0 = w * 32 + (l >> 2), rowB1 = rowB0 + 16;
    const int cch = l & 3;
    const char* gB0 = (const char*)Bp + (size_t)(bn + rowB0) * rb + ((cch ^ (rowB0 & 3)) * 16);
    const char* gB1 = (const char*)Bp + (size_t)(bn + rowB1) * rb + ((cch ^ (rowB1 & 3)) * 16);
    const char* gB0l = SPLIT ? (const char*)Blp + (size_t)(bn + rowB0) * rb + ((cch ^ (rowB0 & 3)) * 16) : nullptr;
    const char* gB1l = SPLIT ? (const char*)Blp + (size_t)(bn + rowB1) * rb + ((cch ^ (rowB1 & 3)) * 16) : nullptr;
    int rowA0, rowA1;
    if constexpr (BM == 128) { rowA0 = w * 32 + (l >> 2); rowA1 = rowA0 + 16; }
    else                     { rowA0 = w * 16 + (l >> 2); rowA1 = 0; }
    size_t arow0, arow1 = 0;
    if constexpr (MODE == 7) {
        arow0 = (size_t)rmap[bm + rowA0];
        if (BM == 128) arow1 = (size_t)rmap[bm + rowA1];
    } else {
        arow0 = (size_t)(bm + rowA0);
        if (BM == 128) arow1 = (size_t)(bm + rowA1);
    }
    const char* gA0 = (const char*)Ap + arow0 * rb + ((cch ^ (rowA0 & 3)) * 16);
    const char* gA1 = (BM == 128) ? (const char*)Ap + arow1 * rb + ((cch ^ (rowA1 & 3)) * 16) : nullptr;
    const char* gA0l = SPLIT ? (const char*)Alp + arow0 * rb + ((cch ^ (rowA0 & 3)) * 16) : nullptr;
    const char* gA1l = (SPLIT && BM == 128) ? (const char*)Alp + arow1 * rb + ((cch ^ (rowA1 & 3)) * 16) : nullptr;

    f32x4 acc[NM][4] = {};
    for (int k0 = 0; k0 < KC; k0 += 32) {
        const size_t kb = (size_t)k0 * 2;
        GLD(gA0 + kb, (char*)AsH + ((BM == 128) ? w * 2048 : w * 1024) + l * 16);
        if constexpr (BM == 128) GLD(gA1 + kb, (char*)AsH + w * 2048 + 1024 + l * 16);
        GLD(gB0 + kb, (char*)BsH + w * 2048 + l * 16);
        GLD(gB1 + kb, (char*)BsH + w * 2048 + 1024 + l * 16);
        if constexpr (SPLIT) {
            GLD(gA0l + kb, (char*)AsL + ((BM == 128) ? w * 2048 : w * 1024) + l * 16);
            if constexpr (BM == 128) GLD(gA1l + kb, (char*)AsL + w * 2048 + 1024 + l * 16);
            GLD(gB0l + kb, (char*)BsL + w * 2048 + l * 16);
            GLD(gB1l + kb, (char*)BsL + w * 2048 + 1024 + l * 16);
        }
        __syncthreads();
        bf16x8 ah[NM], bh[4];
#pragma unroll
        for (int mi = 0; mi < NM; ++mi) {
            int r = wr * (BM / 2) + mi * 16 + lr;
            ah[mi] = *(const bf16x8*)((const char*)AsH + r * 64 + ((half ^ (r & 3)) * 16));
        }
#pragma unroll
        for (int ni = 0; ni < 4; ++ni) {
            int r = wc * 64 + ni * 16 + lr;
            bh[ni] = *(const bf16x8*)((const char*)BsH + r * 64 + ((half ^ (r & 3)) * 16));
        }
#pragma unroll
        for (int mi = 0; mi < NM; ++mi)
#pragma unroll
            for (int ni = 0; ni < 4; ++ni)
                acc[mi][ni] = __builtin_amdgcn_mfma_f32_16x16x32_bf16(ah[mi], bh[ni],
                                                                      acc[mi][ni], 0, 0, 0);
        if constexpr (SPLIT) {
            bf16x8 al[NM], bl[4];
#pragma unroll
            for (int mi = 0; mi < NM; ++mi) {
                int r = wr * (BM / 2) + mi * 16 + lr;
                al[mi] = *(const bf16x8*)((const char*)AsL + r * 64 + ((half ^ (r & 3)) * 16));
            }
#pragma unroll
            for (int ni = 0; ni < 4; ++ni) {
                int r = wc * 64 + ni * 16 + lr;
                bl[ni] = *(const bf16x8*)((const char*)BsL + r * 64 + ((half ^ (r & 3)) * 16));
            }
#pragma unroll
            for (int mi = 0; mi < NM; ++mi)
#pragma unroll
                for (int ni = 0; ni < 4; ++ni) {
                    acc[mi][ni] = __builtin_amdgcn_mfma_f32_16x16x32_bf16(ah[mi], bl[ni],
                                                                          acc[mi][ni], 0, 0, 0);
                    acc[mi][ni] = __builtin_amdgcn_mfma_f32_16x16x32_bf16(al[mi], bh[ni],
                                                                          acc[mi][ni], 0, 0, 0);
                }
        }
        __syncthreads();
    }
    // epilogue: C/D layout col=lane&15, row=(lane>>4)*4+reg
#pragma unroll
    for (int mi = 0; mi < NM; ++mi)
#pragma unroll
        for (int r = 0; r < 4; ++r) {
            int row = bm + wr * (BM / 2) + mi * 16 + half * 4 + r;
            int token = 0; float wv = 0.0f;
            if constexpr (MODE == 8) { token = rmap[row]; wv = rwgt[row]; }
#pragma unroll
            for (int ni = 0; ni < 4; ++ni) {
                int col = bn + wc * 64 + ni * 16 + lr;
                size_t ix = (size_t)row * N + col;
                if constexpr (MODE == 0)      C[ix] = acc[mi][ni][r];
                else if constexpr (MODE == 5) unsafeAtomicAdd(&C[ix], acc[mi][ni][r]);
                else if constexpr (MODE == 8)
                    unsafeAtomicAdd(&C[(size_t)token * N + col], wv * acc[mi][ni][r]);
                else                          ((ushort_t*)C)[ix] = f2bf(acc[mi][ni][r]);
            }
        }
}

// ---------------- fused rope + split-bf16 pack of q,k (q pre-scaled by 1/8)
__global__ __launch_bounds__(256) void qk_pack(const float* __restrict__ qkv,
                                               const float* __restrict__ cs,
                                               const float* __restrict__ sn,
                                               ushort_t* __restrict__ Qh, ushort_t* __restrict__ Ql,
                                               ushort_t* __restrict__ Kh, ushort_t* __restrict__ Kl) {
    int idx = blockIdx.x * 256 + threadIdx.x;   // B*S*NH*32 = 1M
    int p = idx & 31;
    int h = (idx >> 5) & 15;
    int s = (idx >> 9) & (S_SEQ - 1);
    int b = idx >> 19;
    float c = cs[s * 32 + p], si = sn[s * 32 + p];
    long base = ((long)(b * S_SEQ + s)) * 3072 + h * 192;
    long dst = (((long)(b * NHEAD + h)) * S_SEQ + s) * 64 + 2 * p;
    float re = qkv[base + 2 * p], im = qkv[base + 2 * p + 1];
    float qre = (re * c - im * si) * 0.125f;
    float qim = (re * si + im * c) * 0.125f;
    unsigned short hh = f2bf(qre);
    Qh[dst] = hh; Ql[dst] = f2bf(qre - bf2f(hh));
    hh = f2bf(qim);
    Qh[dst + 1] = hh; Ql[dst + 1] = f2bf(qim - bf2f(hh));
    re = qkv[base + 64 + 2 * p]; im = qkv[base + 64 + 2 * p + 1];
    float kre = re * c - im * si;
    float kim = re * si + im * c;
    hh = f2bf(kre);
    Kh[dst] = hh; Kl[dst] = f2bf(kre - bf2f(hh));
    hh = f2bf(kim);
    Kh[dst + 1] = hh; Kl[dst + 1] = f2bf(kim - bf2f(hh));
}

// ---------------- V transpose + split: qkv v-part -> Vt [b][h][64 d][1024 s]
__global__ __launch_bounds__(256) void v_trans(const float* __restrict__ qkv,
                                               ushort_t* __restrict__ Vth,
                                               ushort_t* __restrict__ Vtl) {
    __shared__ float t[64][65];
    const int s0 = blockIdx.x * 64, h = blockIdx.y, b = blockIdx.z;
    const int tid = threadIdx.x;
#pragma unroll
    for (int i = 0; i < 16; ++i) {
        int e = tid + i * 256;
        int sl = e >> 6, d = e & 63;
        t[d][sl] = qkv[((long)(b * S_SEQ + s0 + sl)) * 3072 + h * 192 + 128 + d];
    }
    __syncthreads();
#pragma unroll
    for (int i = 0; i < 16; ++i) {
        int e = tid + i * 256;
        int d = e >> 6, sl = e & 63;
        float v = t[d][sl];
        long o = (((long)(b * NHEAD + h)) * 64 + d) * S_SEQ + s0 + sl;
        unsigned short hh = f2bf(v);
        Vth[o] = hh;
        Vtl[o] = f2bf(v - bf2f(hh));
    }
}

// =====================================================================
// MFMA flash attention, full hi/lo split (fp32-class accuracy).
// =====================================================================
__device__ __forceinline__ bf16x8 lds_frag(const ushort_t* base, int row, int chunk) {
    return *(const bf16x8*)((const char*)base + row * 128 + ((chunk ^ (row & 7)) * 16));
}

__global__ __launch_bounds__(256) void attn_mfma(const ushort_t* __restrict__ Qh,
                                                 const ushort_t* __restrict__ Ql,
                                                 const ushort_t* __restrict__ Kh,
                                                 const ushort_t* __restrict__ Kl,
                                                 const ushort_t* __restrict__ Vth,
                                                 const ushort_t* __restrict__ Vtl,
                                                 float* __restrict__ ctx) {
    __shared__ __align__(16) ushort_t KsH[64 * 64], KsL[64 * 64];
    __shared__ __align__(16) ushort_t VsH[64 * 64], VsL[64 * 64];
    __shared__ __align__(16) ushort_t Ps[4][2][16][72];
    const int qb = blockIdx.x * 64, h = blockIdx.y, b = blockIdx.z;
    const int tid = threadIdx.x;
    const int w = tid >> 6, l = tid & 63;
    const int lr = l & 15, g = l >> 4;
    const long bh = b * NHEAD + h;

    const long qoff = (bh * S_SEQ + qb + w * 16 + lr) * 64 + g * 8;
    bf16x8 qh0 = *(const bf16x8*)(Qh + qoff);
    bf16x8 qh1 = *(const bf16x8*)(Qh + qoff + 32);
    bf16x8 ql0 = *(const bf16x8*)(Ql + qoff);
    bf16x8 ql1 = *(const bf16x8*)(Ql + qoff + 32);

    const int rowS0 = w * 16 + (l >> 3), rowS1 = rowS0 + 8;
    const int cch = l & 7;
    const char* gK0 = (const char*)Kh + (bh * S_SEQ + rowS0) * 128 + ((cch ^ (rowS0 & 7)) * 16);
    const char* gK1 = (const char*)Kh + (bh * S_SEQ + rowS1) * 128 + ((cch ^ (rowS1 & 7)) * 16);
    const char* gKl0 = (const char*)Kl + (bh * S_SEQ + rowS0) * 128 + ((cch ^ (rowS0 & 7)) * 16);
    const char* gKl1 = (const char*)Kl + (bh * S_SEQ + rowS1) * 128 + ((cch ^ (rowS1 & 7)) * 16);
    const char* gV0 = (const char*)Vth + (bh * 64 + rowS0) * 2048 + ((cch ^ (rowS0 & 7)) * 16);
    const char* gV1 = (const char*)Vth + (bh * 64 + rowS1) * 2048 + ((cch ^ (rowS1 & 7)) * 16);
    const char* gVl0 = (const char*)Vtl + (bh * 64 + rowS0) * 2048 + ((cch ^ (rowS0 & 7)) * 16);
    const char* gVl1 = (const char*)Vtl + (bh * 64 + rowS1) * 2048 + ((cch ^ (rowS1 & 7)) * 16);

    float m_run[4] = {-1e30f, -1e30f, -1e30f, -1e30f};
    float l_run[4] = {0.f, 0.f, 0.f, 0.f};
    f32x4 acco[4] = {};

    for (int k0 = 0; k0 < S_SEQ; k0 += 64) {
        GLD(gK0 + (size_t)k0 * 128, (char*)KsH + w * 2048 + l * 16);
        GLD(gK1 + (size_t)k0 * 128, (char*)KsH + w * 2048 + 1024 + l * 16);
        GLD(gKl0 + (size_t)k0 * 128, (char*)KsL + w * 2048 + l * 16);
        GLD(gKl1 + (size_t)k0 * 128, (char*)KsL + w * 2048 + 1024 + l * 16);
        GLD(gV0 + (size_t)k0 * 2, (char*)VsH + w * 2048 + l * 16);
        GLD(gV1 + (size_t)k0 * 2, (char*)VsH + w * 2048 + 1024 + l * 16);
        GLD(gVl0 + (size_t)k0 * 2, (char*)VsL + w * 2048 + l * 16);
        GLD(gVl1 + (size_t)k0 * 2, (char*)VsL + w * 2048 + 1024 + l * 16);
        __syncthreads();

        f32x4 accs[4] = {};
#pragma unroll
        for (int n = 0; n < 4; ++n) {
            bf16x8 bkh0 = lds_frag(KsH, n * 16 + lr, g);
            bf16x8 bkh1 = lds_frag(KsH, n * 16 + lr, g + 4);
            bf16x8 bkl0 = lds_frag(KsL, n * 16 + lr, g);
            bf16x8 bkl1 = lds_frag(KsL, n * 16 + lr, g + 4);
            accs[n] = __builtin_amdgcn_mfma_f32_16x16x32_bf16(qh0, bkh0, accs[n], 0, 0, 0);
            accs[n] = __builtin_amdgcn_mfma_f32_16x16x32_bf16(qh1, bkh1, accs[n], 0, 0, 0);
            accs[n] = __builtin_amdgcn_mfma_f32_16x16x32_bf16(qh0, bkl0, accs[n], 0, 0, 0);
            accs[n] = __builtin_amdgcn_mfma_f32_16x16x32_bf16(qh1, bkl1, accs[n], 0, 0, 0);
            accs[n] = __builtin_amdgcn_mfma_f32_16x16x32_bf16(ql0, bkh0, accs[n], 0, 0, 0);
            accs[n] = __builtin_amdgcn_mfma_f32_16x16x32_bf16(ql1, bkh1, accs[n], 0, 0, 0);
        }
        float alpha[4];
#pragma unroll
        for (int r = 0; r < 4; ++r) {
            float mx = fmaxf(fmaxf(accs[0][r], accs[1][r]), fmaxf(accs[2][r], accs[3][r]));
#pragma unroll
            for (int msk = 1; msk < 16; msk <<= 1) mx = fmaxf(mx, __shfl_xor(mx, msk, 64));
            float m_new = fmaxf(m_run[r], mx);
            float ps = 0.f;
#pragma unroll
            for (int n = 0; n < 4; ++n) {
                float p = __expf(accs[n][r] - m_new);
                accs[n][r] = p;
                ps += p;
            }
#pragma unroll
            for (int msk = 1; msk < 16; msk <<= 1) ps += __shfl_xor(ps, msk, 64);
            alpha[r] = __expf(m_run[r] - m_new);
            l_run[r] = l_run[r] * alpha[r] + ps;
            m_run[r] = m_new;
        }
#pragma unroll
        for (int nd = 0; nd < 4; ++nd)
#pragma unroll
            for (int r = 0; r < 4; ++r) acco[nd][r] *= alpha[r];
#pragma unroll
        for (int n = 0; n < 4; ++n)
#pragma unroll
            for (int r = 0; r < 4; ++r) {
                float p = accs[n][r];
                unsigned short hh = f2bf(p);
                Ps[w][0][g * 4 + r][n * 16 + lr] = hh;
                Ps[w][1][g * 4 + r][n * 16 + lr] = f2bf(p - bf2f(hh));
            }
        __syncthreads();
        bf16x8 pah0 = *(const bf16x8*)&Ps[w][0][lr][g * 8];
        bf16x8 pah1 = *(const bf16x8*)&Ps[w][0][lr][32 + g * 8];
        bf16x8 pal0 = *(const bf16x8*)&Ps[w][1][lr][g * 8];
        bf16x8 pal1 = *(const bf16x8*)&Ps[w][1][lr][32 + g * 8];
#pragma unroll
        for (int nd = 0; nd < 4; ++nd) {
            bf16x8 bvh0 = lds_frag(VsH, nd * 16 + lr, g);
            bf16x8 bvh1 = lds_frag(VsH, nd * 16 + lr, g + 4);
            bf16x8 bvl0 = lds_frag(VsL, nd * 16 + lr, g);
            bf16x8 bvl1 = lds_frag(VsL, nd * 16 + lr, g + 4);
            acco[nd] = __builtin_amdgcn_mfma_f32_16x16x32_bf16(pah0, bvh0, acco[nd], 0, 0, 0);
            acco[nd] = __builtin_amdgcn_mfma_f32_16x16x32_bf16(pah1, bvh1, acco[nd], 0, 0, 0);
            acco[nd] = __builtin_amdgcn_mfma_f32_16x16x32_bf16(pah0, bvl0, acco[nd], 0, 0, 0);
            acco[nd] = __builtin_amdgcn_mfma_f32_16x16x32_bf16(pah1, bvl1, acco[nd], 0, 0, 0);
            acco[nd] = __builtin_amdgcn_mfma_f32_16x16x32_bf16(pal0, bvh0, acco[nd], 0, 0, 0);
            acco[nd] = __builtin_amdgcn_mfma_f32_16x16x32_bf16(pal1, bvh1, acco[nd], 0, 0, 0);
        }
        __syncthreads();
    }
#pragma unroll
    for (int r = 0; r < 4; ++r) {
        float inv = 1.0f / l_run[r];
        long row = (long)b * S_SEQ + qb + w * 16 + g * 4 + r;
#pragma unroll
        for (int nd = 0; nd < 4; ++nd)
            ctx[row * H_DIM + h * 64 + nd * 16 + lr] = acco[nd][r] * inv;
    }
}

// ---------------- gate + route: top-2 sel/weights + per-expert counts
__global__ __launch_bounds__(256) void gate_route(const float* __restrict__ h2,
                                                  const float* __restrict__ gate_w,
                                                  int2* __restrict__ sel,
                                                  float2* __restrict__ selw,
                                                  int* __restrict__ cnts) {
    long t = blockIdx.x;
    float sum[4] = {0, 0, 0, 0};
    for (int i = threadIdx.x; i < H_DIM; i += 256) {
        float v = h2[t * H_DIM + i];
#pragma unroll
        for (int e = 0; e < 4; ++e) sum[e] = fmaf(v, gate_w[e * H_DIM + i], sum[e]);
    }
#pragma unroll
    for (int w = 1; w < 64; w <<= 1)
#pragma unroll
        for (int e = 0; e < 4; ++e) sum[e] += __shfl_xor(sum[e], w, 64);
    __shared__ float part[4][4];
    if ((threadIdx.x & 63) == 0)
#pragma unroll
        for (int e = 0; e < 4; ++e) part[e][threadIdx.x >> 6] = sum[e];
    __syncthreads();
    if (threadIdx.x == 0) {
        float lg[4];
#pragma unroll
        for (int e = 0; e < 4; ++e) lg[e] = part[e][0] + part[e][1] + part[e][2] + part[e][3];
        int i0 = 0;
        for (int e = 1; e < 4; ++e) if (lg[e] > lg[i0]) i0 = e;   // ties -> lower idx
        int i1 = -1;
        for (int e = 0; e < 4; ++e) if (e != i0 && (i1 < 0 || lg[e] > lg[i1])) i1 = e;
        float mx = fmaxf(lg[i0], lg[i1]);
        float e0 = __expf(lg[i0] - mx), e1 = __expf(lg[i1] - mx);
        float inv = 1.0f / (e0 + e1);
        sel[t] = make_int2(i0, i1);
        selw[t] = make_float2(e0 * inv, e1 * inv);
        atomicAdd(&cnts[i0], 1);
        atomicAdd(&cnts[i1], 1);
    }
}

// ---------------- route offsets (single block): 128-aligned segments + eblk
__global__ void route_offsets(const int* __restrict__ cnts, int* __restrict__ fill,
                              int* __restrict__ off, int* __restrict__ eblk) {
    if (threadIdx.x != 0) return;
    int o = 0;
    for (int e = 0; e < 4; ++e) {
        off[e] = o;
        fill[e] = o;
        o += ((cnts[e] + 127) >> 7) << 7;
    }
    off[4] = o;
    for (int rb = 0; rb < NRB; ++rb) {
        int rs = rb * 128, e = 0;
        for (int q = 0; q < 4; ++q)
            if (rs >= off[q] && rs < off[q + 1]) e = q;
        eblk[rb] = e;
    }
}

// ---------------- route scatter: token -> permuted row slots
__global__ __launch_bounds__(256) void route_scatter(const int2* __restrict__ sel,
                                                     const float2* __restrict__ selw,
                                                     int* __restrict__ fill,
                                                     int* __restrict__ map,
                                                     float* __restrict__ wgt) {
    int t = blockIdx.x * 256 + threadIdx.x;
    if (t >= T_TOK) return;
    int2 s = sel[t]; float2 w = selw[t];
    int p0 = atomicAdd(&fill[s.x], 1); map[p0] = t; wgt[p0] = w.x;
    int p1 = atomicAdd(&fill[s.y], 1); map[p1] = t; wgt[p1] = w.y;
}

// ================= fallback-only kernels (round-0 fp32 path) =================
#define KI 8
#define BKK 72
__global__ __launch_bounds__(256) void kan_gemm(const float* __restrict__ Act,
                                                const float* __restrict__ baseW,
                                                const float* __restrict__ splW,
                                                const float* __restrict__ scal,
                                                float* __restrict__ C,
                                                const float* __restrict__ rowScale,
                                                int rsStride, int N, int mode) {
    __shared__ float As[BKK][64];
    __shared__ float Bs[BKK][64];
    const int bm = blockIdx.y * 64;
    const int bn = blockIdx.x * 64;
    const int tid = threadIdx.x;
    const int tx = tid & 15, ty = tid >> 4;
    float acc[4][4] = {};
    for (int i0 = 0; i0 < H_DIM; i0 += KI) {
        for (int e = tid; e < 64 * KI; e += 256) {
            int m = e >> 3, ii = e & 7;
            float xv = Act[(long)(bm + m) * H_DIM + i0 + ii];
            float sp[8];
            bspline8(xv, sp);
            As[ii * 9][m] = xv * sigmoidf_(xv);
#pragma unroll
            for (int c = 0; c < 8; ++c) As[ii * 9 + 1 + c][m] = sp[c];
        }
        for (int e = tid; e < 64 * KI; e += 256) {
            int n = e >> 3, ii = e & 7;
            long w = (long)(bn + n) * H_DIM + i0 + ii;
            float sc = scal[w];
            Bs[ii * 9][n] = baseW[w];
            const float4* sp4 = (const float4*)(splW + w * 8);
            float4 s0 = sp4[0], s1 = sp4[1];
            Bs[ii * 9 + 1][n] = s0.x * sc; Bs[ii * 9 + 2][n] = s0.y * sc;
            Bs[ii * 9 + 3][n] = s0.z * sc; Bs[ii * 9 + 4][n] = s0.w * sc;
            Bs[ii * 9 + 5][n] = s1.x * sc; Bs[ii * 9 + 6][n] = s1.y * sc;
            Bs[ii * 9 + 7][n] = s1.z * sc; Bs[ii * 9 + 8][n] = s1.w * sc;
        }
        __syncthreads();
#pragma unroll 8
        for (int k = 0; k < BKK; ++k) {
            float4 a = *(const float4*)&As[k][ty * 4];
            float4 b = *(const float4*)&Bs[k][tx * 4];
            float av[4] = {a.x, a.y, a.z, a.w};
            float bv[4] = {b.x, b.y, b.z, b.w};
#pragma unroll
            for (int i = 0; i < 4; ++i)
#pragma unroll
                for (int j = 0; j < 4; ++j) acc[i][j] = fmaf(av[i], bv[j], acc[i][j]);
        }
        __syncthreads();
    }
#pragma unroll
    for (int i = 0; i < 4; ++i) {
        long m = bm + ty * 4 + i;
        float rs = (mode == 1) ? rowScale[m * rsStride] : 0.0f;
#pragma unroll
        for (int j = 0; j < 4; ++j) {
            long idx = m * (long)N + bn + tx * 4 + j;
            if (mode == 0) C[idx] = acc[i][j];
            else           C[idx] += rs * acc[i][j];
        }
    }
}

__global__ __launch_bounds__(256) void gemm_bias_res(const float* __restrict__ A,
                                                     const float* __restrict__ Bw,
                                                     const float* __restrict__ bias,
                                                     const float* __restrict__ res,
                                                     float* __restrict__ C) {
    __shared__ float As[16][64];
    __shared__ float Bs[16][64];
    const int bm = blockIdx.y * 64, bn = blockIdx.x * 64;
    const int tid = threadIdx.x;
    const int tx = tid & 15, ty = tid >> 4;
    float acc[4][4] = {};
    for (int k0 = 0; k0 < 1024; k0 += 16) {
        for (int e = tid; e < 1024; e += 256) {
            int r = e >> 4, kk = e & 15;
            As[kk][r] = A[(long)(bm + r) * 1024 + k0 + kk];
            Bs[kk][r] = Bw[(long)(bn + r) * 1024 + k0 + kk];
        }
        __syncthreads();
#pragma unroll
        for (int k = 0; k < 16; ++k) {
            float4 a = *(const float4*)&As[k][ty * 4];
            float4 b = *(const float4*)&Bs[k][tx * 4];
            float av[4] = {a.x, a.y, a.z, a.w};
            float bv[4] = {b.x, b.y, b.z, b.w};
#pragma unroll
            for (int i = 0; i < 4; ++i)
#pragma unroll
                for (int j = 0; j < 4; ++j) acc[i][j] = fmaf(av[i], bv[j], acc[i][j]);
        }
        __syncthreads();
    }
#pragma unroll
    for (int i = 0; i < 4; ++i) {
        long m = bm + ty * 4 + i;
#pragma unroll
        for (int j = 0; j < 4; ++j) {
            long n = bn + tx * 4 + j;
            C[m * 1024 + n] = res[m * 1024 + n] + bias[n] + acc[i][j];
        }
    }
}

__global__ __launch_bounds__(256) void rope_kernel(float* __restrict__ qkv,
                                                   const float* __restrict__ cs,
                                                   const float* __restrict__ sn) {
    int idx = blockIdx.x * 256 + threadIdx.x;
    if (idx >= T_TOK * NHEAD * 32) return;
    int p = idx & 31;
    int n = (idx >> 5) & 15;
    int t = idx >> 9;
    int s = t & (S_SEQ - 1);
    float c = cs[s * 32 + p], si = sn[s * 32 + p];
    long base = (long)t * 3072 + n * 192;
    float re = qkv[base + 2 * p], im = qkv[base + 2 * p + 1];
    qkv[base + 2 * p]     = re * c - im * si;
    qkv[base + 2 * p + 1] = re * si + im * c;
    re = qkv[base + 64 + 2 * p]; im = qkv[base + 64 + 2 * p + 1];
    qkv[base + 64 + 2 * p]     = re * c - im * si;
    qkv[base + 64 + 2 * p + 1] = re * si + im * c;
}

__global__ __launch_bounds__(256) void attn_kernel(const float* __restrict__ qkv,
                                                   float* __restrict__ ctx) {
    const int qb = blockIdx.x * 32;
    const int h = blockIdx.y, b = blockIdx.z;
    __shared__ float Qs[32][64];
    __shared__ float Ks[64][64];
    __shared__ float Vs[64][64];
    __shared__ float Ss[32][64];
    const int tid = threadIdx.x;
    const int q = tid >> 3, g = tid & 7;
    for (int e = tid; e < 32 * 64; e += 256) {
        int r = e >> 6, d = e & 63;
        Qs[r][d] = qkv[(long)(b * S_SEQ + qb + r) * 3072 + h * 192 + d];
    }
    float m_run = -1e30f, l_run = 0.0f;
    float acc[8] = {};
    for (int k0 = 0; k0 < S_SEQ; k0 += 64) {
        for (int e = tid; e < 64 * 64; e += 256) {
            int r = e >> 6, d = e & 63;
            long base = (long)(b * S_SEQ + k0 + r) * 3072 + h * 192;
            Ks[r][d] = qkv[base + 64 + d];
            Vs[r][d] = qkv[base + 128 + d];
        }
        __syncthreads();
        float s[8];
#pragma unroll
        for (int kk = 0; kk < 8; ++kk) {
            int k = g * 8 + kk;
            float dot = 0.0f;
#pragma unroll
            for (int d = 0; d < 64; ++d) dot = fmaf(Qs[q][d], Ks[k][d], dot);
            s[kk] = dot * 0.125f;
        }
        float mx = s[0];
#pragma unroll
        for (int kk = 1; kk < 8; ++kk) mx = fmaxf(mx, s[kk]);
#pragma unroll
        for (int w = 1; w < 8; w <<= 1) mx = fmaxf(mx, __shfl_xor(mx, w, 64));
        float m_new = fmaxf(m_run, mx);
        float p[8], ls = 0.0f;
#pragma unroll
        for (int kk = 0; kk < 8; ++kk) { p[kk] = __expf(s[kk] - m_new); ls += p[kk]; }
#pragma unroll
        for (int w = 1; w < 8; w <<= 1) ls += __shfl_xor(ls, w, 64);
        float alpha = __expf(m_run - m_new);
        l_run = l_run * alpha + ls;
        m_run = m_new;
#pragma unroll
        for (int kk = 0; kk < 8; ++kk) Ss[q][g * 8 + kk] = p[kk];
        __syncthreads();
#pragma unroll
        for (int j = 0; j < 8; ++j) acc[j] *= alpha;
        for (int k = 0; k < 64; ++k) {
            float pv = Ss[q][k];
#pragma unroll
            for (int j = 0; j < 8; ++j) acc[j] = fmaf(pv, Vs[k][g * 8 + j], acc[j]);
        }
        __syncthreads();
    }
    float inv = 1.0f / l_run;
#pragma unroll
    for (int j = 0; j < 8; ++j)
        ctx[(long)(b * S_SEQ + qb + q) * H_DIM + h * 64 + g * 8 + j] = acc[j] * inv;
}

__global__ __launch_bounds__(256) void gate_kernel(const float* __restrict__ h2,
                                                   const float* __restrict__ gate_w,
                                                   float* __restrict__ gw) {
    long t = blockIdx.x;
    float sum[4] = {0, 0, 0, 0};
    for (int i = threadIdx.x; i < H_DIM; i += 256) {
        float v = h2[t * H_DIM + i];
#pragma unroll
        for (int e = 0; e < 4; ++e) sum[e] = fmaf(v, gate_w[e * H_DIM + i], sum[e]);
    }
#pragma unroll
    for (int w = 1; w < 64; w <<= 1)
#pragma unroll
        for (int e = 0; e < 4; ++e) sum[e] += __shfl_xor(sum[e], w, 64);
    __shared__ float part[4][4];
    if ((threadIdx.x & 63) == 0)
#pragma unroll
        for (int e = 0; e < 4; ++e) part[e][threadIdx.x >> 6] = sum[e];
    __syncthreads();
    if (threadIdx.x == 0) {
        float lg[4];
#pragma unroll
        for (int e = 0; e < 4; ++e) lg[e] = part[e][0] + part[e][1] + part[e][2] + part[e][3];
        int i0 = 0;
        for (int e = 1; e < 4; ++e) if (lg[e] > lg[i0]) i0 = e;
        int i1 = -1;
        for (int e = 0; e < 4; ++e) if (e != i0 && (i1 < 0 || lg[e] > lg[i1])) i1 = e;
        float mx = fmaxf(lg[i0], lg[i1]);
        float e0 = __expf(lg[i0] - mx), e1 = __expf(lg[i1] - mx);
        float inv = 1.0f / (e0 + e1);
        float o[4] = {0, 0, 0, 0};
        o[i0] = e0 * inv; o[i1] = e1 * inv;
#pragma unroll
        for (int e = 0; e < 4; ++e) gw[t * 4 + e] = o[e];
    }
}

__global__ __launch_bounds__(256) void mul_kernel(const float* __restrict__ a,
                                                  const float* __restrict__ b,
                                                  float* __restrict__ c, int n) {
    int i = blockIdx.x * 256 + threadIdx.x;
    if (i < n) c[i] = a[i] * b[i];
}

extern "C" void kernel_launch(void* const* d_in, const int* in_sizes, int n_in,
                              void* d_out, int out_size, void* d_ws, size_t ws_size,
                              hipStream_t stream) {
    const float* x          = (const float*)d_in[0];
    const float* rot_cos    = (const float*)d_in[1];
    const float* rot_sin    = (const float*)d_in[2];
    const float* norm1_w    = (const float*)d_in[3];
    const float* norm2_w    = (const float*)d_in[4];
    const float* qkv_base   = (const float*)d_in[5];
    const float* qkv_spline = (const float*)d_in[6];
    const float* qkv_scaler = (const float*)d_in[7];
    const float* out_w      = (const float*)d_in[8];
    const float* out_b      = (const float*)d_in[9];
    const float* gate_w     = (const float*)d_in[10];
    const float* w1_base    = (const float*)d_in[11];
    const float* w1_spline  = (const float*)d_in[12];
    const float* w1_scaler  = (const float*)d_in[13];
    const float* w2_base    = (const float*)d_in[14];
    const float* w2_spline  = (const float*)d_in[15];
    const float* w2_scaler  = (const float*)d_in[16];
    const float* w3_base    = (const float*)d_in[17];
    const float* w3_spline  = (const float*)d_in[18];
    const float* w3_scaler  = (const float*)d_in[19];
    float* out = (float*)d_out;

    const size_t SZ_AUG  = (size_t)T_TOK * KAUG * 2;   // 37,748,736
    const size_t SZ_WQ   = (size_t)3072 * KAUG * 2;    // 56,623,104
    const size_t SZ_QKV  = (size_t)T_TOK * 3072 * 4;   // 25,165,824
    const size_t SZ_G12  = (size_t)T_TOK * 2048 * 4;   // 16,777,216
    const size_t SZ_TOK  = (size_t)T_TOK * H_DIM * 4;  //  8,388,608
    const size_t NEED = 2 * SZ_AUG + 2 * SZ_WQ + SZ_QKV + SZ_G12 + 2 * SZ_TOK + 32768;

    if (ws_size >= NEED) {
        char* pool = (char*)d_ws;
        // ---- attention-phase overlay ----
        ushort_t* A_hi = (ushort_t*)pool;
        ushort_t* A_lo = (ushort_t*)(pool + SZ_AUG);
        char* W1p = pool + 2 * SZ_AUG;
        char* W2p = pool + 2 * SZ_AUG + SZ_WQ;
        float* qkv = (float*)(pool + 2 * SZ_AUG + 2 * SZ_WQ);
        float* ctx = (float*)(pool + 2 * SZ_AUG + 2 * SZ_WQ + SZ_QKV + SZ_G12);
        float* tok = (float*)(pool + 2 * SZ_AUG + 2 * SZ_WQ + SZ_QKV + SZ_G12 + SZ_TOK);
        ushort_t* W1b = (ushort_t*)W1p;
        ushort_t* W2b = (ushort_t*)W2p;
        const size_t SZ_P = (size_t)T_TOK * 1024 * 2;  // 4 MB
        ushort_t* Qh  = (ushort_t*)W1p;
        ushort_t* Ql  = (ushort_t*)(W1p + SZ_P);
        ushort_t* Kh  = (ushort_t*)(W1p + 2 * SZ_P);
        ushort_t* Kl  = (ushort_t*)(W1p + 3 * SZ_P);
        ushort_t* Vth = (ushort_t*)(W1p + 4 * SZ_P);
        ushort_t* Vtl = (ushort_t*)(W1p + 5 * SZ_P);
        ushort_t* CtxH = (ushort_t*)W2p;
        ushort_t* CtxL = (ushort_t*)(W2p + SZ_P);
        ushort_t* OWh  = (ushort_t*)(W2p + 2 * SZ_P);
        ushort_t* OWl  = (ushort_t*)(W2p + 2 * SZ_P + SZ_P / 2);
        // ---- MoE-phase overlay (lifetimes disjoint, stream-ordered) ----
        const size_t SZ_W12G = (size_t)8192 * KAUG * 2;            // 150,994,944
        const size_t SZ_G12G = (size_t)MROWS * 2048 * 2;           //  18,874,368
        const size_t SZ_GG   = (size_t)MROWS * KAUG * 2;           //  84,934,656
        ushort_t* A2   = (ushort_t*)pool;                          // [0, 37.7M)
        ushort_t* W12g = (ushort_t*)(pool + SZ_AUG);               // [37.7, 188.7M)
        ushort_t* g12g = (ushort_t*)(pool + SZ_AUG + SZ_W12G);     // [188.7, 207.6M)
        char* route    = pool + SZ_AUG + SZ_W12G + SZ_G12G;        // ~70 KB
        int2*   sel  = (int2*)route;                               // 16 KB
        float2* selw = (float2*)(route + 16384);                   // 16 KB
        int*    rmap = (int*)(route + 32768);                      // 18,432 B
        float*  rwgt = (float*)(route + 51200);                    // 18,432 B
        int*    cnts = (int*)(route + 69632);                      // [0..3]
        int*    fill = cnts + 4;
        int*    roff = cnts + 8;                                   // [0..4]
        int*    eblk = cnts + 16;                                  // [0..35]
        ushort_t* Gg  = (ushort_t*)pool;                           // [0, 84.9M)
        ushort_t* W3a = (ushort_t*)(pool + SZ_GG);                 // [84.9, 160.4M)

        // --- attention branch: split-bf16 everywhere upstream of the gate ---
        rmsnorm_kernel<<<T_TOK, 256, 0, stream>>>(x, norm1_w, tok);
        pack_act<<<(T_TOK * 1024) / 256, 256, 0, stream>>>(tok, A_hi, A_lo);
        pack_w<<<(3072 * 1024) / 256, 256, 0, stream>>>(qkv_base, qkv_spline, qkv_scaler,
                                                        W1b, W2b, (long)3072 * 1024);
        hipMemsetAsync(qkv, 0, SZ_QKV, stream);
        mfma_gemm2<128, 1, 5, 4><<<dim3(3072 / 128, T_TOK / 128, 4), 256, 0, stream>>>(
            A_hi, A_lo, W1b, W2b, qkv, nullptr, nullptr, nullptr, 3072, KAUG);
        qk_pack<<<(T_TOK * NHEAD * 32) / 256, 256, 0, stream>>>(qkv, rot_cos, rot_sin,
                                                                Qh, Ql, Kh, Kl);
        v_trans<<<dim3(S_SEQ / 64, NHEAD, 2), 256, 0, stream>>>(qkv, Vth, Vtl);
        attn_mfma<<<dim3(S_SEQ / 64, NHEAD, 2), 256, 0, stream>>>(Qh, Ql, Kh, Kl,
                                                                  Vth, Vtl, ctx);
        split_pack<<<(T_TOK * 1024) / 256, 256, 0, stream>>>(ctx, CtxH, CtxL,
                                                             (long)T_TOK * 1024);
        split_pack<<<(1024 * 1024) / 256, 256, 0, stream>>>(out_w, OWh, OWl,
                                                            (long)1024 * 1024);
        prefill_out<<<(T_TOK * H_DIM / 4) / 256, 256, 0, stream>>>(x, out_b, out);
        mfma_gemm2<128, 1, 5, 4><<<dim3(1024 / 128, T_TOK / 128, 4), 256, 0, stream>>>(
            CtxH, CtxL, OWh, OWl, out, nullptr, nullptr, nullptr, 1024, 1024);
        rmsnorm_kernel<<<T_TOK, 256, 0, stream>>>(out, norm2_w, tok);

        // --- gate + routing (top-2, exact) ---
        hipMemsetAsync(route + 32768, 0, 36864, stream);      // rmap, rwgt = 0
        hipMemsetAsync(cnts, 0, 256, stream);                 // cnts/fill/off/eblk
        gate_route<<<T_TOK, 256, 0, stream>>>(tok, gate_w, sel, selw, cnts);
        route_offsets<<<1, 64, 0, stream>>>(cnts, fill, roff, eblk);
        route_scatter<<<T_TOK / 256, 256, 0, stream>>>(sel, selw, fill, rmap, rwgt);

        // --- MoE: grouped top-2, plain bf16 (downstream of gate) ---
        pack_act<<<(T_TOK * 1024) / 256, 256, 0, stream>>>(tok, A2, nullptr);
        pack_w_g<<<(4 * 1024 * 1024) / 256, 256, 0, stream>>>(
            w1_base, w1_spline, w1_scaler, W12g, 0);
        pack_w_g<<<(4 * 1024 * 1024) / 256, 256, 0, stream>>>(
            w2_base, w2_spline, w2_scaler, W12g, 1024);
        // grouped w1w2: M=4608 gathered rows, N=2048 per-expert cols
        mfma_gemm2<128, 0, 7, 1><<<dim3(2048 / 128, NRB), 256, 0, stream>>>(
            A2, nullptr, W12g, nullptr, (float*)g12g, rmap, eblk, nullptr, 2048, KAUG);
        // G rows = augment(g1*g2) on permuted rows (overwrites A2/W12g head - dead)
        mul_pack_g<<<(MROWS * 1024) / 256, 256, 0, stream>>>(g12g, Gg);
        // w3 pack (overwrites W12g middle - dead)
        pack_w<<<(4 * 1024 * 1024) / 256, 256, 0, stream>>>(
            w3_base, w3_spline, w3_scaler, W3a, nullptr, (long)4 * 1024 * 1024);
        // grouped w3 split-K2: out[map[row]] += wgt[row] * (G row @ W3_e^T)
        mfma_gemm2<128, 0, 8, 2><<<dim3(1024 / 128, NRB, 2), 256, 0, stream>>>(
            Gg, nullptr, W3a, nullptr, out, rmap, eblk, rwgt, 1024, KAUG);
        return;
    }

    // ---- fallback: fp32 path ----
    char* ws = (char*)d_ws;
    float* hn  = (float*)ws; ws += (size_t)T_TOK * H_DIM * 4;
    float* qkv = (float*)ws; ws += (size_t)T_TOK * 3072 * 4;
    float* ctx = (float*)ws; ws += (size_t)T_TOK * H_DIM * 4;
    float* h2  = (float*)ws; ws += (size_t)T_TOK * H_DIM * 4;
    float* gw  = (float*)ws; ws += (size_t)T_TOK * E_EXP * 4;
    float* g1  = (float*)ws; ws += (size_t)T_TOK * DFF_ * 4;
    float* g2  = (float*)ws; ws += (size_t)T_TOK * DFF_ * 4;
    float* gm  = (float*)ws; ws += (size_t)T_TOK * DFF_ * 4;

    rmsnorm_kernel<<<T_TOK, 256, 0, stream>>>(x, norm1_w, hn);
    dim3 gq(3072 / 64, T_TOK / 64);
    kan_gemm<<<gq, 256, 0, stream>>>(hn, qkv_base, qkv_spline, qkv_scaler, qkv,
                                     nullptr, 0, 3072, 0);
    rope_kernel<<<(T_TOK * NHEAD * 32) / 256, 256, 0, stream>>>(qkv, rot_cos, rot_sin);
    dim3 ga(S_SEQ / 32, NHEAD, 2);
    attn_kernel<<<ga, 256, 0, stream>>>(qkv, ctx);
    dim3 go(1024 / 64, T_TOK / 64);
    gemm_bias_res<<<go, 256, 0, stream>>>(ctx, out_w, out_b, x, out);
    rmsnorm_kernel<<<T_TOK, 256, 0, stream>>>(out, norm2_w, h2);
    gate_kernel<<<T_TOK, 256, 0, stream>>>(h2, gate_w, gw);
    dim3 ge(1024 / 64, T_TOK / 64);
    for (int e = 0; e < E_EXP; ++e) {
        long wo = (long)e * DFF_ * H_DIM;
        kan_gemm<<<ge, 256, 0, stream>>>(h2, w1_base + wo, w1_spline + wo * 8,
                                         w1_scaler + wo, g1, nullptr, 0, DFF_, 0);
        kan_gemm<<<ge, 256, 0, stream>>>(h2, w2_base + wo, w2_spline + wo * 8,
                                         w2_scaler + wo, g2, nullptr, 0, DFF_, 0);
        mul_kernel<<<(T_TOK * DFF_) / 256, 256, 0, stream>>>(g1, g2, gm, T_TOK * DFF_);
        kan_gemm<<<ge, 256, 0, stream>>>(gm, w3_base + wo, w3_spline + wo * 8,
                                         w3_scaler + wo, out, gw + e, E_EXP, H_DIM, 1);
    }
}

// Round 7
// 1291.129 us; speedup vs baseline: 9.3464x; 1.0073x over previous
//
#include <hip/hip_runtime.h>
#include <hip/hip_bf16.h>

// KANBlock: B=2,S=1024,H=1024,NH=16,HD=64,DFF=1024,E=4,TOPK=2, NB=8 spline bases
#define T_TOK 2048
#define H_DIM 1024
#define S_SEQ 1024
#define NHEAD 16
#define E_EXP 4
#define DFF_  1024
#define KAUG  9216   // 9*1024 augmented K (k = c*1024 + i; c=0 silu, c=1..8 splines)
#define MROWS 4608   // 2*T + 4*127 padded, rounded to 36*128
#define NRB   36     // row blocks of 128

typedef __bf16 bf16x8 __attribute__((ext_vector_type(8)));
typedef float  f32x4  __attribute__((ext_vector_type(4)));
typedef unsigned short ushort_t;

__device__ __forceinline__ float sigmoidf_(float x) { return 1.0f / (1.0f + __expf(-x)); }

__device__ __forceinline__ unsigned short f2bf(float f) {   // RNE f32 -> bf16 bits
    unsigned int u = __float_as_uint(f);
    u = (u + 0x7fffu + ((u >> 16) & 1u)) >> 16;
    return (unsigned short)u;
}
__device__ __forceinline__ float bf2f(unsigned short h) {
    return __uint_as_float(((unsigned int)h) << 16);
}

// Cubic B-spline bases, matches reference b_splines() (verified round 0)
__device__ __forceinline__ void bspline8(float x, float* o) {
    float b[11];
#pragma unroll
    for (int m = 0; m < 11; ++m) {
        float g0 = 0.4f * (float)(m - 3) - 1.0f;
        float g1 = 0.4f * (float)(m - 2) - 1.0f;
        b[m] = (x >= g0 && x < g1) ? 1.0f : 0.0f;
    }
#pragma unroll
    for (int j = 1; j <= 3; ++j) {
        float inv = 1.0f / (0.4f * (float)j);
#pragma unroll
        for (int m = 0; m + j < 11; ++m) {
            float gm   = 0.4f * (float)(m - 3) - 1.0f;
            float gmj1 = 0.4f * (float)(m + j - 2) - 1.0f;
            b[m] = ((x - gm) * b[m] + (gmj1 - x) * b[m + 1]) * inv;
        }
    }
#pragma unroll
    for (int c = 0; c < 8; ++c) o[c] = b[c];
}

// ---------------- RMSNorm
__global__ __launch_bounds__(256) void rmsnorm_kernel(const float* __restrict__ x,
                                                      const float* __restrict__ w,
                                                      float* __restrict__ out) {
    long t = blockIdx.x;
    float4 v = ((const float4*)(x + t * H_DIM))[threadIdx.x];
    float ss = v.x * v.x + v.y * v.y + v.z * v.z + v.w * v.w;
#pragma unroll
    for (int m = 1; m < 64; m <<= 1) ss += __shfl_xor(ss, m, 64);
    __shared__ float wsum[4];
    if ((threadIdx.x & 63) == 0) wsum[threadIdx.x >> 6] = ss;
    __syncthreads();
    ss = wsum[0] + wsum[1] + wsum[2] + wsum[3];
    float sc = rsqrtf(ss * (1.0f / (float)H_DIM) + 1e-6f);
    float4 wv = ((const float4*)w)[threadIdx.x];
    float4 r;
    r.x = v.x * sc * wv.x; r.y = v.y * sc * wv.y;
    r.z = v.z * sc * wv.z; r.w = v.w * sc * wv.w;
    ((float4*)(out + t * H_DIM))[threadIdx.x] = r;
}

// ---------------- out prefill: out = x + bias
__global__ __launch_bounds__(256) void prefill_out(const float* __restrict__ x,
                                                   const float* __restrict__ bias,
                                                   float* __restrict__ out) {
    long i = (long)blockIdx.x * 256 + threadIdx.x;   // T*H/4
    float4 xv = ((const float4*)x)[i];
    float4 bv = ((const float4*)bias)[i & 255];
    float4 r;
    r.x = xv.x + bv.x; r.y = xv.y + bv.y; r.z = xv.z + bv.z; r.w = xv.w + bv.w;
    ((float4*)out)[i] = r;
}

// ---------------- pack activations -> augmented bf16 (hi, optional lo)
__global__ __launch_bounds__(256) void pack_act(const float* __restrict__ act,
                                                ushort_t* __restrict__ hi,
                                                ushort_t* __restrict__ lo) {
    long idx = (long)blockIdx.x * 256 + threadIdx.x;
    long m = idx >> 10; int i = (int)(idx & 1023);
    float v = act[idx];
    float ch[9];
    ch[0] = v * sigmoidf_(v);
    bspline8(v, ch + 1);
    ushort_t* oh = hi + m * (long)KAUG + i;
#pragma unroll
    for (int c = 0; c < 9; ++c) oh[(long)c * 1024] = f2bf(ch[c]);
    if (lo) {
        ushort_t* ol = lo + m * (long)KAUG + i;
#pragma unroll
        for (int c = 0; c < 9; ++c) {
            unsigned short h = f2bf(ch[c]);
            ol[(long)c * 1024] = f2bf(ch[c] - bf2f(h));
        }
    }
}

// ---------------- pack weights -> augmented bf16: [base | spline*scaler]
__global__ __launch_bounds__(256) void pack_w(const float* __restrict__ base,
                                              const float* __restrict__ spl,
                                              const float* __restrict__ scal,
                                              ushort_t* __restrict__ hi,
                                              ushort_t* __restrict__ lo,
                                              long total) {
    long idx = (long)blockIdx.x * 256 + threadIdx.x;
    if (idx >= total) return;
    long n = idx >> 10; int i = (int)(idx & 1023);
    float sc = scal[idx];
    const float4* s4 = (const float4*)(spl + idx * 8);
    float4 s0 = s4[0], s1 = s4[1];
    float ch[9] = {base[idx], s0.x * sc, s0.y * sc, s0.z * sc, s0.w * sc,
                   s1.x * sc, s1.y * sc, s1.z * sc, s1.w * sc};
    ushort_t* oh = hi + n * (long)KAUG + i;
#pragma unroll
    for (int c = 0; c < 9; ++c) oh[(long)c * 1024] = f2bf(ch[c]);
    if (lo) {
        ushort_t* ol = lo + n * (long)KAUG + i;
#pragma unroll
        for (int c = 0; c < 9; ++c) {
            unsigned short h = f2bf(ch[c]);
            ol[(long)c * 1024] = f2bf(ch[c] - bf2f(h));
        }
    }
}

// ---------------- grouped weight pack: expert-major [e][w1|w2] rows of 2048
// input row n = e*1024 + d ; output row = e*2048 + grpOff + d
__global__ __launch_bounds__(256) void pack_w_g(const float* __restrict__ base,
                                                const float* __restrict__ spl,
                                                const float* __restrict__ scal,
                                                ushort_t* __restrict__ hi,
                                                int grpOff) {
    long idx = (long)blockIdx.x * 256 + threadIdx.x;   // 4M exact
    long n = idx >> 10; int i = (int)(idx & 1023);
    long e = n >> 10, d = n & 1023;
    float sc = scal[idx];
    const float4* s4 = (const float4*)(spl + idx * 8);
    float4 s0 = s4[0], s1 = s4[1];
    float ch[9] = {base[idx], s0.x * sc, s0.y * sc, s0.z * sc, s0.w * sc,
                   s1.x * sc, s1.y * sc, s1.z * sc, s1.w * sc};
    ushort_t* oh = hi + (e * 2048 + grpOff + d) * (long)KAUG + i;
#pragma unroll
    for (int c = 0; c < 9; ++c) oh[(long)c * 1024] = f2bf(ch[c]);
}

// ---------------- grouped: v = g1*g2 (bf16, row-local) -> augmented bf16 G rows
__global__ __launch_bounds__(256) void mul_pack_g(const ushort_t* __restrict__ g12,
                                                  ushort_t* __restrict__ G) {
    long idx = (long)blockIdx.x * 256 + threadIdx.x;   // MROWS*1024
    long p = idx >> 10; int i = (int)(idx & 1023);
    float v = bf2f(g12[p * 2048 + i]) * bf2f(g12[p * 2048 + 1024 + i]);
    float ch[9];
    ch[0] = v * sigmoidf_(v);
    bspline8(v, ch + 1);
    ushort_t* oh = G + p * (long)KAUG + i;
#pragma unroll
    for (int c = 0; c < 9; ++c) oh[(long)c * 1024] = f2bf(ch[c]);
}

// ---------------- elementwise f32 -> bf16 hi/lo split
__global__ __launch_bounds__(256) void split_pack(const float* __restrict__ in,
                                                  ushort_t* __restrict__ hi,
                                                  ushort_t* __restrict__ lo, long n) {
    long i = (long)blockIdx.x * 256 + threadIdx.x;
    if (i >= n) return;
    float v = in[i];
    unsigned short h = f2bf(v);
    hi[i] = h;
    lo[i] = f2bf(v - bf2f(h));
}

// =====================================================================
// MFMA GEMM (m97 structure): C(M,N) = A(M,K) @ B(N,K)^T, bf16 ops fp32 acc.
// BM x 128 tile, BK=32, 4 waves (2x2). 2-bit XOR chunk swizzle on LDS
// (pre-swizzled global source). SPLIT: 3-pass hi/lo (fp32-class).
// MODE 0: C = acc (fp32)
// MODE 5: splitK (z=kk): atomicAdd C += acc  (C pre-zeroed/prefilled)
// MODE 6: C bf16 = acc
// MODE 7: grouped-MoE w1w2: e=eblk[by]; A row gathered via rmap; B+=e*2048*K;
//         C bf16 (N=2048)
// MODE 8: grouped-MoE w3 (z=kk): e=eblk[by]; B+=e*1024*K;
//         atomicAdd out[rmap[row]*N+col] += rwgt[row]*acc
// =====================================================================
#define GLD(gp, lp) __builtin_amdgcn_global_load_lds( \
    (const __attribute__((address_space(1))) void*)(gp), \
    (__attribute__((address_space(3))) void*)(lp), 16, 0, 0)

template<int BM, int SPLIT, int MODE, int KSPLIT>
__global__ __launch_bounds__(256) void mfma_gemm2(const ushort_t* __restrict__ Ah,
                                                  const ushort_t* __restrict__ Al,
                                                  const ushort_t* __restrict__ Bh,
                                                  const ushort_t* __restrict__ Bl,
                                                  float* __restrict__ C,
                                                  const int* __restrict__ rmap,
                                                  const int* __restrict__ eblk,
                                                  const float* __restrict__ rwgt,
                                                  int N, int K) {
    constexpr int NM = BM / 32;            // A fragments per wave
    __shared__ __align__(16) ushort_t AsH[BM * 32];
    __shared__ __align__(16) ushort_t BsH[128 * 32];
    __shared__ __align__(16) ushort_t AsL[SPLIT ? BM * 32 : 16];
    __shared__ __align__(16) ushort_t BsL[SPLIT ? 128 * 32 : 16];
    const int bm = blockIdx.y * BM, bn = blockIdx.x * 128;

    const int KC = K / KSPLIT;
    int kk = (KSPLIT > 1) ? blockIdx.z : 0;
    int e = 0;
    if constexpr (MODE == 7 || MODE == 8) e = eblk[blockIdx.y];
    const ushort_t* Ap = Ah + (size_t)kk * KC;
    const ushort_t* Bp = Bh + (size_t)kk * KC
                            + (MODE == 7 ? (size_t)e * 2048 * (size_t)K : 0)
                            + (MODE == 8 ? (size_t)e * 1024 * (size_t)K : 0);
    const ushort_t* Alp = SPLIT ? Al + (size_t)kk * KC : nullptr;
    const ushort_t* Blp = SPLIT ? Bl + (size_t)kk * KC : nullptr;

    const int tid = threadIdx.x;
    const int w = tid >> 6, l = tid & 63;
    const int wr = w >> 1, wc = w & 1;
    const int half = l >> 4, lr = l & 15;
    const size_t rb = (size_t)K * 2;       // full row bytes

    const int rowB0 = w * 32 + (l >> 2), rowB1 = rowB0 + 16;
    const int cch = l & 3;
    const char* gB0 = (const char*)Bp + (size_t)(bn + rowB0) * rb + ((cch ^ (rowB0 & 3)) * 16);
    const char* gB1 = (const char*)Bp + (size_t)(bn + rowB1) * rb + ((cch ^ (rowB1 & 3)) * 16);
    const char* gB0l = SPLIT ? (const char*)Blp + (size_t)(bn + rowB0) * rb + ((cch ^ (rowB0 & 3)) * 16) : nullptr;
    const char* gB1l = SPLIT ? (const char*)Blp + (size_t)(bn + rowB1) * rb + ((cch ^ (rowB1 & 3)) * 16) : nullptr;
    int rowA0, rowA1;
    if constexpr (BM == 128) { rowA0 = w * 32 + (l >> 2); rowA1 = rowA0 + 16; }
    else                     { rowA0 = w * 16 + (l >> 2); rowA1 = 0; }
    size_t arow0, arow1 = 0;
    if constexpr (MODE == 7) {
        arow0 = (size_t)rmap[bm + rowA0];
        if (BM == 128) arow1 = (size_t)rmap[bm + rowA1];
    } else {
        arow0 = (size_t)(bm + rowA0);
        if (BM == 128) arow1 = (size_t)(bm + rowA1);
    }
    const char* gA0 = (const char*)Ap + arow0 * rb + ((cch ^ (rowA0 & 3)) * 16);
    const char* gA1 = (BM == 128) ? (const char*)Ap + arow1 * rb + ((cch ^ (rowA1 & 3)) * 16) : nullptr;
    const char* gA0l = SPLIT ? (const char*)Alp + arow0 * rb + ((cch ^ (rowA0 & 3)) * 16) : nullptr;
    const char* gA1l = (SPLIT && BM == 128) ? (const char*)Alp + arow1 * rb + ((cch ^ (rowA1 & 3)) * 16) : nullptr;

    f32x4 acc[NM][4] = {};
    for (int k0 = 0; k0 < KC; k0 += 32) {
        const size_t kb = (size_t)k0 * 2;
        GLD(gA0 + kb, (char*)AsH + ((BM == 128) ? w * 2048 : w * 1024) + l * 16);
        if constexpr (BM == 128) GLD(gA1 + kb, (char*)AsH + w * 2048 + 1024 + l * 16);
        GLD(gB0 + kb, (char*)BsH + w * 2048 + l * 16);
        GLD(gB1 + kb, (char*)BsH + w * 2048 + 1024 + l * 16);
        if constexpr (SPLIT) {
            GLD(gA0l + kb, (char*)AsL + ((BM == 128) ? w * 2048 : w * 1024) + l * 16);
            if constexpr (BM == 128) GLD(gA1l + kb, (char*)AsL + w * 2048 + 1024 + l * 16);
            GLD(gB0l + kb, (char*)BsL + w * 2048 + l * 16);
            GLD(gB1l + kb, (char*)BsL + w * 2048 + 1024 + l * 16);
        }
        __syncthreads();
        bf16x8 ah[NM], bh[4];
#pragma unroll
        for (int mi = 0; mi < NM; ++mi) {
            int r = wr * (BM / 2) + mi * 16 + lr;
            ah[mi] = *(const bf16x8*)((const char*)AsH + r * 64 + ((half ^ (r & 3)) * 16));
        }
#pragma unroll
        for (int ni = 0; ni < 4; ++ni) {
            int r = wc * 64 + ni * 16 + lr;
            bh[ni] = *(const bf16x8*)((const char*)BsH + r * 64 + ((half ^ (r & 3)) * 16));
        }
#pragma unroll
        for (int mi = 0; mi < NM; ++mi)
#pragma unroll
            for (int ni = 0; ni < 4; ++ni)
                acc[mi][ni] = __builtin_amdgcn_mfma_f32_16x16x32_bf16(ah[mi], bh[ni],
                                                                      acc[mi][ni], 0, 0, 0);
        if constexpr (SPLIT) {
            bf16x8 al[NM], bl[4];
#pragma unroll
            for (int mi = 0; mi < NM; ++mi) {
                int r = wr * (BM / 2) + mi * 16 + lr;
                al[mi] = *(const bf16x8*)((const char*)AsL + r * 64 + ((half ^ (r & 3)) * 16));
            }
#pragma unroll
            for (int ni = 0; ni < 4; ++ni) {
                int r = wc * 64 + ni * 16 + lr;
                bl[ni] = *(const bf16x8*)((const char*)BsL + r * 64 + ((half ^ (r & 3)) * 16));
            }
#pragma unroll
            for (int mi = 0; mi < NM; ++mi)
#pragma unroll
                for (int ni = 0; ni < 4; ++ni) {
                    acc[mi][ni] = __builtin_amdgcn_mfma_f32_16x16x32_bf16(ah[mi], bl[ni],
                                                                          acc[mi][ni], 0, 0, 0);
                    acc[mi][ni] = __builtin_amdgcn_mfma_f32_16x16x32_bf16(al[mi], bh[ni],
                                                                          acc[mi][ni], 0, 0, 0);
                }
        }
        __syncthreads();
    }
    // epilogue: C/D layout col=lane&15, row=(lane>>4)*4+reg
#pragma unroll
    for (int mi = 0; mi < NM; ++mi)
#pragma unroll
        for (int r = 0; r < 4; ++r) {
            int row = bm + wr * (BM / 2) + mi * 16 + half * 4 + r;
            int token = 0; float wv = 0.0f;
            if constexpr (MODE == 8) { token = rmap[row]; wv = rwgt[row]; }
#pragma unroll
            for (int ni = 0; ni < 4; ++ni) {
                int col = bn + wc * 64 + ni * 16 + lr;
                size_t ix = (size_t)row * N + col;
                if constexpr (MODE == 0)      C[ix] = acc[mi][ni][r];
                else if constexpr (MODE == 5) unsafeAtomicAdd(&C[ix], acc[mi][ni][r]);
                else if constexpr (MODE == 8)
                    unsafeAtomicAdd(&C[(size_t)token * N + col], wv * acc[mi][ni][r]);
                else                          ((ushort_t*)C)[ix] = f2bf(acc[mi][ni][r]);
            }
        }
}

// ---------------- fused rope + split-bf16 pack of q,k (q pre-scaled by 1/8)
__global__ __launch_bounds__(256) void qk_pack(const float* __restrict__ qkv,
                                               const float* __restrict__ cs,
                                               const float* __restrict__ sn,
                                               ushort_t* __restrict__ Qh, ushort_t* __restrict__ Ql,
                                               ushort_t* __restrict__ Kh, ushort_t* __restrict__ Kl) {
    int idx = blockIdx.x * 256 + threadIdx.x;   // B*S*NH*32 = 1M
    int p = idx & 31;
    int h = (idx >> 5) & 15;
    int s = (idx >> 9) & (S_SEQ - 1);
    int b = idx >> 19;
    float c = cs[s * 32 + p], si = sn[s * 32 + p];
    long base = ((long)(b * S_SEQ + s)) * 3072 + h * 192;
    long dst = (((long)(b * NHEAD + h)) * S_SEQ + s) * 64 + 2 * p;
    float re = qkv[base + 2 * p], im = qkv[base + 2 * p + 1];
    float qre = (re * c - im * si) * 0.125f;
    float qim = (re * si + im * c) * 0.125f;
    unsigned short hh = f2bf(qre);
    Qh[dst] = hh; Ql[dst] = f2bf(qre - bf2f(hh));
    hh = f2bf(qim);
    Qh[dst + 1] = hh; Ql[dst + 1] = f2bf(qim - bf2f(hh));
    re = qkv[base + 64 + 2 * p]; im = qkv[base + 64 + 2 * p + 1];
    float kre = re * c - im * si;
    float kim = re * si + im * c;
    hh = f2bf(kre);
    Kh[dst] = hh; Kl[dst] = f2bf(kre - bf2f(hh));
    hh = f2bf(kim);
    Kh[dst + 1] = hh; Kl[dst + 1] = f2bf(kim - bf2f(hh));
}

// ---------------- V transpose + split: qkv v-part -> Vt [b][h][64 d][1024 s]
__global__ __launch_bounds__(256) void v_trans(const float* __restrict__ qkv,
                                               ushort_t* __restrict__ Vth,
                                               ushort_t* __restrict__ Vtl) {
    __shared__ float t[64][65];
    const int s0 = blockIdx.x * 64, h = blockIdx.y, b = blockIdx.z;
    const int tid = threadIdx.x;
#pragma unroll
    for (int i = 0; i < 16; ++i) {
        int e = tid + i * 256;
        int sl = e >> 6, d = e & 63;
        t[d][sl] = qkv[((long)(b * S_SEQ + s0 + sl)) * 3072 + h * 192 + 128 + d];
    }
    __syncthreads();
#pragma unroll
    for (int i = 0; i < 16; ++i) {
        int e = tid + i * 256;
        int d = e >> 6, sl = e & 63;
        float v = t[d][sl];
        long o = (((long)(b * NHEAD + h)) * 64 + d) * S_SEQ + s0 + sl;
        unsigned short hh = f2bf(v);
        Vth[o] = hh;
        Vtl[o] = f2bf(v - bf2f(hh));
    }
}

// =====================================================================
// MFMA flash attention, full hi/lo split (fp32-class accuracy).
// =====================================================================
__device__ __forceinline__ bf16x8 lds_frag(const ushort_t* base, int row, int chunk) {
    return *(const bf16x8*)((const char*)base + row * 128 + ((chunk ^ (row & 7)) * 16));
}

__global__ __launch_bounds__(256) void attn_mfma(const ushort_t* __restrict__ Qh,
                                                 const ushort_t* __restrict__ Ql,
                                                 const ushort_t* __restrict__ Kh,
                                                 const ushort_t* __restrict__ Kl,
                                                 const ushort_t* __restrict__ Vth,
                                                 const ushort_t* __restrict__ Vtl,
                                                 float* __restrict__ ctx) {
    __shared__ __align__(16) ushort_t KsH[64 * 64], KsL[64 * 64];
    __shared__ __align__(16) ushort_t VsH[64 * 64], VsL[64 * 64];
    __shared__ __align__(16) ushort_t Ps[4][2][16][72];
    const int qb = blockIdx.x * 64, h = blockIdx.y, b = blockIdx.z;
    const int tid = threadIdx.x;
    const int w = tid >> 6, l = tid & 63;
    const int lr = l & 15, g = l >> 4;
    const long bh = b * NHEAD + h;

    const long qoff = (bh * S_SEQ + qb + w * 16 + lr) * 64 + g * 8;
    bf16x8 qh0 = *(const bf16x8*)(Qh + qoff);
    bf16x8 qh1 = *(const bf16x8*)(Qh + qoff + 32);
    bf16x8 ql0 = *(const bf16x8*)(Ql + qoff);
    bf16x8 ql1 = *(const bf16x8*)(Ql + qoff + 32);

    const int rowS0 = w * 16 + (l >> 3), rowS1 = rowS0 + 8;
    const int cch = l & 7;
    const char* gK0 = (const char*)Kh + (bh * S_SEQ + rowS0) * 128 + ((cch ^ (rowS0 & 7)) * 16);
    const char* gK1 = (const char*)Kh + (bh * S_SEQ + rowS1) * 128 + ((cch ^ (rowS1 & 7)) * 16);
    const char* gKl0 = (const char*)Kl + (bh * S_SEQ + rowS0) * 128 + ((cch ^ (rowS0 & 7)) * 16);
    const char* gKl1 = (const char*)Kl + (bh * S_SEQ + rowS1) * 128 + ((cch ^ (rowS1 & 7)) * 16);
    const char* gV0 = (const char*)Vth + (bh * 64 + rowS0) * 2048 + ((cch ^ (rowS0 & 7)) * 16);
    const char* gV1 = (const char*)Vth + (bh * 64 + rowS1) * 2048 + ((cch ^ (rowS1 & 7)) * 16);
    const char* gVl0 = (const char*)Vtl + (bh * 64 + rowS0) * 2048 + ((cch ^ (rowS0 & 7)) * 16);
    const char* gVl1 = (const char*)Vtl + (bh * 64 + rowS1) * 2048 + ((cch ^ (rowS1 & 7)) * 16);

    float m_run[4] = {-1e30f, -1e30f, -1e30f, -1e30f};
    float l_run[4] = {0.f, 0.f, 0.f, 0.f};
    f32x4 acco[4] = {};

    for (int k0 = 0; k0 < S_SEQ; k0 += 64) {
        GLD(gK0 + (size_t)k0 * 128, (char*)KsH + w * 2048 + l * 16);
        GLD(gK1 + (size_t)k0 * 128, (char*)KsH + w * 2048 + 1024 + l * 16);
        GLD(gKl0 + (size_t)k0 * 128, (char*)KsL + w * 2048 + l * 16);
        GLD(gKl1 + (size_t)k0 * 128, (char*)KsL + w * 2048 + 1024 + l * 16);
        GLD(gV0 + (size_t)k0 * 2, (char*)VsH + w * 2048 + l * 16);
        GLD(gV1 + (size_t)k0 * 2, (char*)VsH + w * 2048 + 1024 + l * 16);
        GLD(gVl0 + (size_t)k0 * 2, (char*)VsL + w * 2048 + l * 16);
        GLD(gVl1 + (size_t)k0 * 2, (char*)VsL + w * 2048 + 1024 + l * 16);
        __syncthreads();

        f32x4 accs[4] = {};
#pragma unroll
        for (int n = 0; n < 4; ++n) {
            bf16x8 bkh0 = lds_frag(KsH, n * 16 + lr, g);
            bf16x8 bkh1 = lds_frag(KsH, n * 16 + lr, g + 4);
            bf16x8 bkl0 = lds_frag(KsL, n * 16 + lr, g);
            bf16x8 bkl1 = lds_frag(KsL, n * 16 + lr, g + 4);
            accs[n] = __builtin_amdgcn_mfma_f32_16x16x32_bf16(qh0, bkh0, accs[n], 0, 0, 0);
            accs[n] = __builtin_amdgcn_mfma_f32_16x16x32_bf16(qh1, bkh1, accs[n], 0, 0, 0);
            accs[n] = __builtin_amdgcn_mfma_f32_16x16x32_bf16(qh0, bkl0, accs[n], 0, 0, 0);
            accs[n] = __builtin_amdgcn_mfma_f32_16x16x32_bf16(qh1, bkl1, accs[n], 0, 0, 0);
            accs[n] = __builtin_amdgcn_mfma_f32_16x16x32_bf16(ql0, bkh0, accs[n], 0, 0, 0);
            accs[n] = __builtin_amdgcn_mfma_f32_16x16x32_bf16(ql1, bkh1, accs[n], 0, 0, 0);
        }
        float alpha[4];
#pragma unroll
        for (int r = 0; r < 4; ++r) {
            float mx = fmaxf(fmaxf(accs[0][r], accs[1][r]), fmaxf(accs[2][r], accs[3][r]));
#pragma unroll
            for (int msk = 1; msk < 16; msk <<= 1) mx = fmaxf(mx, __shfl_xor(mx, msk, 64));
            float m_new = fmaxf(m_run[r], mx);
            float ps = 0.f;
#pragma unroll
            for (int n = 0; n < 4; ++n) {
                float p = __expf(accs[n][r] - m_new);
                accs[n][r] = p;
                ps += p;
            }
#pragma unroll
            for (int msk = 1; msk < 16; msk <<= 1) ps += __shfl_xor(ps, msk, 64);
            alpha[r] = __expf(m_run[r] - m_new);
            l_run[r] = l_run[r] * alpha[r] + ps;
            m_run[r] = m_new;
        }
#pragma unroll
        for (int nd = 0; nd < 4; ++nd)
#pragma unroll
            for (int r = 0; r < 4; ++r) acco[nd][r] *= alpha[r];
#pragma unroll
        for (int n = 0; n < 4; ++n)
#pragma unroll
            for (int r = 0; r < 4; ++r) {
                float p = accs[n][r];
                unsigned short hh = f2bf(p);
                Ps[w][0][g * 4 + r][n * 16 + lr] = hh;
                Ps[w][1][g * 4 + r][n * 16 + lr] = f2bf(p - bf2f(hh));
            }
        __syncthreads();
        bf16x8 pah0 = *(const bf16x8*)&Ps[w][0][lr][g * 8];
        bf16x8 pah1 = *(const bf16x8*)&Ps[w][0][lr][32 + g * 8];
        bf16x8 pal0 = *(const bf16x8*)&Ps[w][1][lr][g * 8];
        bf16x8 pal1 = *(const bf16x8*)&Ps[w][1][lr][32 + g * 8];
#pragma unroll
        for (int nd = 0; nd < 4; ++nd) {
            bf16x8 bvh0 = lds_frag(VsH, nd * 16 + lr, g);
            bf16x8 bvh1 = lds_frag(VsH, nd * 16 + lr, g + 4);
            bf16x8 bvl0 = lds_frag(VsL, nd * 16 + lr, g);
            bf16x8 bvl1 = lds_frag(VsL, nd * 16 + lr, g + 4);
            acco[nd] = __builtin_amdgcn_mfma_f32_16x16x32_bf16(pah0, bvh0, acco[nd], 0, 0, 0);
            acco[nd] = __builtin_amdgcn_mfma_f32_16x16x32_bf16(pah1, bvh1, acco[nd], 0, 0, 0);
            acco[nd] = __builtin_amdgcn_mfma_f32_16x16x32_bf16(pah0, bvl0, acco[nd], 0, 0, 0);
            acco[nd] = __builtin_amdgcn_mfma_f32_16x16x32_bf16(pah1, bvl1, acco[nd], 0, 0, 0);
            acco[nd] = __builtin_amdgcn_mfma_f32_16x16x32_bf16(pal0, bvh0, acco[nd], 0, 0, 0);
            acco[nd] = __builtin_amdgcn_mfma_f32_16x16x32_bf16(pal1, bvh1, acco[nd], 0, 0, 0);
        }
        __syncthreads();
    }
#pragma unroll
    for (int r = 0; r < 4; ++r) {
        float inv = 1.0f / l_run[r];
        long row = (long)b * S_SEQ + qb + w * 16 + g * 4 + r;
#pragma unroll
        for (int nd = 0; nd < 4; ++nd)
            ctx[row * H_DIM + h * 64 + nd * 16 + lr] = acco[nd][r] * inv;
    }
}

// ---------------- gate + route: top-2 sel/weights + per-expert counts
__global__ __launch_bounds__(256) void gate_route(const float* __restrict__ h2,
                                                  const float* __restrict__ gate_w,
                                                  int2* __restrict__ sel,
                                                  float2* __restrict__ selw,
                                                  int* __restrict__ cnts) {
    long t = blockIdx.x;
    float sum[4] = {0, 0, 0, 0};
    for (int i = threadIdx.x; i < H_DIM; i += 256) {
        float v = h2[t * H_DIM + i];
#pragma unroll
        for (int e = 0; e < 4; ++e) sum[e] = fmaf(v, gate_w[e * H_DIM + i], sum[e]);
    }
#pragma unroll
    for (int w = 1; w < 64; w <<= 1)
#pragma unroll
        for (int e = 0; e < 4; ++e) sum[e] += __shfl_xor(sum[e], w, 64);
    __shared__ float part[4][4];
    if ((threadIdx.x & 63) == 0)
#pragma unroll
        for (int e = 0; e < 4; ++e) part[e][threadIdx.x >> 6] = sum[e];
    __syncthreads();
    if (threadIdx.x == 0) {
        float lg[4];
#pragma unroll
        for (int e = 0; e < 4; ++e) lg[e] = part[e][0] + part[e][1] + part[e][2] + part[e][3];
        int i0 = 0;
        for (int e = 1; e < 4; ++e) if (lg[e] > lg[i0]) i0 = e;   // ties -> lower idx
        int i1 = -1;
        for (int e = 0; e < 4; ++e) if (e != i0 && (i1 < 0 || lg[e] > lg[i1])) i1 = e;
        float mx = fmaxf(lg[i0], lg[i1]);
        float e0 = __expf(lg[i0] - mx), e1 = __expf(lg[i1] - mx);
        float inv = 1.0f / (e0 + e1);
        sel[t] = make_int2(i0, i1);
        selw[t] = make_float2(e0 * inv, e1 * inv);
        atomicAdd(&cnts[i0], 1);
        atomicAdd(&cnts[i1], 1);
    }
}

// ---------------- route offsets (single block): 128-aligned segments + eblk
__global__ void route_offsets(const int* __restrict__ cnts, int* __restrict__ fill,
                              int* __restrict__ off, int* __restrict__ eblk) {
    if (threadIdx.x != 0) return;
    int o = 0;
    for (int e = 0; e < 4; ++e) {
        off[e] = o;
        fill[e] = o;
        o += ((cnts[e] + 127) >> 7) << 7;
    }
    off[4] = o;
    for (int rb = 0; rb < NRB; ++rb) {
        int rs = rb * 128, e = 0;
        for (int q = 0; q < 4; ++q)
            if (rs >= off[q] && rs < off[q + 1]) e = q;
        eblk[rb] = e;
    }
}

// ---------------- route scatter: token -> permuted row slots
__global__ __launch_bounds__(256) void route_scatter(const int2* __restrict__ sel,
                                                     const float2* __restrict__ selw,
                                                     int* __restrict__ fill,
                                                     int* __restrict__ map,
                                                     float* __restrict__ wgt) {
    int t = blockIdx.x * 256 + threadIdx.x;
    if (t >= T_TOK) return;
    int2 s = sel[t]; float2 w = selw[t];
    int p0 = atomicAdd(&fill[s.x], 1); map[p0] = t; wgt[p0] = w.x;
    int p1 = atomicAdd(&fill[s.y], 1); map[p1] = t; wgt[p1] = w.y;
}

// ================= fallback-only kernels (round-0 fp32 path) =================
#define KI 8
#define BKK 72
__global__ __launch_bounds__(256) void kan_gemm(const float* __restrict__ Act,
                                                const float* __restrict__ baseW,
                                                const float* __restrict__ splW,
                                                const float* __restrict__ scal,
                                                float* __restrict__ C,
                                                const float* __restrict__ rowScale,
                                                int rsStride, int N, int mode) {
    __shared__ float As[BKK][64];
    __shared__ float Bs[BKK][64];
    const int bm = blockIdx.y * 64;
    const int bn = blockIdx.x * 64;
    const int tid = threadIdx.x;
    const int tx = tid & 15, ty = tid >> 4;
    float acc[4][4] = {};
    for (int i0 = 0; i0 < H_DIM; i0 += KI) {
        for (int e = tid; e < 64 * KI; e += 256) {
            int m = e >> 3, ii = e & 7;
            float xv = Act[(long)(bm + m) * H_DIM + i0 + ii];
            float sp[8];
            bspline8(xv, sp);
            As[ii * 9][m] = xv * sigmoidf_(xv);
#pragma unroll
            for (int c = 0; c < 8; ++c) As[ii * 9 + 1 + c][m] = sp[c];
        }
        for (int e = tid; e < 64 * KI; e += 256) {
            int n = e >> 3, ii = e & 7;
            long w = (long)(bn + n) * H_DIM + i0 + ii;
            float sc = scal[w];
            Bs[ii * 9][n] = baseW[w];
            const float4* sp4 = (const float4*)(splW + w * 8);
            float4 s0 = sp4[0], s1 = sp4[1];
            Bs[ii * 9 + 1][n] = s0.x * sc; Bs[ii * 9 + 2][n] = s0.y * sc;
            Bs[ii * 9 + 3][n] = s0.z * sc; Bs[ii * 9 + 4][n] = s0.w * sc;
            Bs[ii * 9 + 5][n] = s1.x * sc; Bs[ii * 9 + 6][n] = s1.y * sc;
            Bs[ii * 9 + 7][n] = s1.z * sc; Bs[ii * 9 + 8][n] = s1.w * sc;
        }
        __syncthreads();
#pragma unroll 8
        for (int k = 0; k < BKK; ++k) {
            float4 a = *(const float4*)&As[k][ty * 4];
            float4 b = *(const float4*)&Bs[k][tx * 4];
            float av[4] = {a.x, a.y, a.z, a.w};
            float bv[4] = {b.x, b.y, b.z, b.w};
#pragma unroll
            for (int i = 0; i < 4; ++i)
#pragma unroll
                for (int j = 0; j < 4; ++j) acc[i][j] = fmaf(av[i], bv[j], acc[i][j]);
        }
        __syncthreads();
    }
#pragma unroll
    for (int i = 0; i < 4; ++i) {
        long m = bm + ty * 4 + i;
        float rs = (mode == 1) ? rowScale[m * rsStride] : 0.0f;
#pragma unroll
        for (int j = 0; j < 4; ++j) {
            long idx = m * (long)N + bn + tx * 4 + j;
            if (mode == 0) C[idx] = acc[i][j];
            else           C[idx] += rs * acc[i][j];
        }
    }
}

__global__ __launch_bounds__(256) void gemm_bias_res(const float* __restrict__ A,
                                                     const float* __restrict__ Bw,
                                                     const float* __restrict__ bias,
                                                     const float* __restrict__ res,
                                                     float* __restrict__ C) {
    __shared__ float As[16][64];
    __shared__ float Bs[16][64];
    const int bm = blockIdx.y * 64, bn = blockIdx.x * 64;
    const int tid = threadIdx.x;
    const int tx = tid & 15, ty = tid >> 4;
    float acc[4][4] = {};
    for (int k0 = 0; k0 < 1024; k0 += 16) {
        for (int e = tid; e < 1024; e += 256) {
            int r = e >> 4, kk = e & 15;
            As[kk][r] = A[(long)(bm + r) * 1024 + k0 + kk];
            Bs[kk][r] = Bw[(long)(bn + r) * 1024 + k0 + kk];
        }
        __syncthreads();
#pragma unroll
        for (int k = 0; k < 16; ++k) {
            float4 a = *(const float4*)&As[k][ty * 4];
            float4 b = *(const float4*)&Bs[k][tx * 4];
            float av[4] = {a.x, a.y, a.z, a.w};
            float bv[4] = {b.x, b.y, b.z, b.w};
#pragma unroll
            for (int i = 0; i < 4; ++i)
#pragma unroll
                for (int j = 0; j < 4; ++j) acc[i][j] = fmaf(av[i], bv[j], acc[i][j]);
        }
        __syncthreads();
    }
#pragma unroll
    for (int i = 0; i < 4; ++i) {
        long m = bm + ty * 4 + i;
#pragma unroll
        for (int j = 0; j < 4; ++j) {
            long n = bn + tx * 4 + j;
            C[m * 1024 + n] = res[m * 1024 + n] + bias[n] + acc[i][j];
        }
    }
}

__global__ __launch_bounds__(256) void rope_kernel(float* __restrict__ qkv,
                                                   const float* __restrict__ cs,
                                                   const float* __restrict__ sn) {
    int idx = blockIdx.x * 256 + threadIdx.x;
    if (idx >= T_TOK * NHEAD * 32) return;
    int p = idx & 31;
    int n = (idx >> 5) & 15;
    int t = idx >> 9;
    int s = t & (S_SEQ - 1);
    float c = cs[s * 32 + p], si = sn[s * 32 + p];
    long base = (long)t * 3072 + n * 192;
    float re = qkv[base + 2 * p], im = qkv[base + 2 * p + 1];
    qkv[base + 2 * p]     = re * c - im * si;
    qkv[base + 2 * p + 1] = re * si + im * c;
    re = qkv[base + 64 + 2 * p]; im = qkv[base + 64 + 2 * p + 1];
    qkv[base + 64 + 2 * p]     = re * c - im * si;
    qkv[base + 64 + 2 * p + 1] = re * si + im * c;
}

__global__ __launch_bounds__(256) void attn_kernel(const float* __restrict__ qkv,
                                                   float* __restrict__ ctx) {
    const int qb = blockIdx.x * 32;
    const int h = blockIdx.y, b = blockIdx.z;
    __shared__ float Qs[32][64];
    __shared__ float Ks[64][64];
    __shared__ float Vs[64][64];
    __shared__ float Ss[32][64];
    const int tid = threadIdx.x;
    const int q = tid >> 3, g = tid & 7;
    for (int e = tid; e < 32 * 64; e += 256) {
        int r = e >> 6, d = e & 63;
        Qs[r][d] = qkv[(long)(b * S_SEQ + qb + r) * 3072 + h * 192 + d];
    }
    float m_run = -1e30f, l_run = 0.0f;
    float acc[8] = {};
    for (int k0 = 0; k0 < S_SEQ; k0 += 64) {
        for (int e = tid; e < 64 * 64; e += 256) {
            int r = e >> 6, d = e & 63;
            long base = (long)(b * S_SEQ + k0 + r) * 3072 + h * 192;
            Ks[r][d] = qkv[base + 64 + d];
            Vs[r][d] = qkv[base + 128 + d];
        }
        __syncthreads();
        float s[8];
#pragma unroll
        for (int kk = 0; kk < 8; ++kk) {
            int k = g * 8 + kk;
            float dot = 0.0f;
#pragma unroll
            for (int d = 0; d < 64; ++d) dot = fmaf(Qs[q][d], Ks[k][d], dot);
            s[kk] = dot * 0.125f;
        }
        float mx = s[0];
#pragma unroll
        for (int kk = 1; kk < 8; ++kk) mx = fmaxf(mx, s[kk]);
#pragma unroll
        for (int w = 1; w < 8; w <<= 1) mx = fmaxf(mx, __shfl_xor(mx, w, 64));
        float m_new = fmaxf(m_run, mx);
        float p[8], ls = 0.0f;
#pragma unroll
        for (int kk = 0; kk < 8; ++kk) { p[kk] = __expf(s[kk] - m_new); ls += p[kk]; }
#pragma unroll
        for (int w = 1; w < 8; w <<= 1) ls += __shfl_xor(ls, w, 64);
        float alpha = __expf(m_run - m_new);
        l_run = l_run * alpha + ls;
        m_run = m_new;
#pragma unroll
        for (int kk = 0; kk < 8; ++kk) Ss[q][g * 8 + kk] = p[kk];
        __syncthreads();
#pragma unroll
        for (int j = 0; j < 8; ++j) acc[j] *= alpha;
        for (int k = 0; k < 64; ++k) {
            float pv = Ss[q][k];
#pragma unroll
            for (int j = 0; j < 8; ++j) acc[j] = fmaf(pv, Vs[k][g * 8 + j], acc[j]);
        }
        __syncthreads();
    }
    float inv = 1.0f / l_run;
#pragma unroll
    for (int j = 0; j < 8; ++j)
        ctx[(long)(b * S_SEQ + qb + q) * H_DIM + h * 64 + g * 8 + j] = acc[j] * inv;
}

__global__ __launch_bounds__(256) void gate_kernel(const float* __restrict__ h2,
                                                   const float* __restrict__ gate_w,
                                                   float* __restrict__ gw) {
    long t = blockIdx.x;
    float sum[4] = {0, 0, 0, 0};
    for (int i = threadIdx.x; i < H_DIM; i += 256) {
        float v = h2[t * H_DIM + i];
#pragma unroll
        for (int e = 0; e < 4; ++e) sum[e] = fmaf(v, gate_w[e * H_DIM + i], sum[e]);
    }
#pragma unroll
    for (int w = 1; w < 64; w <<= 1)
#pragma unroll
        for (int e = 0; e < 4; ++e) sum[e] += __shfl_xor(sum[e], w, 64);
    __shared__ float part[4][4];
    if ((threadIdx.x & 63) == 0)
#pragma unroll
        for (int e = 0; e < 4; ++e) part[e][threadIdx.x >> 6] = sum[e];
    __syncthreads();
    if (threadIdx.x == 0) {
        float lg[4];
#pragma unroll
        for (int e = 0; e < 4; ++e) lg[e] = part[e][0] + part[e][1] + part[e][2] + part[e][3];
        int i0 = 0;
        for (int e = 1; e < 4; ++e) if (lg[e] > lg[i0]) i0 = e;
        int i1 = -1;
        for (int e = 0; e < 4; ++e) if (e != i0 && (i1 < 0 || lg[e] > lg[i1])) i1 = e;
        float mx = fmaxf(lg[i0], lg[i1]);
        float e0 = __expf(lg[i0] - mx), e1 = __expf(lg[i1] - mx);
        float inv = 1.0f / (e0 + e1);
        float o[4] = {0, 0, 0, 0};
        o[i0] = e0 * inv; o[i1] = e1 * inv;
#pragma unroll
        for (int e = 0; e < 4; ++e) gw[t * 4 + e] = o[e];
    }
}

__global__ __launch_bounds__(256) void mul_kernel(const float* __restrict__ a,
                                                  const float* __restrict__ b,
                                                  float* __restrict__ c, int n) {
    int i = blockIdx.x * 256 + threadIdx.x;
    if (i < n) c[i] = a[i] * b[i];
}

extern "C" void kernel_launch(void* const* d_in, const int* in_sizes, int n_in,
                              void* d_out, int out_size, void* d_ws, size_t ws_size,
                              hipStream_t stream) {
    const float* x          = (const float*)d_in[0];
    const float* rot_cos    = (const float*)d_in[1];
    const float* rot_sin    = (const float*)d_in[2];
    const float* norm1_w    = (const float*)d_in[3];
    const float* norm2_w    = (const float*)d_in[4];
    const float* qkv_base   = (const float*)d_in[5];
    const float* qkv_spline = (const float*)d_in[6];
    const float* qkv_scaler = (const float*)d_in[7];
    const float* out_w      = (const float*)d_in[8];
    const float* out_b      = (const float*)d_in[9];
    const float* gate_w     = (const float*)d_in[10];
    const float* w1_base    = (const float*)d_in[11];
    const float* w1_spline  = (const float*)d_in[12];
    const float* w1_scaler  = (const float*)d_in[13];
    const float* w2_base    = (const float*)d_in[14];
    const float* w2_spline  = (const float*)d_in[15];
    const float* w2_scaler  = (const float*)d_in[16];
    const float* w3_base    = (const float*)d_in[17];
    const float* w3_spline  = (const float*)d_in[18];
    const float* w3_scaler  = (const float*)d_in[19];
    float* out = (float*)d_out;

    const size_t SZ_AUG  = (size_t)T_TOK * KAUG * 2;   // 37,748,736
    const size_t SZ_WQ   = (size_t)3072 * KAUG * 2;    // 56,623,104
    const size_t SZ_QKV  = (size_t)T_TOK * 3072 * 4;   // 25,165,824
    const size_t SZ_G12  = (size_t)T_TOK * 2048 * 4;   // 16,777,216
    const size_t SZ_TOK  = (size_t)T_TOK * H_DIM * 4;  //  8,388,608
    const size_t NEED = 2 * SZ_AUG + 2 * SZ_WQ + SZ_QKV + SZ_G12 + 2 * SZ_TOK + 32768;

    if (ws_size >= NEED) {
        char* pool = (char*)d_ws;
        // ---- attention-phase overlay ----
        ushort_t* A_hi = (ushort_t*)pool;
        ushort_t* A_lo = (ushort_t*)(pool + SZ_AUG);
        char* W1p = pool + 2 * SZ_AUG;
        char* W2p = pool + 2 * SZ_AUG + SZ_WQ;
        float* qkv = (float*)(pool + 2 * SZ_AUG + 2 * SZ_WQ);
        float* ctx = (float*)(pool + 2 * SZ_AUG + 2 * SZ_WQ + SZ_QKV + SZ_G12);
        float* tok = (float*)(pool + 2 * SZ_AUG + 2 * SZ_WQ + SZ_QKV + SZ_G12 + SZ_TOK);
        ushort_t* W1b = (ushort_t*)W1p;
        ushort_t* W2b = (ushort_t*)W2p;
        const size_t SZ_P = (size_t)T_TOK * 1024 * 2;  // 4 MB
        ushort_t* Qh  = (ushort_t*)W1p;
        ushort_t* Ql  = (ushort_t*)(W1p + SZ_P);
        ushort_t* Kh  = (ushort_t*)(W1p + 2 * SZ_P);
        ushort_t* Kl  = (ushort_t*)(W1p + 3 * SZ_P);
        ushort_t* Vth = (ushort_t*)(W1p + 4 * SZ_P);
        ushort_t* Vtl = (ushort_t*)(W1p + 5 * SZ_P);
        ushort_t* CtxH = (ushort_t*)W2p;
        ushort_t* CtxL = (ushort_t*)(W2p + SZ_P);
        ushort_t* OWh  = (ushort_t*)(W2p + 2 * SZ_P);
        ushort_t* OWl  = (ushort_t*)(W2p + 2 * SZ_P + SZ_P / 2);
        // ---- MoE-phase overlay (lifetimes disjoint, stream-ordered) ----
        const size_t SZ_W12G = (size_t)8192 * KAUG * 2;            // 150,994,944
        const size_t SZ_G12G = (size_t)MROWS * 2048 * 2;           //  18,874,368
        const size_t SZ_GG   = (size_t)MROWS * KAUG * 2;           //  84,934,656
        ushort_t* A2   = (ushort_t*)pool;                          // [0, 37.7M)
        ushort_t* W12g = (ushort_t*)(pool + SZ_AUG);               // [37.7, 188.7M)
        ushort_t* g12g = (ushort_t*)(pool + SZ_AUG + SZ_W12G);     // [188.7, 207.6M)
        char* route    = pool + SZ_AUG + SZ_W12G + SZ_G12G;        // ~70 KB
        int2*   sel  = (int2*)route;                               // 16 KB
        float2* selw = (float2*)(route + 16384);                   // 16 KB
        int*    rmap = (int*)(route + 32768);                      // 18,432 B
        float*  rwgt = (float*)(route + 51200);                    // 18,432 B
        int*    cnts = (int*)(route + 69632);                      // [0..3]
        int*    fill = cnts + 4;
        int*    roff = cnts + 8;                                   // [0..4]
        int*    eblk = cnts + 16;                                  // [0..35]
        ushort_t* Gg  = (ushort_t*)pool;                           // [0, 84.9M)
        ushort_t* W3a = (ushort_t*)(pool + SZ_GG);                 // [84.9, 160.4M)

        // --- attention branch: split-bf16 everywhere upstream of the gate ---
        rmsnorm_kernel<<<T_TOK, 256, 0, stream>>>(x, norm1_w, tok);
        pack_act<<<(T_TOK * 1024) / 256, 256, 0, stream>>>(tok, A_hi, A_lo);
        pack_w<<<(3072 * 1024) / 256, 256, 0, stream>>>(qkv_base, qkv_spline, qkv_scaler,
                                                        W1b, W2b, (long)3072 * 1024);
        hipMemsetAsync(qkv, 0, SZ_QKV, stream);
        mfma_gemm2<128, 1, 5, 4><<<dim3(3072 / 128, T_TOK / 128, 4), 256, 0, stream>>>(
            A_hi, A_lo, W1b, W2b, qkv, nullptr, nullptr, nullptr, 3072, KAUG);
        qk_pack<<<(T_TOK * NHEAD * 32) / 256, 256, 0, stream>>>(qkv, rot_cos, rot_sin,
                                                                Qh, Ql, Kh, Kl);
        v_trans<<<dim3(S_SEQ / 64, NHEAD, 2), 256, 0, stream>>>(qkv, Vth, Vtl);
        attn_mfma<<<dim3(S_SEQ / 64, NHEAD, 2), 256, 0, stream>>>(Qh, Ql, Kh, Kl,
                                                                  Vth, Vtl, ctx);
        split_pack<<<(T_TOK * 1024) / 256, 256, 0, stream>>>(ctx, CtxH, CtxL,
                                                             (long)T_TOK * 1024);
        split_pack<<<(1024 * 1024) / 256, 256, 0, stream>>>(out_w, OWh, OWl,
                                                            (long)1024 * 1024);
        prefill_out<<<(T_TOK * H_DIM / 4) / 256, 256, 0, stream>>>(x, out_b, out);
        mfma_gemm2<128, 1, 5, 4><<<dim3(1024 / 128, T_TOK / 128, 4), 256, 0, stream>>>(
            CtxH, CtxL, OWh, OWl, out, nullptr, nullptr, nullptr, 1024, 1024);
        rmsnorm_kernel<<<T_TOK, 256, 0, stream>>>(out, norm2_w, tok);

        // --- gate + routing (top-2, exact) ---
        hipMemsetAsync(route + 32768, 0, 36864, stream);      // rmap, rwgt = 0
        hipMemsetAsync(cnts, 0, 256, stream);                 // cnts/fill/off/eblk
        gate_route<<<T_TOK, 256, 0, stream>>>(tok, gate_w, sel, selw, cnts);
        route_offsets<<<1, 64, 0, stream>>>(cnts, fill, roff, eblk);
        route_scatter<<<T_TOK / 256, 256, 0, stream>>>(sel, selw, fill, rmap, rwgt);

        // --- MoE: grouped top-2, plain bf16 (downstream of gate) ---
        pack_act<<<(T_TOK * 1024) / 256, 256, 0, stream>>>(tok, A2, nullptr);
        pack_w_g<<<(4 * 1024 * 1024) / 256, 256, 0, stream>>>(
            w1_base, w1_spline, w1_scaler, W12g, 0);
        pack_w_g<<<(4 * 1024 * 1024) / 256, 256, 0, stream>>>(
            w2_base, w2_spline, w2_scaler, W12g, 1024);
        // grouped w1w2: M=4608 gathered rows, N=2048 per-expert cols
        mfma_gemm2<128, 0, 7, 1><<<dim3(2048 / 128, NRB), 256, 0, stream>>>(
            A2, nullptr, W12g, nullptr, (float*)g12g, rmap, eblk, nullptr, 2048, KAUG);
        // G rows = augment(g1*g2) on permuted rows (overwrites A2/W12g head - dead)
        mul_pack_g<<<(MROWS * 1024) / 256, 256, 0, stream>>>(g12g, Gg);
        // w3 pack (overwrites W12g middle - dead)
        pack_w<<<(4 * 1024 * 1024) / 256, 256, 0, stream>>>(
            w3_base, w3_spline, w3_scaler, W3a, nullptr, (long)4 * 1024 * 1024);
        // grouped w3 split-K2: out[map[row]] += wgt[row] * (G row @ W3_e^T)
        mfma_gemm2<128, 0, 8, 2><<<dim3(1024 / 128, NRB, 2), 256, 0, stream>>>(
            Gg, nullptr, W3a, nullptr, out, rmap, eblk, rwgt, 1024, KAUG);
        return;
    }

    // ---- fallback: fp32 path ----
    char* ws = (char*)d_ws;
    float* hn  = (float*)ws; ws += (size_t)T_TOK * H_DIM * 4;
    float* qkv = (float*)ws; ws += (size_t)T_TOK * 3072 * 4;
    float* ctx = (float*)ws; ws += (size_t)T_TOK * H_DIM * 4;
    float* h2  = (float*)ws; ws += (size_t)T_TOK * H_DIM * 4;
    float* gw  = (float*)ws; ws += (size_t)T_TOK * E_EXP * 4;
    float* g1  = (float*)ws; ws += (size_t)T_TOK * DFF_ * 4;
    float* g2  = (float*)ws; ws += (size_t)T_TOK * DFF_ * 4;
    float* gm  = (float*)ws; ws += (size_t)T_TOK * DFF_ * 4;

    rmsnorm_kernel<<<T_TOK, 256, 0, stream>>>(x, norm1_w, hn);
    dim3 gq(3072 / 64, T_TOK / 64);
    kan_gemm<<<gq, 256, 0, stream>>>(hn, qkv_base, qkv_spline, qkv_scaler, qkv,
                                     nullptr, 0, 3072, 0);
    rope_kernel<<<(T_TOK * NHEAD * 32) / 256, 256, 0, stream>>>(qkv, rot_cos, rot_sin);
    dim3 ga(S_SEQ / 32, NHEAD, 2);
    attn_kernel<<<ga, 256, 0, stream>>>(qkv, ctx);
    dim3 go(1024 / 64, T_TOK / 64);
    gemm_bias_res<<<go, 256, 0, stream>>>(ctx, out_w, out_b, x, out);
    rmsnorm_kernel<<<T_TOK, 256, 0, stream>>>(out, norm2_w, h2);
    gate_kernel<<<T_TOK, 256, 0, stream>>>(h2, gate_w, gw);
    dim3 ge(1024 / 64, T_TOK / 64);
    for (int e = 0; e < E_EXP; ++e) {
        long wo = (long)e * DFF_ * H_DIM;
        kan_gemm<<<ge, 256, 0, stream>>>(h2, w1_base + wo, w1_spline + wo * 8,
                                         w1_scaler + wo, g1, nullptr, 0, DFF_, 0);
        kan_gemm<<<ge, 256, 0, stream>>>(h2, w2_base + wo, w2_spline + wo * 8,
                                         w2_scaler + wo, g2, nullptr, 0, DFF_, 0);
        mul_kernel<<<(T_TOK * DFF_) / 256, 256, 0, stream>>>(g1, g2, gm, T_TOK * DFF_);
        kan_gemm<<<ge, 256, 0, stream>>>(gm, w3_base + wo, w3_spline + wo * 8,
                                         w3_scaler + wo, out, gw + e, E_EXP, H_DIM, 1);
    }
}